// Round 9
// baseline (346.338 us; speedup 1.0000x reference)
//
#include <hip/hip_runtime.h>
#include <cstdint>
#include <cstddef>
#include <math.h>

#define N_NODES 40000
#define N_RELS  474
#define E0      100000
#define NE      130000
#define NB      8192
#define LRALPHA 0.2f

#define KP1 128
#define KP2 256
// Pcat cols: [0:200) Pt interleaved | [200:400) Ps interleaved | [400:600) entW | [600:604) dots | pad
#define LD1 608
// Qcat cols: [0:200) Qt | [200:400) Qs | 400 dqt | 401 dqs | pad
#define LD2 416
#define NPAD1 640
#define NPAD2 448
#define DTH 16
#define HUBW 2048

// MEGA-A block ranges (raw-input-only regions)
#define A_HIST   508
#define A_RELP   (A_HIST + 119)
#define A_MMW    (A_RELP + 32)
#define A_PACK1  (A_MMW + 320)
#define A_PACK2  (A_PACK1 + 448)
#define A_MASK   (A_PACK2 + 32)
#define A_TOT    (A_MASK + 128)
// SCAN-B: full scan (1 block) | dR1 (119) | R2 GEMM (32)
#define B_DR1    120
#define B_TOT    (B_DR1 + 32)
// MEGA-C: scatter | gemm1(fused l2norm + unmasked out) | compact | dotv | ortho_fin
#define C_SCAT   508
#define C_GEMM   (C_SCAT + 1250)
#define C_CMP    (C_GEMM + 157)
#define C_DOTV   (C_CMP + 119)
#define C_TOT    (C_DOTV + 1)
// NODE1: layer-1 main interleave | layer-1 hub
#define N1_MAIN  2500
#define N1_TOT   (N1_MAIN + 512)

typedef __attribute__((ext_vector_type(8))) short short8;
typedef __attribute__((ext_vector_type(4))) float floatx4;

static __device__ __forceinline__ unsigned short f2bf(float f) {
    union { float f; uint32_t u; } v; v.f = f;
    uint32_t r = v.u + 0x7fff + ((v.u >> 16) & 1);
    return (unsigned short)(r >> 16);
}
static __device__ __forceinline__ float bf2f(unsigned short h) {
    union { uint32_t u; float f; } v; v.u = ((uint32_t)h) << 16;
    return v.f;
}
static __device__ __forceinline__ float bflo(uint32_t u) { return bf2f((unsigned short)(u & 0xffff)); }
static __device__ __forceinline__ float bfhi(uint32_t u) { return bf2f((unsigned short)(u >> 16)); }

static __device__ __forceinline__ int rdl(int v, int l) {
    return __builtin_amdgcn_readlane(v, l);
}
static __device__ __forceinline__ float rdlf(float v, int l) {
    return __int_as_float(__builtin_amdgcn_readlane(__float_as_int(v), l));
}
static __device__ __forceinline__ float frcp(float x) { return __builtin_amdgcn_rcpf(x); }

// ================= device components =================

static __device__ void d_hist(int bid, int tid, const int* __restrict__ tgt_el,
                              const int* __restrict__ nhop, int* __restrict__ deg) {
    int e = bid * 256 + tid;
    if (e >= NE) return;
    int t = (e < E0) ? tgt_el[e] : nhop[(size_t)(e - E0) * 4 + 3];
    atomicAdd(&deg[t], 1);
}

static __device__ void d_mask(int bid, int tid, const int* __restrict__ batch,
                              float* __restrict__ mask) {
    int i = bid * 256 + tid;
    if (i < NB) mask[batch[(size_t)i * 3 + 2]] = 1.0f;
}

static __device__ void d_ortho_part(int bid, int tid, const float* __restrict__ att_a,
                                    const float* __restrict__ out_a, float* __restrict__ accum) {
    float loc[9] = {0,0,0,0,0,0,0,0,0};
    for (int i = bid * 256 + tid; i < 90000; i += 128 * 256) {
        int seg, li;
        const float* base;
        int L;
        if (i < 15000)      { seg = 0; li = i;          base = att_a;         L = 15000; }
        else if (i < 30000) { seg = 1; li = i - 15000;  base = att_a + 30000; L = 15000; }
        else                { seg = 2; li = i - 30000;  base = out_a;         L = 60000; }
        float a = base[li], b = base[L + li];
        loc[seg * 3 + 0] += a * a;
        loc[seg * 3 + 1] += b * b;
        loc[seg * 3 + 2] += a * b;
    }
    int lane = tid & 63;
#pragma unroll
    for (int q = 0; q < 9; q++) {
        float s = loc[q];
#pragma unroll
        for (int o = 32; o > 0; o >>= 1) s += __shfl_down(s, o);
        if (lane == 0 && s != 0.f) atomicAdd(&accum[q], s);
    }
}

// ---- single-block full prefix scan: deg (in degcur) -> rowptr, cursor copy (in-place) ----
static __device__ void d_fullscan(int tid, int* degcur, int* rowptr) {
    __shared__ int wsum[4];
    int lane = tid & 63, wv = tid >> 6;
    int carry = 0;
    for (int base = 0; base < N_NODES; base += 1024) {
        int i0 = base + tid * 4;
        int v0 = (i0 + 0 < N_NODES) ? degcur[i0 + 0] : 0;
        int v1 = (i0 + 1 < N_NODES) ? degcur[i0 + 1] : 0;
        int v2 = (i0 + 2 < N_NODES) ? degcur[i0 + 2] : 0;
        int v3 = (i0 + 3 < N_NODES) ? degcur[i0 + 3] : 0;
        int s1 = v0 + v1, s2 = s1 + v2, tot = s2 + v3;
        int x = tot;
#pragma unroll
        for (int o = 1; o < 64; o <<= 1) {
            int t = __shfl_up(x, o);
            if (lane >= o) x += t;
        }
        if (lane == 63) wsum[wv] = x;
        __syncthreads();
        int add = carry;
        for (int k = 0; k < wv; k++) add += wsum[k];
        int excl = add + x - tot;
        if (i0 + 0 < N_NODES) { rowptr[i0 + 0] = excl;      degcur[i0 + 0] = excl; }
        if (i0 + 1 < N_NODES) { rowptr[i0 + 1] = excl + v0; degcur[i0 + 1] = excl + v0; }
        if (i0 + 2 < N_NODES) { rowptr[i0 + 2] = excl + s1; degcur[i0 + 2] = excl + s1; }
        if (i0 + 3 < N_NODES) { rowptr[i0 + 3] = excl + s2; degcur[i0 + 3] = excl + s2; }
        int tot_all = wsum[0] + wsum[1] + wsum[2] + wsum[3];
        __syncthreads();
        carry += tot_all;
    }
    if (tid == 0) rowptr[N_NODES] = carry;
}

// ---- pack layer-1 B matrix (uvec rows computed inline) ----
static __device__ void d_pack1(int bid, int tid, const float* __restrict__ att_a,
                               const float* __restrict__ att_a2,
                               const float* __restrict__ W_ent,
                               unsigned short* __restrict__ W) {
    int idx = bid * 256 + tid;
    if (idx >= NPAD1 * KP1) return;
    int j = idx & 7;
    int lane = (idx >> 3) & 63;
    int u = idx >> 9;
    int ks = u & 3;
    int t = u >> 2;
    int r = t * 16 + (lane & 15);
    int k = ks * 32 + (lane >> 4) * 8 + j;
    float val = 0.f;
    if (k < 100) {
        if (r < 200) {
            int i = r >> 1, h = r & 1;
            val = att_a[h * 30000 + i * 300 + k];
        } else if (r < 400) {
            int rr = r - 200, i = rr >> 1, h = rr & 1;
            val = att_a[h * 30000 + i * 300 + 100 + k];
        } else if (r < 600) {
            val = W_ent[k * 200 + (r - 400)];
        } else if (r < 604) {
            int v = r - 600, head = v >> 1, part = v & 1;
            const float* base = att_a + head * 30000 + part * 100 + k;
            const float* a2v = att_a2 + head * 100;
            float s = 0.f;
            for (int n = 0; n < 100; n++) s += a2v[n] * base[n * 300];
            val = s;
        }
    }
    W[idx] = f2bf(val);
}

// ---- pack layer-2 B matrix (uvec rows computed inline) ----
static __device__ void d_pack2(int bid, int tid, const float* __restrict__ out_a,
                               const float* __restrict__ out_a2,
                               unsigned short* __restrict__ W) {
    int idx = bid * 256 + tid;
    if (idx >= NPAD2 * KP2) return;
    int j = idx & 7;
    int lane = (idx >> 3) & 63;
    int u = idx >> 9;
    int ks = u & 7;
    int t = u >> 3;
    int r = t * 16 + (lane & 15);
    int k = ks * 32 + (lane >> 4) * 8 + j;
    float val = 0.f;
    if (k < 200) {
        int klog = (k & 1) * 100 + (k >> 1);
        if (r < 200)       val = out_a[r * 600 + klog];
        else if (r < 400)  val = out_a[(r - 200) * 600 + 200 + klog];
        else if (r == 400) {
            float s = 0.f;
            for (int n = 0; n < 200; n++) s += out_a2[n] * out_a[n * 600 + klog];
            val = s;
        } else if (r == 401) {
            float s = 0.f;
            for (int n = 0; n < 200; n++) s += out_a2[n] * out_a[n * 600 + 200 + klog];
            val = s;
        }
    }
    W[idx] = f2bf(val);
}

static __device__ void d_scatter(int bid, int tid, const int* __restrict__ tgt_el,
                                 const int* __restrict__ src_el, const int* __restrict__ etype,
                                 const int* __restrict__ nhop, int* __restrict__ cursor,
                                 int* __restrict__ srcs, int2* __restrict__ relpk) {
    int e = bid * 256 + tid;
    if (e >= NE) return;
    int t, s, r1, r2;
    if (e < E0) {
        t = tgt_el[e]; s = src_el[e]; r1 = etype[e]; r2 = -1;
    } else {
        const int* nh = nhop + (size_t)(e - E0) * 4;
        t = nh[3]; s = nh[0]; r1 = nh[1]; r2 = nh[2];
    }
    int p = atomicAdd(&cursor[t], 1);
    srcs[p] = s;
    relpk[p] = make_int2(r1, r2);
}

static __device__ void d_compact(int bid, int tid, const int* __restrict__ rowptr,
                                 const float* __restrict__ mask,
                                 int* __restrict__ Hlist, int* __restrict__ Mlist,
                                 int* __restrict__ cnts) {
    int i = bid * 256 + tid;
    if (i >= N_NODES) return;
    int deg = rowptr[i + 1] - rowptr[i];
    if (deg > DTH) { int p = atomicAdd(&cnts[0], 1); Hlist[p] = i; }
    if (mask[i] != 0.f) { int p = atomicAdd(&cnts[1], 1); Mlist[p] = i; }
}

// ---- bf16 MFMA GEMM (fragment-ordered B) — layer-2 ----
template <int KP>
static __device__ void d_gemm(int bx, int by, char* smem_raw, int tid,
                              const unsigned short* __restrict__ A,
                              const unsigned short* __restrict__ B,
                              unsigned short* __restrict__ C,
                              int ldc, int N, int gPerSplit) {
    constexpr int KSTEPS = KP / 32;
    constexpr int KCH = KSTEPS / 4;
    unsigned short (*cbuf)[16][64] = (unsigned short (*)[16][64])smem_raw;
    int wave = tid >> 6;
    int lane = tid & 63;
    int quad = lane >> 4;
    int l16 = lane & 15;
    int m0 = bx * 64 + wave * 16;
    short8 afrag[KSTEPS];
    const unsigned short* arow = A + (size_t)(m0 + l16) * KP + quad * 8;
#pragma unroll
    for (int ks = 0; ks < KSTEPS; ks++)
        afrag[ks] = *(const short8*)(arow + ks * 32);

    int Gtot = (N + 63) >> 6;
    int g0 = by * gPerSplit;
    int g1 = g0 + gPerSplit;
    if (g1 > Gtot) g1 = Gtot;
    for (int g = g0; g < g1; g++) {
        int nb = g << 6;
        const unsigned short* bgrp = B + (((size_t)(g << 2) * KSTEPS) << 9) + (lane << 3);
        floatx4 acc[4];
#pragma unroll
        for (int t = 0; t < 4; t++) acc[t] = (floatx4){0.f, 0.f, 0.f, 0.f};
#pragma unroll
        for (int ch = 0; ch < KCH; ch++) {
            short8 bf[4][4];
#pragma unroll
            for (int t = 0; t < 4; t++)
#pragma unroll
                for (int k = 0; k < 4; k++)
                    bf[t][k] = *(const short8*)(bgrp + ((size_t)(t * KSTEPS + ch * 4 + k) << 9));
#pragma unroll
            for (int k = 0; k < 4; k++)
#pragma unroll
                for (int t = 0; t < 4; t++)
                    acc[t] = __builtin_amdgcn_mfma_f32_16x16x32_bf16(afrag[ch * 4 + k], bf[t][k], acc[t], 0, 0, 0);
        }
        int r0 = quad * 4;
#pragma unroll
        for (int t = 0; t < 4; t++)
#pragma unroll
            for (int i = 0; i < 4; i++)
                cbuf[wave][r0 + i][t * 16 + l16] = f2bf(acc[t][i]);
        int colsA = N - nb; if (colsA > 64) colsA = 64;
        int cols8 = colsA >> 3;
        int sh = (colsA >= 64) ? 3 : 2;
        int nchunks = cols8 << 4;
        for (int c = lane; c < nchunks; c += 64) {
            int row = c >> sh;
            int col8 = (c & (cols8 - 1)) << 3;
            *(uint4*)(C + (size_t)(m0 + row) * ldc + nb + col8) =
                *(const uint4*)&cbuf[wave][row][col8];
        }
    }
}

// ---- layer-1 GEMM: fused row-l2norm (raw fp32 in) + fused unmasked out-write (by==1) ----
static __device__ void d_gemm1f(int bx, int by, char* smem_raw, int tid,
                                const float* __restrict__ ent,
                                const unsigned short* __restrict__ B,
                                unsigned short* __restrict__ C,
                                const float* __restrict__ mask,
                                float* __restrict__ out) {
    float (*rows)[105] = (float (*)[105])smem_raw;              // 26880 B (consumed pre-loop)
    float* invn = (float*)(smem_raw + 64 * 105 * 4);            // +256 B  (consumed pre-loop)
    unsigned short (*entw)[200] = (unsigned short (*)[200])(smem_raw + 8192);  // 25600 B (loop+epilogue)
    int m0 = bx * 64;
    for (int idx = tid; idx < 6400; idx += 256) {
        int r = idx / 100, c = idx - r * 100;
        rows[r][c] = ent[(size_t)(m0 + r) * 100 + c];
    }
    __syncthreads();
    {
        int r = tid >> 2, q = tid & 3;
        const float* rp = rows[r] + q * 25;
        float s = 0.f;
#pragma unroll
        for (int c = 0; c < 25; c++) { float v = rp[c]; s += v * v; }
        s += __shfl_xor(s, 1);
        s += __shfl_xor(s, 2);
        if (q == 0) invn[r] = 1.f / fmaxf(sqrtf(s), 1e-12f);
    }
    __syncthreads();
    int wave = tid >> 6;
    int lane = tid & 63;
    int quad = lane >> 4;
    int l16 = lane & 15;
    int rr = wave * 16 + l16;
    float inv = invn[rr];
    short8 afrag[4];
#pragma unroll
    for (int ks = 0; ks < 4; ks++) {
        short8 f;
#pragma unroll
        for (int j = 0; j < 8; j++) {
            int col = ks * 32 + quad * 8 + j;
            f[j] = (col < 100) ? (short)f2bf(rows[rr][col] * inv) : (short)0;
        }
        afrag[ks] = f;
    }
    __syncthreads();   // rows region reused as cbuf below
    unsigned short (*cbuf)[16][64] = (unsigned short (*)[16][64])smem_raw;
    int mo0 = m0 + wave * 16;
    int g0 = by * 5, g1 = g0 + 5;
    if (g1 > 10) g1 = 10;
    for (int g = g0; g < g1; g++) {
        int nb = g << 6;
        const unsigned short* bgrp = B + (((size_t)(g << 2) * 4) << 9) + (lane << 3);
        floatx4 acc[4];
#pragma unroll
        for (int t = 0; t < 4; t++) acc[t] = (floatx4){0.f, 0.f, 0.f, 0.f};
        short8 bf[4][4];
#pragma unroll
        for (int t = 0; t < 4; t++)
#pragma unroll
            for (int k = 0; k < 4; k++)
                bf[t][k] = *(const short8*)(bgrp + ((size_t)(t * 4 + k) << 9));
#pragma unroll
        for (int k = 0; k < 4; k++)
#pragma unroll
            for (int t = 0; t < 4; t++)
                acc[t] = __builtin_amdgcn_mfma_f32_16x16x32_bf16(afrag[k], bf[t][k], acc[t], 0, 0, 0);
        int r0 = quad * 4;
#pragma unroll
        for (int t = 0; t < 4; t++)
#pragma unroll
            for (int i = 0; i < 4; i++)
                cbuf[wave][r0 + i][t * 16 + l16] = f2bf(acc[t][i]);
        int colsA = 608 - nb; if (colsA > 64) colsA = 64;
        int cols8 = colsA >> 3;
        int sh = (colsA >= 64) ? 3 : 2;
        int nchunks = cols8 << 4;
        for (int c = lane; c < nchunks; c += 64) {
            int row = c >> sh;
            int col8 = (c & (cols8 - 1)) << 3;
            *(uint4*)(C + (size_t)(mo0 + row) * LD1 + nb + col8) =
                *(const uint4*)&cbuf[wave][row][col8];
        }
        // keep entW window (cols [400,600)) for fused out-write
        if (by == 1) {
            int cg = nb + lane;
            if (cg >= 400 && cg < 600) {
#pragma unroll
                for (int i = 0; i < 16; i++)
                    entw[wave * 16 + i][cg - 400] = cbuf[wave][i][lane];
            }
        }
    }
    // fused layer-2 unmasked streaming output: out[node] = l2norm(entW row)
    if (by == 1) {
        bool fv = (lane < 50);
        int c4 = lane * 4;
        for (int i = 0; i < 16; i++) {
            int row = wave * 16 + i;
            int node = m0 + row;
            float mk = mask[node];
            if (mk != 0.f) continue;    // masked nodes written by node2h
            float v0 = 0.f, v1 = 0.f, v2 = 0.f, v3 = 0.f;
            if (fv) {
                v0 = bf2f(entw[row][c4 + 0]);
                v1 = bf2f(entw[row][c4 + 1]);
                v2 = bf2f(entw[row][c4 + 2]);
                v3 = bf2f(entw[row][c4 + 3]);
            }
            float ss = v0 * v0 + v1 * v1 + v2 * v2 + v3 * v3;
#pragma unroll
            for (int o = 32; o > 0; o >>= 1) ss += __shfl_down(ss, o);
            ss = __shfl(ss, 0);
            float iv = frcp(fmaxf(sqrtf(ss), 1e-12f));
            if (fv) {
                *(float4*)(out + (size_t)node * 200 + c4) =
                    make_float4(v0 * iv, v1 * iv, v2 * iv, v3 * iv);
            }
        }
    }
}

// ---- generic tiled fp32 matmul (474-row cases) ----
template <bool BT>
static __device__ void d_mm(int bx, int by, char* smem_raw, int tid,
                            const float* __restrict__ A, int lda,
                            const float* __restrict__ B, int ldb,
                            float* __restrict__ C, int ldc,
                            int M, int N, int K) {
    float (*As)[65] = (float (*)[65])smem_raw;
    float (*Bs)[65] = (float (*)[65])(smem_raw + 16 * 65 * 4);
    int tx = tid & 15, ty = tid >> 4;
    int m0 = by * 64, n0 = bx * 64;
    float acc[4][4] = {};
    for (int k0 = 0; k0 < K; k0 += 16) {
        {
            int r = tid >> 2;
            int c4 = (tid & 3) * 4;
            int m = m0 + r;
#pragma unroll
            for (int u = 0; u < 4; u++) {
                int k = k0 + c4 + u;
                As[c4 + u][r] = (m < M && k < K) ? A[(size_t)m * lda + k] : 0.f;
            }
        }
        if (BT) {
            int r = tid >> 2;
            int c4 = (tid & 3) * 4;
            int n = n0 + r;
#pragma unroll
            for (int u = 0; u < 4; u++) {
                int k = k0 + c4 + u;
                Bs[c4 + u][r] = (n < N && k < K) ? B[(size_t)n * ldb + k] : 0.f;
            }
        } else {
            int kk = tid >> 4;
            int nn4 = (tid & 15) * 4;
            int k = k0 + kk;
#pragma unroll
            for (int u = 0; u < 4; u++) {
                int n = n0 + nn4 + u;
                Bs[kk][nn4 + u] = (k < K && n < N) ? B[(size_t)k * ldb + n] : 0.f;
            }
        }
        __syncthreads();
#pragma unroll
        for (int k = 0; k < 16; k++) {
            float a[4], b[4];
#pragma unroll
            for (int i = 0; i < 4; i++) a[i] = As[k][ty + 16 * i];
#pragma unroll
            for (int j = 0; j < 4; j++) b[j] = Bs[k][tx + 16 * j];
#pragma unroll
            for (int i = 0; i < 4; i++)
#pragma unroll
                for (int j = 0; j < 4; j++) acc[i][j] += a[i] * b[j];
        }
        __syncthreads();
    }
#pragma unroll
    for (int i = 0; i < 4; i++) {
        int m = m0 + ty + 16 * i;
        if (m >= M) continue;
#pragma unroll
        for (int j = 0; j < 4; j++) {
            int n = n0 + tx + 16 * j;
            if (n < N) C[(size_t)m * ldc + n] = acc[i][j];
        }
    }
}

static __device__ void d_relproj1(int bid, int tid, const float* __restrict__ rel_emb,
                                  const float* __restrict__ att_a, float* __restrict__ R1i) {
    int w = (bid * 256 + tid) >> 6;
    int lane = tid & 63;
    if (w >= N_RELS) return;
    const float* re = rel_emb + (size_t)w * 100;
    float2* dst = (float2*)(R1i + (size_t)w * 200);
    for (int f = lane; f < 100; f += 64) {
        const float* a0 = att_a + f * 300 + 200;
        const float* a1 = att_a + 30000 + f * 300 + 200;
        float s0 = 0.f, s1 = 0.f;
        for (int k = 0; k < 100; k++) {
            float rk = re[k];
            s0 += rk * a0[k];
            s1 += rk * a1[k];
        }
        dst[f] = make_float2(s0, s1);
    }
}

static __device__ void d_dR1(int bid, int tid, const float* __restrict__ R1i,
                             const float* __restrict__ att_a2,
                             float* __restrict__ dR10, float* __restrict__ dR11) {
    int w = (bid * 256 + tid) >> 6;
    int lane = tid & 63;
    if (w >= N_RELS) return;
    const float2* row = (const float2*)(R1i + (size_t)w * 200);
    float s0 = 0.f, s1 = 0.f;
    for (int f = lane; f < 100; f += 64) {
        float2 v = row[f];
        s0 += v.x * att_a2[f];
        s1 += v.y * att_a2[100 + f];
    }
#pragma unroll
    for (int o = 32; o > 0; o >>= 1) {
        s0 += __shfl_down(s0, o);
        s1 += __shfl_down(s1, o);
    }
    if (lane == 0) { dR10[w] = s0; dR11[w] = s1; }
}

static __device__ void d_ortho_fin(int tid, const float* __restrict__ accum,
                                   float* __restrict__ out_scalar) {
    if (tid != 0) return;
    float total = 0.f;
#pragma unroll
    for (int m = 0; m < 3; m++) {
        float s0 = accum[m * 3 + 0], s1 = accum[m * 3 + 1], sc = accum[m * 3 + 2];
        float c = sc / (fmaxf(sqrtf(s0), 1e-12f) * fmaxf(sqrtf(s1), 1e-12f));
        total += 0.01f * 2.f * c * c;
    }
    out_scalar[0] = total;
}

// ================= node layer-1 components =================

static __device__ void d_node1_one(int node, int lane,
                        const int* __restrict__ rowptr, const int* __restrict__ srcs,
                        const int2* __restrict__ relpk,
                        const unsigned short* __restrict__ Pcat,
                        const float* __restrict__ R1i,
                        const float* __restrict__ dR10, const float* __restrict__ dR11,
                        unsigned short* __restrict__ x) {
    bool fv = (lane < 50);
    int c4 = lane * 4;
    int beg = rowptr[node], end = rowptr[node + 1];
    int deg = end - beg;
    int fast = (deg < 64) ? deg : 64;
    uint2 td = *(const uint2*)(Pcat + (size_t)node * LD1 + 600);
    float t0h = bflo(td.x), t1h = bflo(td.y);
    int sL = 0, rxL = 0, ryL = -1;
    float wxL = 0.f, wyL = 0.f;
    if (lane < fast) {
        int p = beg + lane;
        sL = srcs[p];
        int2 rp = relpk[p];
        rxL = rp.x; ryL = rp.y;
        float dr0 = dR10[rp.x], dr1 = dR11[rp.x];
        if (rp.y >= 0) { dr0 += dR10[rp.y]; dr1 += dR11[rp.y]; }
        uint2 sd = *(const uint2*)(Pcat + (size_t)sL * LD1 + 600);
        float p0 = t0h + bfhi(sd.x) + dr0;
        float p1 = t1h + bfhi(sd.y) + dr1;
        p0 = (p0 >= 0.f) ? p0 : LRALPHA * p0;
        p1 = (p1 >= 0.f) ? p1 : LRALPHA * p1;
        wxL = __expf(-p0);
        wyL = __expf(-p1);
    }
    float b0 = 0.f, b1 = 0.f, b2 = 0.f, b3 = 0.f;
    float rs0 = 0.f, rs1 = 0.f;
    for (int j = 0; j < fast; j += 4) {
#pragma unroll
        for (int u = 0; u < 4; u++) {
            int jj = j + u;
            bool act = (jj < fast);
            int ls = act ? jj : 0;
            int sE = rdl(sL, ls);
            int rxE = rdl(rxL, ls);
            int ryE = act ? rdl(ryL, ls) : -1;
            float wxE = act ? rdlf(wxL, ls) : 0.f;
            float wyE = act ? rdlf(wyL, ls) : 0.f;
            uint2 ps = make_uint2(0u, 0u);
            float4 rv = make_float4(0.f, 0.f, 0.f, 0.f);
            if (fv) {
                ps = *(const uint2*)(Pcat + (size_t)sE * LD1 + 200 + c4);
                rv = *(const float4*)(R1i + (size_t)rxE * 200 + c4);
                if (ryE >= 0) {
                    float4 rb = *(const float4*)(R1i + (size_t)ryE * 200 + c4);
                    rv.x += rb.x; rv.y += rb.y; rv.z += rb.z; rv.w += rb.w;
                }
            }
            rs0 += wxE; rs1 += wyE;
            b0 += wxE * (bflo(ps.x) + rv.x);
            b1 += wyE * (bfhi(ps.x) + rv.y);
            b2 += wxE * (bflo(ps.y) + rv.z);
            b3 += wyE * (bfhi(ps.y) + rv.w);
        }
    }
    for (int p = beg + 64; p < end; p++) {
        int sE = srcs[p];
        int2 rp = relpk[p];
        float dr0 = dR10[rp.x], dr1 = dR11[rp.x];
        if (rp.y >= 0) { dr0 += dR10[rp.y]; dr1 += dR11[rp.y]; }
        uint2 sd = *(const uint2*)(Pcat + (size_t)sE * LD1 + 600);
        float p0 = t0h + bfhi(sd.x) + dr0;
        float p1 = t1h + bfhi(sd.y) + dr1;
        p0 = (p0 >= 0.f) ? p0 : LRALPHA * p0;
        p1 = (p1 >= 0.f) ? p1 : LRALPHA * p1;
        float wx = __expf(-p0), wy = __expf(-p1);
        uint2 ps = make_uint2(0u, 0u);
        float4 rv = make_float4(0.f, 0.f, 0.f, 0.f);
        if (fv) {
            ps = *(const uint2*)(Pcat + (size_t)sE * LD1 + 200 + c4);
            rv = *(const float4*)(R1i + (size_t)rp.x * 200 + c4);
            if (rp.y >= 0) {
                float4 rb = *(const float4*)(R1i + (size_t)rp.y * 200 + c4);
                rv.x += rb.x; rv.y += rb.y; rv.z += rb.z; rv.w += rb.w;
            }
        }
        rs0 += wx; rs1 += wy;
        b0 += wx * (bflo(ps.x) + rv.x);
        b1 += wy * (bfhi(ps.x) + rv.y);
        b2 += wx * (bflo(ps.y) + rv.z);
        b3 += wy * (bfhi(ps.y) + rv.w);
    }
    float d0 = (rs0 == 0.f) ? 1e-12f : rs0;
    float d1 = (rs1 == 0.f) ? 1e-12f : rs1;
    float i0 = frcp(d0), i1 = frcp(d1);
    if (fv) {
        uint2 pt = *(const uint2*)(Pcat + (size_t)node * LD1 + c4);
        float v0 = (b0 + rs0 * bflo(pt.x)) * i0;
        float v1 = (b1 + rs1 * bfhi(pt.x)) * i1;
        float v2 = (b2 + rs0 * bflo(pt.y)) * i0;
        float v3 = (b3 + rs1 * bfhi(pt.y)) * i1;
        v0 = (v0 > 0.f) ? v0 : __expf(v0) - 1.f;
        v1 = (v1 > 0.f) ? v1 : __expf(v1) - 1.f;
        v2 = (v2 > 0.f) ? v2 : __expf(v2) - 1.f;
        v3 = (v3 > 0.f) ? v3 : __expf(v3) - 1.f;
        uint2 w;
        w.x = (uint32_t)f2bf(v0) | ((uint32_t)f2bf(v1) << 16);
        w.y = (uint32_t)f2bf(v2) | ((uint32_t)f2bf(v3) << 16);
        unsigned short* xr = x + (size_t)node * KP2;
        *(uint2*)(xr + c4) = w;
    }
}

static __device__ void d_node1_main(int wid, int lane,
                        const int* __restrict__ rowptr, const int* __restrict__ srcs,
                        const int2* __restrict__ relpk,
                        const unsigned short* __restrict__ Pcat,
                        const float* __restrict__ R1i,
                        const float* __restrict__ dR10, const float* __restrict__ dR11,
                        unsigned short* __restrict__ x) {
    int n0 = wid * 4;
    if (n0 >= N_NODES) return;
    bool fv = (lane < 50);
    int c4 = lane * 4;
    int rp = (lane < 5) ? rowptr[n0 + lane] : 0;
    int bnd0 = rdl(rp, 0), bnd1 = rdl(rp, 1), bnd2 = rdl(rp, 2), bnd3 = rdl(rp, 3), bnd4 = rdl(rp, 4);
    int beg[4] = {bnd0, bnd1, bnd2, bnd3};
    int end[4] = {bnd1, bnd2, bnd3, bnd4};
    int deg[4], fast[4];
#pragma unroll
    for (int i = 0; i < 4; i++) {
        deg[i] = end[i] - beg[i];
        fast[i] = (deg[i] <= DTH) ? deg[i] : 0;
    }
    int li = lane >> 4, lk = lane & 15;
    int begL = (li == 0) ? bnd0 : (li == 1) ? bnd1 : (li == 2) ? bnd2 : bnd3;
    int endL = (li == 0) ? bnd1 : (li == 1) ? bnd2 : (li == 2) ? bnd3 : bnd4;
    int degL = endL - begL;
    int fastL = (degL <= DTH) ? degL : 0;
    uint2 tdL = *(const uint2*)(Pcat + (size_t)(n0 + li) * LD1 + 600);
    float t0L = bflo(tdL.x), t1L = bflo(tdL.y);
    int sL = 0, rxL = 0, ryL = -1;
    float wxL = 0.f, wyL = 0.f;
    if (lk < fastL) {
        int p = begL + lk;
        sL = srcs[p];
        int2 rq = relpk[p];
        rxL = rq.x; ryL = rq.y;
        float dr0 = dR10[rq.x], dr1 = dR11[rq.x];
        if (rq.y >= 0) { dr0 += dR10[rq.y]; dr1 += dR11[rq.y]; }
        uint2 sd = *(const uint2*)(Pcat + (size_t)sL * LD1 + 600);
        float p0 = t0L + bfhi(sd.x) + dr0;
        float p1 = t1L + bfhi(sd.y) + dr1;
        p0 = (p0 >= 0.f) ? p0 : LRALPHA * p0;
        p1 = (p1 >= 0.f) ? p1 : LRALPHA * p1;
        wxL = __expf(-p0);
        wyL = __expf(-p1);
    }
    float b[4][4] = {};
    float rsx[4] = {0.f, 0.f, 0.f, 0.f}, rsy[4] = {0.f, 0.f, 0.f, 0.f};
    int kmax = max(max(fast[0], fast[1]), max(fast[2], fast[3]));
    for (int k = 0; k < kmax; k++) {
        uint2 ps[4]; float4 rv[4]; float wxe[4], wye[4];
#pragma unroll
        for (int i = 0; i < 4; i++) {
            bool act = (k < fast[i]);
            int ls = i * 16 + k;
            int sE = rdl(sL, ls);
            int rxE = rdl(rxL, ls);
            int ryE = act ? rdl(ryL, ls) : -1;
            wxe[i] = act ? rdlf(wxL, ls) : 0.f;
            wye[i] = act ? rdlf(wyL, ls) : 0.f;
            ps[i] = make_uint2(0u, 0u);
            rv[i] = make_float4(0.f, 0.f, 0.f, 0.f);
            if (fv) {
                ps[i] = *(const uint2*)(Pcat + (size_t)sE * LD1 + 200 + c4);
                rv[i] = *(const float4*)(R1i + (size_t)rxE * 200 + c4);
                if (ryE >= 0) {
                    float4 rb = *(const float4*)(R1i + (size_t)ryE * 200 + c4);
                    rv[i].x += rb.x; rv[i].y += rb.y; rv[i].z += rb.z; rv[i].w += rb.w;
                }
            }
        }
#pragma unroll
        for (int i = 0; i < 4; i++) {
            rsx[i] += wxe[i]; rsy[i] += wye[i];
            b[i][0] += wxe[i] * (bflo(ps[i].x) + rv[i].x);
            b[i][1] += wye[i] * (bfhi(ps[i].x) + rv[i].y);
            b[i][2] += wxe[i] * (bflo(ps[i].y) + rv[i].z);
            b[i][3] += wye[i] * (bfhi(ps[i].y) + rv[i].w);
        }
    }
    uint2 pt[4];
#pragma unroll
    for (int i = 0; i < 4; i++)
        pt[i] = fv ? *(const uint2*)(Pcat + (size_t)(n0 + i) * LD1 + c4) : make_uint2(0u, 0u);
#pragma unroll
    for (int i = 0; i < 4; i++) {
        unsigned short* xr = x + (size_t)(n0 + i) * KP2;
        if (fv) {
            if (deg[i] <= DTH) {
                float d0 = (rsx[i] == 0.f) ? 1e-12f : rsx[i];
                float d1 = (rsy[i] == 0.f) ? 1e-12f : rsy[i];
                float i0 = frcp(d0), i1 = frcp(d1);
                float v0 = (b[i][0] + rsx[i] * bflo(pt[i].x)) * i0;
                float v1 = (b[i][1] + rsy[i] * bfhi(pt[i].x)) * i1;
                float v2 = (b[i][2] + rsx[i] * bflo(pt[i].y)) * i0;
                float v3 = (b[i][3] + rsy[i] * bfhi(pt[i].y)) * i1;
                v0 = (v0 > 0.f) ? v0 : __expf(v0) - 1.f;
                v1 = (v1 > 0.f) ? v1 : __expf(v1) - 1.f;
                v2 = (v2 > 0.f) ? v2 : __expf(v2) - 1.f;
                v3 = (v3 > 0.f) ? v3 : __expf(v3) - 1.f;
                uint2 w;
                w.x = (uint32_t)f2bf(v0) | ((uint32_t)f2bf(v1) << 16);
                w.y = (uint32_t)f2bf(v2) | ((uint32_t)f2bf(v3) << 16);
                *(uint2*)(xr + c4) = w;
            }
        } else {
            *(uint2*)(xr + 200 + (lane - 50) * 4) = make_uint2(0u, 0u);
        }
    }
}

// ================= node layer-2 component (masked nodes) =================

static __device__ void d_node2_one(int node, int lane,
                        const int* __restrict__ rowptr, const int* __restrict__ srcs,
                        const int2* __restrict__ relpk,
                        const unsigned short* __restrict__ Qcat,
                        const unsigned short* __restrict__ Pcat,
                        const float* __restrict__ R2, const float* __restrict__ dR2,
                        const float* __restrict__ mask, float* __restrict__ out) {
    bool fv = (lane < 50);
    int c4 = lane * 4;
    int beg = rowptr[node], end = rowptr[node + 1];
    int deg = end - beg;
    int fast = (deg < 64) ? deg : 64;
    uint32_t tq = *(const uint32_t*)(Qcat + (size_t)node * LD2 + 400);
    float tdot = bflo(tq);
    int sL = 0, rxL = 0, ryL = -1;
    float WL = 0.f;
    if (lane < fast) {
        int p = beg + lane;
        sL = srcs[p];
        int2 rp = relpk[p];
        rxL = rp.x; ryL = rp.y;
        float dr = dR2[rp.x];
        if (rp.y >= 0) dr += dR2[rp.y];
        uint32_t sq = *(const uint32_t*)(Qcat + (size_t)sL * LD2 + 400);
        float pp = tdot + bfhi(sq) + dr;
        pp = (pp >= 0.f) ? pp : LRALPHA * pp;
        WL = __expf(-pp);
    }
    float c0 = 0.f, c1 = 0.f, c2 = 0.f, c3 = 0.f;
    float rs = 0.f;
    for (int j = 0; j < fast; j += 4) {
#pragma unroll
        for (int u = 0; u < 4; u++) {
            int jj = j + u;
            bool act = (jj < fast);
            int ls = act ? jj : 0;
            int sE = rdl(sL, ls);
            int rxE = rdl(rxL, ls);
            int ryE = act ? rdl(ryL, ls) : -1;
            float WE = act ? rdlf(WL, ls) : 0.f;
            uint2 qv = make_uint2(0u, 0u);
            float4 rv = make_float4(0.f, 0.f, 0.f, 0.f);
            if (fv) {
                qv = *(const uint2*)(Qcat + (size_t)sE * LD2 + 200 + c4);
                rv = *(const float4*)(R2 + (size_t)rxE * 200 + c4);
                if (ryE >= 0) {
                    float4 rb = *(const float4*)(R2 + (size_t)ryE * 200 + c4);
                    rv.x += rb.x; rv.y += rb.y; rv.z += rb.z; rv.w += rb.w;
                }
            }
            rs += WE;
            c0 += WE * (bflo(qv.x) + rv.x);
            c1 += WE * (bfhi(qv.x) + rv.y);
            c2 += WE * (bflo(qv.y) + rv.z);
            c3 += WE * (bfhi(qv.y) + rv.w);
        }
    }
    for (int p = beg + 64; p < end; p++) {
        int sE = srcs[p];
        int2 rp = relpk[p];
        float dr = dR2[rp.x];
        if (rp.y >= 0) dr += dR2[rp.y];
        uint32_t sq = *(const uint32_t*)(Qcat + (size_t)sE * LD2 + 400);
        float pp = tdot + bfhi(sq) + dr;
        pp = (pp >= 0.f) ? pp : LRALPHA * pp;
        float W = __expf(-pp);
        uint2 qv = make_uint2(0u, 0u);
        float4 rv = make_float4(0.f, 0.f, 0.f, 0.f);
        if (fv) {
            qv = *(const uint2*)(Qcat + (size_t)sE * LD2 + 200 + c4);
            rv = *(const float4*)(R2 + (size_t)rp.x * 200 + c4);
            if (rp.y >= 0) {
                float4 rb = *(const float4*)(R2 + (size_t)rp.y * 200 + c4);
                rv.x += rb.x; rv.y += rb.y; rv.z += rb.z; rv.w += rb.w;
            }
        }
        rs += W;
        c0 += W * (bflo(qv.x) + rv.x);
        c1 += W * (bfhi(qv.x) + rv.y);
        c2 += W * (bflo(qv.y) + rv.z);
        c3 += W * (bfhi(qv.y) + rv.w);
    }
    float d = (rs == 0.f) ? 1e-12f : rs;
    float idn = frcp(d);
    float mk = mask[node];
    float val0 = 0.f, val1 = 0.f, val2 = 0.f, val3 = 0.f;
    if (fv) {
        uint2 t = *(const uint2*)(Qcat + (size_t)node * LD2 + c4);
        uint2 e = *(const uint2*)(Pcat + (size_t)node * LD1 + 400 + c4);
        val0 = bflo(e.x) + mk * ((c0 + rs * bflo(t.x)) * idn);
        val1 = bfhi(e.x) + mk * ((c1 + rs * bfhi(t.x)) * idn);
        val2 = bflo(e.y) + mk * ((c2 + rs * bflo(t.y)) * idn);
        val3 = bfhi(e.y) + mk * ((c3 + rs * bfhi(t.y)) * idn);
    }
    float ss = val0 * val0 + val1 * val1 + val2 * val2 + val3 * val3;
#pragma unroll
    for (int o = 32; o > 0; o >>= 1) ss += __shfl_down(ss, o);
    ss = __shfl(ss, 0);
    float inv = frcp(fmaxf(sqrtf(ss), 1e-12f));
    if (fv) {
        *(float4*)(out + (size_t)node * 200 + c4) =
            make_float4(val0 * inv, val1 * inv, val2 * inv, val3 * inv);
    }
}

// ================= kernels =================

__global__ __launch_bounds__(256) void k_megaA(
        const int* __restrict__ tgt_el, const int* __restrict__ nhop, int* __restrict__ deg,
        const float* __restrict__ rel_emb, const float* __restrict__ att_a,
        float* __restrict__ R1i,
        const float* __restrict__ W_rel, float* __restrict__ outrel,
        const float* __restrict__ att_a2, const float* __restrict__ W_ent,
        unsigned short* __restrict__ W1,
        const float* __restrict__ out_a, const float* __restrict__ out_a2,
        unsigned short* __restrict__ W2,
        const int* __restrict__ batch, float* __restrict__ mask, float* __restrict__ oacc) {
    __shared__ __align__(16) char smem[8448];
    int bid = blockIdx.x, tid = threadIdx.x;
    if (bid < A_HIST) {
        d_hist(bid, tid, tgt_el, nhop, deg);
    } else if (bid < A_RELP) {
        d_relproj1(bid - A_HIST, tid, rel_emb, att_a, R1i);
    } else if (bid < A_MMW) {
        int i = bid - A_RELP;
        d_mm<false>(i & 3, i >> 2, smem, tid, rel_emb, 100, W_rel, 200, outrel, 200,
                    N_RELS, 200, 100);
    } else if (bid < A_PACK1) {
        d_pack1(bid - A_MMW, tid, att_a, att_a2, W_ent, W1);
    } else if (bid < A_PACK2) {
        d_pack2(bid - A_PACK1, tid, out_a, out_a2, W2);
    } else if (bid < A_MASK) {
        d_mask(bid - A_PACK2, tid, batch, mask);
    } else {
        d_ortho_part(bid - A_MASK, tid, att_a, out_a, oacc);
    }
}

// full scan (1 block) + dR1 + R2 GEMM
__global__ __launch_bounds__(256) void k_scanB(
        int* __restrict__ degcur, int* __restrict__ rowptr,
        const float* __restrict__ R1i, const float* __restrict__ att_a2,
        float* __restrict__ dR10, float* __restrict__ dR11,
        const float* __restrict__ outrel, const float* __restrict__ out_a,
        float* __restrict__ R2) {
    __shared__ __align__(16) char smem[8448];
    int bid = blockIdx.x, tid = threadIdx.x;
    if (bid == 0) {
        d_fullscan(tid, degcur, rowptr);
    } else if (bid < B_DR1) {
        d_dR1(bid - 1, tid, R1i, att_a2, dR10, dR11);
    } else {
        int i = bid - B_DR1;
        d_mm<true>(i & 3, i >> 2, smem, tid, outrel, 200, out_a + 400, 600, R2, 200,
                   N_RELS, 200, 200);
    }
}

__global__ __launch_bounds__(256) void k_megaC(
        const int* __restrict__ tgt_el, const int* __restrict__ src_el,
        const int* __restrict__ etype, const int* __restrict__ nhop, int* __restrict__ cursor,
        int* __restrict__ srcs, int2* __restrict__ relpk,
        const float* __restrict__ ent_emb, const unsigned short* __restrict__ Wcat1,
        unsigned short* __restrict__ Pcat,
        const int* __restrict__ rowptr, const float* __restrict__ mask,
        int* __restrict__ Hlist, int* __restrict__ Mlist, int* __restrict__ cnts,
        const float* __restrict__ R2, const float* __restrict__ out_a2,
        float* __restrict__ dR2,
        const float* __restrict__ oacc, float* __restrict__ oscalar,
        float* __restrict__ outbuf) {
    __shared__ __align__(16) char smem[33792];
    int bid = blockIdx.x, tid = threadIdx.x;
    if (bid < C_SCAT) {
        d_scatter(bid, tid, tgt_el, src_el, etype, nhop, cursor, srcs, relpk);
    } else if (bid < C_GEMM) {
        int i = bid - C_SCAT;
        d_gemm1f(i % 625, i / 625, smem, tid, ent_emb, Wcat1, Pcat, mask, outbuf);
    } else if (bid < C_CMP) {
        d_compact(bid - C_GEMM, tid, rowptr, mask, Hlist, Mlist, cnts);
    } else if (bid < C_DOTV) {
        int w = (bid - C_CMP) * 4 + (tid >> 6);
        int lane = tid & 63;
        if (w < N_RELS) {
            const float* r = R2 + (size_t)w * 200;
            float s = 0.f;
            for (int j = lane; j < 200; j += 64) s += r[j] * out_a2[j];
#pragma unroll
            for (int o = 32; o > 0; o >>= 1) s += __shfl_down(s, o);
            if (lane == 0) dR2[w] = s;
        }
    } else {
        d_ortho_fin(tid, oacc, oscalar);
    }
}

// NODE1: layer-1 main | layer-1 hub
__global__ __launch_bounds__(256, 4) void k_node1(
                        const int* __restrict__ rowptr, const int* __restrict__ srcs,
                        const int2* __restrict__ relpk,
                        const unsigned short* __restrict__ Pcat,
                        const float* __restrict__ R1i,
                        const float* __restrict__ dR10, const float* __restrict__ dR11,
                        unsigned short* __restrict__ x,
                        const int* __restrict__ Hlist, const int* __restrict__ cnts) {
    int bid = blockIdx.x, tid = threadIdx.x;
    int lane = tid & 63;
    if (bid < N1_MAIN) {
        int wid = __builtin_amdgcn_readfirstlane(bid * 4 + (tid >> 6));
        d_node1_main(wid, lane, rowptr, srcs, relpk, Pcat, R1i, dR10, dR11, x);
    } else {
        int hw = (bid - N1_MAIN) * 4 + (tid >> 6);
        int cnt = cnts[0];
        for (int j = hw; j < cnt; j += HUBW) {
            int node = __builtin_amdgcn_readfirstlane(Hlist[j]);
            d_node1_one(node, lane, rowptr, srcs, relpk, Pcat, R1i, dR10, dR11, x);
        }
    }
}

__global__ __launch_bounds__(256) void k_gemm2(const unsigned short* __restrict__ A,
                                               const unsigned short* __restrict__ B,
                                               unsigned short* __restrict__ C,
                                               int ldc, int N, int gPerSplit) {
    __shared__ __align__(16) char smem[8192];
    d_gemm<KP2>(blockIdx.x, blockIdx.y, smem, threadIdx.x, A, B, C, ldc, N, gPerSplit);
}

// node2 hub: full-wave aggregation + final fuse for masked nodes only
__global__ __launch_bounds__(256, 4) void k_node2h(
                        const int* __restrict__ rowptr, const int* __restrict__ srcs,
                        const int2* __restrict__ relpk,
                        const unsigned short* __restrict__ Qcat,
                        const unsigned short* __restrict__ Pcat,
                        const float* __restrict__ R2, const float* __restrict__ dR2,
                        const float* __restrict__ mask,
                        const int* __restrict__ Mlist, const int* __restrict__ cnts,
                        float* __restrict__ out) {
    int tid = threadIdx.x;
    int lane = tid & 63;
    int hw = blockIdx.x * 4 + (tid >> 6);
    int cnt = cnts[1];
    for (int j = hw; j < cnt; j += HUBW) {
        int node = __builtin_amdgcn_readfirstlane(Mlist[j]);
        d_node2_one(node, lane, rowptr, srcs, relpk, Qcat, Pcat, R2, dR2, mask, out);
    }
}

// ================= launch =================
extern "C" void kernel_launch(void* const* d_in, const int* in_sizes, int n_in,
                              void* d_out, int out_size, void* d_ws, size_t ws_size,
                              hipStream_t stream) {
    const int* edge_list = (const int*)d_in[0];
    const int* edge_type = (const int*)d_in[1];
    const int* batch     = (const int*)d_in[2];
    const int* nhop      = (const int*)d_in[3];
    const float* ent_emb = (const float*)d_in[4];
    const float* rel_emb = (const float*)d_in[5];
    const float* W_ent   = (const float*)d_in[6];
    const float* W_rel   = (const float*)d_in[7];
    const float* att_a   = (const float*)d_in[8];
    const float* att_a2  = (const float*)d_in[9];
    const float* out_a   = (const float*)d_in[10];
    const float* out_a2  = (const float*)d_in[11];
    float* out = (float*)d_out;
    const int* tgt_el = edge_list;
    const int* src_el = edge_list + E0;

    char* ws = (char*)d_ws;
    size_t o = 0;
    auto alloc = [&](size_t nbytes) -> char* {
        char* p = ws + o;
        o += (nbytes + 255) & ~(size_t)255;
        return p;
    };
    unsigned short* x_bf    = (unsigned short*)alloc((size_t)N_NODES * KP2 * 2);
    unsigned short* Pcat    = (unsigned short*)alloc((size_t)N_NODES * LD1 * 2);
    unsigned short* Qcat    = (unsigned short*)alloc((size_t)N_NODES * LD2 * 2);
    unsigned short* Wcat1   = (unsigned short*)alloc((size_t)NPAD1 * KP1 * 2);
    unsigned short* Wcat2   = (unsigned short*)alloc((size_t)NPAD2 * KP2 * 2);
    float* R1i   = (float*)alloc(474u * 200 * 4);
    float* R2    = (float*)alloc(474u * 200 * 4);
    float* dR10  = (float*)alloc(474u * 4);
    float* dR11  = (float*)alloc(474u * 4);
    float* dR2   = (float*)alloc(474u * 4);
    int* rowptr  = (int*)alloc((N_NODES + 1) * 4);
    int* cursor  = (int*)alloc(N_NODES * 4);
    int* srcs    = (int*)alloc((size_t)NE * 4);
    int2* relpk  = (int2*)alloc((size_t)NE * 8);
    float* mask  = (float*)alloc(N_NODES * 4);
    float* oacc  = (float*)alloc(9 * 4);
    int* Hlist   = (int*)alloc(N_NODES * 4);
    int* Mlist   = (int*)alloc(N_NODES * 4);
    int* cnts    = (int*)alloc(2 * 4);

    hipMemsetAsync(cursor, 0, N_NODES * 4, stream);
    hipMemsetAsync(mask, 0, N_NODES * 4, stream);
    hipMemsetAsync(oacc, 0, 9 * 4, stream);
    hipMemsetAsync(cnts, 0, 2 * 4, stream);

    // 1) hist + relproj1 + out_relation GEMM + pack1 + pack2 + mask + ortho partials
    k_megaA<<<A_TOT, 256, 0, stream>>>(tgt_el, nhop, cursor,
                                       rel_emb, att_a, R1i,
                                       W_rel, out + 8000000,
                                       att_a2, W_ent, Wcat1,
                                       out_a, out_a2, Wcat2,
                                       batch, mask, oacc);
    // 2) full CSR scan (1 block) + dR1 + R2 GEMM
    k_scanB<<<B_TOT, 256, 0, stream>>>(cursor, rowptr, R1i, att_a2, dR10, dR11,
                                       out + 8000000, out_a, R2);
    // 3) scatter + layer-1 GEMM (fused l2norm + unmasked out-write) + compact + dotv + ortho fin
    k_megaC<<<C_TOT, 256, 0, stream>>>(tgt_el, src_el, edge_type, nhop, cursor,
                                       srcs, relpk, ent_emb, Wcat1, Pcat,
                                       rowptr, mask, Hlist, Mlist, cnts,
                                       R2, out_a2, dR2, oacc, out + 8094800, out);
    // 4) layer-1 aggregation (main + hub)
    k_node1<<<N1_TOT, 256, 0, stream>>>(rowptr, srcs, relpk, Pcat, R1i, dR10, dR11,
                                        x_bf, Hlist, cnts);
    // 5) layer-2 GEMM
    k_gemm2<<<dim3(625, 2), 256, 0, stream>>>(x_bf, Wcat2, Qcat, LD2, 416, 4);
    // 6) layer-2 masked-node aggregation + final fuse
    k_node2h<<<512, 256, 0, stream>>>(rowptr, srcs, relpk, Qcat, Pcat, R2, dR2,
                                      mask, Mlist, cnts, out);
}

// Round 10
// 322.956 us; speedup vs baseline: 1.0724x; 1.0724x over previous
//
#include <hip/hip_runtime.h>
#include <cstdint>
#include <cstddef>
#include <math.h>

#define N_NODES 40000
#define N_RELS  474
#define E0      100000
#define NE      130000
#define NB      8192
#define LRALPHA 0.2f

#define KP1 128
#define KP2 256
// Pcat cols: [0:200) Pt interleaved | [200:400) Ps interleaved | [400:600) entW | [600:604) dots | pad
#define LD1 608
// Qcat cols: [0:200) Qt | [200:400) Qs | 400 dqt | 401 dqs | pad
#define LD2 416
#define NPAD1 640
#define NPAD2 448
#define DTH 16
#define HUBW 2048

// MEGA-A block ranges (raw-input-only regions)
#define A_HIST   508
#define A_RELP   (A_HIST + 119)
#define A_MMW    (A_RELP + 32)
#define A_PACK1  (A_MMW + 320)
#define A_PACK2  (A_PACK1 + 448)
#define A_MASK   (A_PACK2 + 32)
#define A_TOT    (A_MASK + 128)
// MEGA-B: scan2 (1) | gemm1f (1250) | dR1 (119) | R2 GEMM (32)
#define B_G1F    1
#define B_DR1    (B_G1F + 1250)
#define B_R2     (B_DR1 + 119)
#define B_TOT    (B_R2 + 32)
// SCAN3D: scan3 (157) | dotv (119)
#define S3_DOTV  157
#define S3_TOT   (S3_DOTV + 119)
// MEGA-C: scatter | compact | ortho_fin
#define C_CMP    508
#define C_OFIN   (C_CMP + 157)
#define C_TOT    (C_OFIN + 1)
// NODE1: layer-1 main interleave | layer-1 hub
#define N1_MAIN  2500
#define N1_TOT   (N1_MAIN + 512)

typedef __attribute__((ext_vector_type(8))) short short8;
typedef __attribute__((ext_vector_type(4))) float floatx4;

static __device__ __forceinline__ unsigned short f2bf(float f) {
    union { float f; uint32_t u; } v; v.f = f;
    uint32_t r = v.u + 0x7fff + ((v.u >> 16) & 1);
    return (unsigned short)(r >> 16);
}
static __device__ __forceinline__ float bf2f(unsigned short h) {
    union { uint32_t u; float f; } v; v.u = ((uint32_t)h) << 16;
    return v.f;
}
static __device__ __forceinline__ float bflo(uint32_t u) { return bf2f((unsigned short)(u & 0xffff)); }
static __device__ __forceinline__ float bfhi(uint32_t u) { return bf2f((unsigned short)(u >> 16)); }

static __device__ __forceinline__ int rdl(int v, int l) {
    return __builtin_amdgcn_readlane(v, l);
}
static __device__ __forceinline__ float rdlf(float v, int l) {
    return __int_as_float(__builtin_amdgcn_readlane(__float_as_int(v), l));
}
static __device__ __forceinline__ float frcp(float x) { return __builtin_amdgcn_rcpf(x); }

// ================= device components =================

static __device__ void d_hist(int bid, int tid, const int* __restrict__ tgt_el,
                              const int* __restrict__ nhop, int* __restrict__ deg) {
    int e = bid * 256 + tid;
    if (e >= NE) return;
    int t = (e < E0) ? tgt_el[e] : nhop[(size_t)(e - E0) * 4 + 3];
    atomicAdd(&deg[t], 1);
}

static __device__ void d_mask(int bid, int tid, const int* __restrict__ batch,
                              float* __restrict__ mask) {
    int i = bid * 256 + tid;
    if (i < NB) mask[batch[(size_t)i * 3 + 2]] = 1.0f;
}

static __device__ void d_ortho_part(int bid, int tid, const float* __restrict__ att_a,
                                    const float* __restrict__ out_a, float* __restrict__ accum) {
    float loc[9] = {0,0,0,0,0,0,0,0,0};
    for (int i = bid * 256 + tid; i < 90000; i += 128 * 256) {
        int seg, li;
        const float* base;
        int L;
        if (i < 15000)      { seg = 0; li = i;          base = att_a;         L = 15000; }
        else if (i < 30000) { seg = 1; li = i - 15000;  base = att_a + 30000; L = 15000; }
        else                { seg = 2; li = i - 30000;  base = out_a;         L = 60000; }
        float a = base[li], b = base[L + li];
        loc[seg * 3 + 0] += a * a;
        loc[seg * 3 + 1] += b * b;
        loc[seg * 3 + 2] += a * b;
    }
    int lane = tid & 63;
#pragma unroll
    for (int q = 0; q < 9; q++) {
        float s = loc[q];
#pragma unroll
        for (int o = 32; o > 0; o >>= 1) s += __shfl_down(s, o);
        if (lane == 0 && s != 0.f) atomicAdd(&accum[q], s);
    }
}

static __device__ void d_scan2(int tid, int* wtot, int* __restrict__ bsums, int nb) {
    int v = (tid < nb) ? bsums[tid] : 0;
    int lane = tid & 63, wv = tid >> 6;
    int x = v;
#pragma unroll
    for (int o = 1; o < 64; o <<= 1) {
        int t = __shfl_up(x, o);
        if (lane >= o) x += t;
    }
    if (lane == 63) wtot[wv] = x;
    __syncthreads();
    int add = 0;
    for (int k = 0; k < wv; k++) add += wtot[k];
    __syncthreads();
    if (tid < nb) bsums[tid] = add + x - v;
    if (tid == 255) bsums[nb] = add + x;
}

// ---- pack layer-1 B matrix (uvec rows computed inline) ----
static __device__ void d_pack1(int bid, int tid, const float* __restrict__ att_a,
                               const float* __restrict__ att_a2,
                               const float* __restrict__ W_ent,
                               unsigned short* __restrict__ W) {
    int idx = bid * 256 + tid;
    if (idx >= NPAD1 * KP1) return;
    int j = idx & 7;
    int lane = (idx >> 3) & 63;
    int u = idx >> 9;
    int ks = u & 3;
    int t = u >> 2;
    int r = t * 16 + (lane & 15);
    int k = ks * 32 + (lane >> 4) * 8 + j;
    float val = 0.f;
    if (k < 100) {
        if (r < 200) {
            int i = r >> 1, h = r & 1;
            val = att_a[h * 30000 + i * 300 + k];
        } else if (r < 400) {
            int rr = r - 200, i = rr >> 1, h = rr & 1;
            val = att_a[h * 30000 + i * 300 + 100 + k];
        } else if (r < 600) {
            val = W_ent[k * 200 + (r - 400)];
        } else if (r < 604) {
            int v = r - 600, head = v >> 1, part = v & 1;
            const float* base = att_a + head * 30000 + part * 100 + k;
            const float* a2v = att_a2 + head * 100;
            float s = 0.f;
            for (int n = 0; n < 100; n++) s += a2v[n] * base[n * 300];
            val = s;
        }
    }
    W[idx] = f2bf(val);
}

// ---- pack layer-2 B matrix (uvec rows computed inline) ----
static __device__ void d_pack2(int bid, int tid, const float* __restrict__ out_a,
                               const float* __restrict__ out_a2,
                               unsigned short* __restrict__ W) {
    int idx = bid * 256 + tid;
    if (idx >= NPAD2 * KP2) return;
    int j = idx & 7;
    int lane = (idx >> 3) & 63;
    int u = idx >> 9;
    int ks = u & 7;
    int t = u >> 3;
    int r = t * 16 + (lane & 15);
    int k = ks * 32 + (lane >> 4) * 8 + j;
    float val = 0.f;
    if (k < 200) {
        int klog = (k & 1) * 100 + (k >> 1);
        if (r < 200)       val = out_a[r * 600 + klog];
        else if (r < 400)  val = out_a[(r - 200) * 600 + 200 + klog];
        else if (r == 400) {
            float s = 0.f;
            for (int n = 0; n < 200; n++) s += out_a2[n] * out_a[n * 600 + klog];
            val = s;
        } else if (r == 401) {
            float s = 0.f;
            for (int n = 0; n < 200; n++) s += out_a2[n] * out_a[n * 600 + 200 + klog];
            val = s;
        }
    }
    W[idx] = f2bf(val);
}

static __device__ void d_scatter(int bid, int tid, const int* __restrict__ tgt_el,
                                 const int* __restrict__ src_el, const int* __restrict__ etype,
                                 const int* __restrict__ nhop, int* __restrict__ cursor,
                                 int* __restrict__ srcs, int2* __restrict__ relpk) {
    int e = bid * 256 + tid;
    if (e >= NE) return;
    int t, s, r1, r2;
    if (e < E0) {
        t = tgt_el[e]; s = src_el[e]; r1 = etype[e]; r2 = -1;
    } else {
        const int* nh = nhop + (size_t)(e - E0) * 4;
        t = nh[3]; s = nh[0]; r1 = nh[1]; r2 = nh[2];
    }
    int p = atomicAdd(&cursor[t], 1);
    srcs[p] = s;
    relpk[p] = make_int2(r1, r2);
}

static __device__ void d_compact(int bid, int tid, const int* __restrict__ rowptr,
                                 const float* __restrict__ mask,
                                 int* __restrict__ Hlist, int* __restrict__ Mlist,
                                 int* __restrict__ cnts) {
    int i = bid * 256 + tid;
    if (i >= N_NODES) return;
    int deg = rowptr[i + 1] - rowptr[i];
    if (deg > DTH) { int p = atomicAdd(&cnts[0], 1); Hlist[p] = i; }
    if (mask[i] != 0.f) { int p = atomicAdd(&cnts[1], 1); Mlist[p] = i; }
}

// ---- bf16 MFMA GEMM (fragment-ordered B) — layer-2 ----
template <int KP>
static __device__ void d_gemm(int bx, int by, char* smem_raw, int tid,
                              const unsigned short* __restrict__ A,
                              const unsigned short* __restrict__ B,
                              unsigned short* __restrict__ C,
                              int ldc, int N, int gPerSplit) {
    constexpr int KSTEPS = KP / 32;
    constexpr int KCH = KSTEPS / 4;
    unsigned short (*cbuf)[16][64] = (unsigned short (*)[16][64])smem_raw;
    int wave = tid >> 6;
    int lane = tid & 63;
    int quad = lane >> 4;
    int l16 = lane & 15;
    int m0 = bx * 64 + wave * 16;
    short8 afrag[KSTEPS];
    const unsigned short* arow = A + (size_t)(m0 + l16) * KP + quad * 8;
#pragma unroll
    for (int ks = 0; ks < KSTEPS; ks++)
        afrag[ks] = *(const short8*)(arow + ks * 32);

    int Gtot = (N + 63) >> 6;
    int g0 = by * gPerSplit;
    int g1 = g0 + gPerSplit;
    if (g1 > Gtot) g1 = Gtot;
    for (int g = g0; g < g1; g++) {
        int nb = g << 6;
        const unsigned short* bgrp = B + (((size_t)(g << 2) * KSTEPS) << 9) + (lane << 3);
        floatx4 acc[4];
#pragma unroll
        for (int t = 0; t < 4; t++) acc[t] = (floatx4){0.f, 0.f, 0.f, 0.f};
#pragma unroll
        for (int ch = 0; ch < KCH; ch++) {
            short8 bf[4][4];
#pragma unroll
            for (int t = 0; t < 4; t++)
#pragma unroll
                for (int k = 0; k < 4; k++)
                    bf[t][k] = *(const short8*)(bgrp + ((size_t)(t * KSTEPS + ch * 4 + k) << 9));
#pragma unroll
            for (int k = 0; k < 4; k++)
#pragma unroll
                for (int t = 0; t < 4; t++)
                    acc[t] = __builtin_amdgcn_mfma_f32_16x16x32_bf16(afrag[ch * 4 + k], bf[t][k], acc[t], 0, 0, 0);
        }
        int r0 = quad * 4;
#pragma unroll
        for (int t = 0; t < 4; t++)
#pragma unroll
            for (int i = 0; i < 4; i++)
                cbuf[wave][r0 + i][t * 16 + l16] = f2bf(acc[t][i]);
        int colsA = N - nb; if (colsA > 64) colsA = 64;
        int cols8 = colsA >> 3;
        int sh = (colsA >= 64) ? 3 : 2;
        int nchunks = cols8 << 4;
        for (int c = lane; c < nchunks; c += 64) {
            int row = c >> sh;
            int col8 = (c & (cols8 - 1)) << 3;
            *(uint4*)(C + (size_t)(m0 + row) * ldc + nb + col8) =
                *(const uint4*)&cbuf[wave][row][col8];
        }
    }
}

// ---- layer-1 GEMM: fused row-l2norm (raw fp32 in) + fused unmasked out-write (by==1) ----
static __device__ void d_gemm1f(int bx, int by, char* smem_raw, int tid,
                                const float* __restrict__ ent,
                                const unsigned short* __restrict__ B,
                                unsigned short* __restrict__ C,
                                const float* __restrict__ mask,
                                float* __restrict__ out) {
    float (*rows)[105] = (float (*)[105])smem_raw;              // 26880 B (consumed pre-loop)
    float* invn = (float*)(smem_raw + 64 * 105 * 4);            // +256 B  (consumed pre-loop)
    unsigned short (*entw)[200] = (unsigned short (*)[200])(smem_raw + 8192);  // 25600 B
    int m0 = bx * 64;
    for (int idx = tid; idx < 6400; idx += 256) {
        int r = idx / 100, c = idx - r * 100;
        rows[r][c] = ent[(size_t)(m0 + r) * 100 + c];
    }
    __syncthreads();
    {
        int r = tid >> 2, q = tid & 3;
        const float* rp = rows[r] + q * 25;
        float s = 0.f;
#pragma unroll
        for (int c = 0; c < 25; c++) { float v = rp[c]; s += v * v; }
        s += __shfl_xor(s, 1);
        s += __shfl_xor(s, 2);
        if (q == 0) invn[r] = 1.f / fmaxf(sqrtf(s), 1e-12f);
    }
    __syncthreads();
    int wave = tid >> 6;
    int lane = tid & 63;
    int quad = lane >> 4;
    int l16 = lane & 15;
    int rr = wave * 16 + l16;
    float inv = invn[rr];
    short8 afrag[4];
#pragma unroll
    for (int ks = 0; ks < 4; ks++) {
        short8 f;
#pragma unroll
        for (int j = 0; j < 8; j++) {
            int col = ks * 32 + quad * 8 + j;
            f[j] = (col < 100) ? (short)f2bf(rows[rr][col] * inv) : (short)0;
        }
        afrag[ks] = f;
    }
    __syncthreads();   // rows region reused as cbuf below
    unsigned short (*cbuf)[16][64] = (unsigned short (*)[16][64])smem_raw;
    int mo0 = m0 + wave * 16;
    int g0 = by * 5, g1 = g0 + 5;
    if (g1 > 10) g1 = 10;
    for (int g = g0; g < g1; g++) {
        int nb = g << 6;
        const unsigned short* bgrp = B + (((size_t)(g << 2) * 4) << 9) + (lane << 3);
        floatx4 acc[4];
#pragma unroll
        for (int t = 0; t < 4; t++) acc[t] = (floatx4){0.f, 0.f, 0.f, 0.f};
        short8 bf[4][4];
#pragma unroll
        for (int t = 0; t < 4; t++)
#pragma unroll
            for (int k = 0; k < 4; k++)
                bf[t][k] = *(const short8*)(bgrp + ((size_t)(t * 4 + k) << 9));
#pragma unroll
        for (int k = 0; k < 4; k++)
#pragma unroll
            for (int t = 0; t < 4; t++)
                acc[t] = __builtin_amdgcn_mfma_f32_16x16x32_bf16(afrag[k], bf[t][k], acc[t], 0, 0, 0);
        int r0 = quad * 4;
#pragma unroll
        for (int t = 0; t < 4; t++)
#pragma unroll
            for (int i = 0; i < 4; i++)
                cbuf[wave][r0 + i][t * 16 + l16] = f2bf(acc[t][i]);
        int colsA = 608 - nb; if (colsA > 64) colsA = 64;
        int cols8 = colsA >> 3;
        int sh = (colsA >= 64) ? 3 : 2;
        int nchunks = cols8 << 4;
        for (int c = lane; c < nchunks; c += 64) {
            int row = c >> sh;
            int col8 = (c & (cols8 - 1)) << 3;
            *(uint4*)(C + (size_t)(mo0 + row) * LD1 + nb + col8) =
                *(const uint4*)&cbuf[wave][row][col8];
        }
        // keep entW window (cols [400,600)) for fused out-write
        if (by == 1) {
            int cg = nb + lane;
            if (cg >= 400 && cg < 600) {
#pragma unroll
                for (int i = 0; i < 16; i++)
                    entw[wave * 16 + i][cg - 400] = cbuf[wave][i][lane];
            }
        }
    }
    // fused layer-2 unmasked streaming output: out[node] = l2norm(entW row)
    if (by == 1) {
        bool fv = (lane < 50);
        int c4 = lane * 4;
        for (int i = 0; i < 16; i++) {
            int row = wave * 16 + i;
            int node = m0 + row;
            float mk = mask[node];
            if (mk != 0.f) continue;    // masked nodes written by node2h
            float v0 = 0.f, v1 = 0.f, v2 = 0.f, v3 = 0.f;
            if (fv) {
                v0 = bf2f(entw[row][c4 + 0]);
                v1 = bf2f(entw[row][c4 + 1]);
                v2 = bf2f(entw[row][c4 + 2]);
                v3 = bf2f(entw[row][c4 + 3]);
            }
            float ss = v0 * v0 + v1 * v1 + v2 * v2 + v3 * v3;
#pragma unroll
            for (int o = 32; o > 0; o >>= 1) ss += __shfl_down(ss, o);
            ss = __shfl(ss, 0);
            float iv = frcp(fmaxf(sqrtf(ss), 1e-12f));
            if (fv) {
                *(float4*)(out + (size_t)node * 200 + c4) =
                    make_float4(v0 * iv, v1 * iv, v2 * iv, v3 * iv);
            }
        }
    }
}

// ---- generic tiled fp32 matmul (474-row cases) ----
template <bool BT>
static __device__ void d_mm(int bx, int by, char* smem_raw, int tid,
                            const float* __restrict__ A, int lda,
                            const float* __restrict__ B, int ldb,
                            float* __restrict__ C, int ldc,
                            int M, int N, int K) {
    float (*As)[65] = (float (*)[65])smem_raw;
    float (*Bs)[65] = (float (*)[65])(smem_raw + 16 * 65 * 4);
    int tx = tid & 15, ty = tid >> 4;
    int m0 = by * 64, n0 = bx * 64;
    float acc[4][4] = {};
    for (int k0 = 0; k0 < K; k0 += 16) {
        {
            int r = tid >> 2;
            int c4 = (tid & 3) * 4;
            int m = m0 + r;
#pragma unroll
            for (int u = 0; u < 4; u++) {
                int k = k0 + c4 + u;
                As[c4 + u][r] = (m < M && k < K) ? A[(size_t)m * lda + k] : 0.f;
            }
        }
        if (BT) {
            int r = tid >> 2;
            int c4 = (tid & 3) * 4;
            int n = n0 + r;
#pragma unroll
            for (int u = 0; u < 4; u++) {
                int k = k0 + c4 + u;
                Bs[c4 + u][r] = (n < N && k < K) ? B[(size_t)n * ldb + k] : 0.f;
            }
        } else {
            int kk = tid >> 4;
            int nn4 = (tid & 15) * 4;
            int k = k0 + kk;
#pragma unroll
            for (int u = 0; u < 4; u++) {
                int n = n0 + nn4 + u;
                Bs[kk][nn4 + u] = (k < K && n < N) ? B[(size_t)k * ldb + n] : 0.f;
            }
        }
        __syncthreads();
#pragma unroll
        for (int k = 0; k < 16; k++) {
            float a[4], b[4];
#pragma unroll
            for (int i = 0; i < 4; i++) a[i] = As[k][ty + 16 * i];
#pragma unroll
            for (int j = 0; j < 4; j++) b[j] = Bs[k][tx + 16 * j];
#pragma unroll
            for (int i = 0; i < 4; i++)
#pragma unroll
                for (int j = 0; j < 4; j++) acc[i][j] += a[i] * b[j];
        }
        __syncthreads();
    }
#pragma unroll
    for (int i = 0; i < 4; i++) {
        int m = m0 + ty + 16 * i;
        if (m >= M) continue;
#pragma unroll
        for (int j = 0; j < 4; j++) {
            int n = n0 + tx + 16 * j;
            if (n < N) C[(size_t)m * ldc + n] = acc[i][j];
        }
    }
}

static __device__ void d_relproj1(int bid, int tid, const float* __restrict__ rel_emb,
                                  const float* __restrict__ att_a, float* __restrict__ R1i) {
    int w = (bid * 256 + tid) >> 6;
    int lane = tid & 63;
    if (w >= N_RELS) return;
    const float* re = rel_emb + (size_t)w * 100;
    float2* dst = (float2*)(R1i + (size_t)w * 200);
    for (int f = lane; f < 100; f += 64) {
        const float* a0 = att_a + f * 300 + 200;
        const float* a1 = att_a + 30000 + f * 300 + 200;
        float s0 = 0.f, s1 = 0.f;
        for (int k = 0; k < 100; k++) {
            float rk = re[k];
            s0 += rk * a0[k];
            s1 += rk * a1[k];
        }
        dst[f] = make_float2(s0, s1);
    }
}

static __device__ void d_dR1(int bid, int tid, const float* __restrict__ R1i,
                             const float* __restrict__ att_a2,
                             float* __restrict__ dR10, float* __restrict__ dR11) {
    int w = (bid * 256 + tid) >> 6;
    int lane = tid & 63;
    if (w >= N_RELS) return;
    const float2* row = (const float2*)(R1i + (size_t)w * 200);
    float s0 = 0.f, s1 = 0.f;
    for (int f = lane; f < 100; f += 64) {
        float2 v = row[f];
        s0 += v.x * att_a2[f];
        s1 += v.y * att_a2[100 + f];
    }
#pragma unroll
    for (int o = 32; o > 0; o >>= 1) {
        s0 += __shfl_down(s0, o);
        s1 += __shfl_down(s1, o);
    }
    if (lane == 0) { dR10[w] = s0; dR11[w] = s1; }
}

static __device__ void d_ortho_fin(int tid, const float* __restrict__ accum,
                                   float* __restrict__ out_scalar) {
    if (tid != 0) return;
    float total = 0.f;
#pragma unroll
    for (int m = 0; m < 3; m++) {
        float s0 = accum[m * 3 + 0], s1 = accum[m * 3 + 1], sc = accum[m * 3 + 2];
        float c = sc / (fmaxf(sqrtf(s0), 1e-12f) * fmaxf(sqrtf(s1), 1e-12f));
        total += 0.01f * 2.f * c * c;
    }
    out_scalar[0] = total;
}

// ================= node layer-1 components =================

static __device__ void d_node1_one(int node, int lane,
                        const int* __restrict__ rowptr, const int* __restrict__ srcs,
                        const int2* __restrict__ relpk,
                        const unsigned short* __restrict__ Pcat,
                        const float* __restrict__ R1i,
                        const float* __restrict__ dR10, const float* __restrict__ dR11,
                        unsigned short* __restrict__ x) {
    bool fv = (lane < 50);
    int c4 = lane * 4;
    int beg = rowptr[node], end = rowptr[node + 1];
    int deg = end - beg;
    int fast = (deg < 64) ? deg : 64;
    uint2 td = *(const uint2*)(Pcat + (size_t)node * LD1 + 600);
    float t0h = bflo(td.x), t1h = bflo(td.y);
    int sL = 0, rxL = 0, ryL = -1;
    float wxL = 0.f, wyL = 0.f;
    if (lane < fast) {
        int p = beg + lane;
        sL = srcs[p];
        int2 rp = relpk[p];
        rxL = rp.x; ryL = rp.y;
        float dr0 = dR10[rp.x], dr1 = dR11[rp.x];
        if (rp.y >= 0) { dr0 += dR10[rp.y]; dr1 += dR11[rp.y]; }
        uint2 sd = *(const uint2*)(Pcat + (size_t)sL * LD1 + 600);
        float p0 = t0h + bfhi(sd.x) + dr0;
        float p1 = t1h + bfhi(sd.y) + dr1;
        p0 = (p0 >= 0.f) ? p0 : LRALPHA * p0;
        p1 = (p1 >= 0.f) ? p1 : LRALPHA * p1;
        wxL = __expf(-p0);
        wyL = __expf(-p1);
    }
    float b0 = 0.f, b1 = 0.f, b2 = 0.f, b3 = 0.f;
    float rs0 = 0.f, rs1 = 0.f;
    for (int j = 0; j < fast; j += 4) {
#pragma unroll
        for (int u = 0; u < 4; u++) {
            int jj = j + u;
            bool act = (jj < fast);
            int ls = act ? jj : 0;
            int sE = rdl(sL, ls);
            int rxE = rdl(rxL, ls);
            int ryE = act ? rdl(ryL, ls) : -1;
            float wxE = act ? rdlf(wxL, ls) : 0.f;
            float wyE = act ? rdlf(wyL, ls) : 0.f;
            uint2 ps = make_uint2(0u, 0u);
            float4 rv = make_float4(0.f, 0.f, 0.f, 0.f);
            if (fv) {
                ps = *(const uint2*)(Pcat + (size_t)sE * LD1 + 200 + c4);
                rv = *(const float4*)(R1i + (size_t)rxE * 200 + c4);
                if (ryE >= 0) {
                    float4 rb = *(const float4*)(R1i + (size_t)ryE * 200 + c4);
                    rv.x += rb.x; rv.y += rb.y; rv.z += rb.z; rv.w += rb.w;
                }
            }
            rs0 += wxE; rs1 += wyE;
            b0 += wxE * (bflo(ps.x) + rv.x);
            b1 += wyE * (bfhi(ps.x) + rv.y);
            b2 += wxE * (bflo(ps.y) + rv.z);
            b3 += wyE * (bfhi(ps.y) + rv.w);
        }
    }
    for (int p = beg + 64; p < end; p++) {
        int sE = srcs[p];
        int2 rp = relpk[p];
        float dr0 = dR10[rp.x], dr1 = dR11[rp.x];
        if (rp.y >= 0) { dr0 += dR10[rp.y]; dr1 += dR11[rp.y]; }
        uint2 sd = *(const uint2*)(Pcat + (size_t)sE * LD1 + 600);
        float p0 = t0h + bfhi(sd.x) + dr0;
        float p1 = t1h + bfhi(sd.y) + dr1;
        p0 = (p0 >= 0.f) ? p0 : LRALPHA * p0;
        p1 = (p1 >= 0.f) ? p1 : LRALPHA * p1;
        float wx = __expf(-p0), wy = __expf(-p1);
        uint2 ps = make_uint2(0u, 0u);
        float4 rv = make_float4(0.f, 0.f, 0.f, 0.f);
        if (fv) {
            ps = *(const uint2*)(Pcat + (size_t)sE * LD1 + 200 + c4);
            rv = *(const float4*)(R1i + (size_t)rp.x * 200 + c4);
            if (rp.y >= 0) {
                float4 rb = *(const float4*)(R1i + (size_t)rp.y * 200 + c4);
                rv.x += rb.x; rv.y += rb.y; rv.z += rb.z; rv.w += rb.w;
            }
        }
        rs0 += wx; rs1 += wy;
        b0 += wx * (bflo(ps.x) + rv.x);
        b1 += wy * (bfhi(ps.x) + rv.y);
        b2 += wx * (bflo(ps.y) + rv.z);
        b3 += wy * (bfhi(ps.y) + rv.w);
    }
    float d0 = (rs0 == 0.f) ? 1e-12f : rs0;
    float d1 = (rs1 == 0.f) ? 1e-12f : rs1;
    float i0 = frcp(d0), i1 = frcp(d1);
    if (fv) {
        uint2 pt = *(const uint2*)(Pcat + (size_t)node * LD1 + c4);
        float v0 = (b0 + rs0 * bflo(pt.x)) * i0;
        float v1 = (b1 + rs1 * bfhi(pt.x)) * i1;
        float v2 = (b2 + rs0 * bflo(pt.y)) * i0;
        float v3 = (b3 + rs1 * bfhi(pt.y)) * i1;
        v0 = (v0 > 0.f) ? v0 : __expf(v0) - 1.f;
        v1 = (v1 > 0.f) ? v1 : __expf(v1) - 1.f;
        v2 = (v2 > 0.f) ? v2 : __expf(v2) - 1.f;
        v3 = (v3 > 0.f) ? v3 : __expf(v3) - 1.f;
        uint2 w;
        w.x = (uint32_t)f2bf(v0) | ((uint32_t)f2bf(v1) << 16);
        w.y = (uint32_t)f2bf(v2) | ((uint32_t)f2bf(v3) << 16);
        unsigned short* xr = x + (size_t)node * KP2;
        *(uint2*)(xr + c4) = w;
    }
}

static __device__ void d_node1_main(int wid, int lane,
                        const int* __restrict__ rowptr, const int* __restrict__ srcs,
                        const int2* __restrict__ relpk,
                        const unsigned short* __restrict__ Pcat,
                        const float* __restrict__ R1i,
                        const float* __restrict__ dR10, const float* __restrict__ dR11,
                        unsigned short* __restrict__ x) {
    int n0 = wid * 4;
    if (n0 >= N_NODES) return;
    bool fv = (lane < 50);
    int c4 = lane * 4;
    int rp = (lane < 5) ? rowptr[n0 + lane] : 0;
    int bnd0 = rdl(rp, 0), bnd1 = rdl(rp, 1), bnd2 = rdl(rp, 2), bnd3 = rdl(rp, 3), bnd4 = rdl(rp, 4);
    int beg[4] = {bnd0, bnd1, bnd2, bnd3};
    int end[4] = {bnd1, bnd2, bnd3, bnd4};
    int deg[4], fast[4];
#pragma unroll
    for (int i = 0; i < 4; i++) {
        deg[i] = end[i] - beg[i];
        fast[i] = (deg[i] <= DTH) ? deg[i] : 0;
    }
    int li = lane >> 4, lk = lane & 15;
    int begL = (li == 0) ? bnd0 : (li == 1) ? bnd1 : (li == 2) ? bnd2 : bnd3;
    int endL = (li == 0) ? bnd1 : (li == 1) ? bnd2 : (li == 2) ? bnd3 : bnd4;
    int degL = endL - begL;
    int fastL = (degL <= DTH) ? degL : 0;
    uint2 tdL = *(const uint2*)(Pcat + (size_t)(n0 + li) * LD1 + 600);
    float t0L = bflo(tdL.x), t1L = bflo(tdL.y);
    int sL = 0, rxL = 0, ryL = -1;
    float wxL = 0.f, wyL = 0.f;
    if (lk < fastL) {
        int p = begL + lk;
        sL = srcs[p];
        int2 rq = relpk[p];
        rxL = rq.x; ryL = rq.y;
        float dr0 = dR10[rq.x], dr1 = dR11[rq.x];
        if (rq.y >= 0) { dr0 += dR10[rq.y]; dr1 += dR11[rq.y]; }
        uint2 sd = *(const uint2*)(Pcat + (size_t)sL * LD1 + 600);
        float p0 = t0L + bfhi(sd.x) + dr0;
        float p1 = t1L + bfhi(sd.y) + dr1;
        p0 = (p0 >= 0.f) ? p0 : LRALPHA * p0;
        p1 = (p1 >= 0.f) ? p1 : LRALPHA * p1;
        wxL = __expf(-p0);
        wyL = __expf(-p1);
    }
    float b[4][4] = {};
    float rsx[4] = {0.f, 0.f, 0.f, 0.f}, rsy[4] = {0.f, 0.f, 0.f, 0.f};
    int kmax = max(max(fast[0], fast[1]), max(fast[2], fast[3]));
    for (int k = 0; k < kmax; k++) {
        uint2 ps[4]; float4 rv[4]; float wxe[4], wye[4];
#pragma unroll
        for (int i = 0; i < 4; i++) {
            bool act = (k < fast[i]);
            int ls = i * 16 + k;
            int sE = rdl(sL, ls);
            int rxE = rdl(rxL, ls);
            int ryE = act ? rdl(ryL, ls) : -1;
            wxe[i] = act ? rdlf(wxL, ls) : 0.f;
            wye[i] = act ? rdlf(wyL, ls) : 0.f;
            ps[i] = make_uint2(0u, 0u);
            rv[i] = make_float4(0.f, 0.f, 0.f, 0.f);
            if (fv) {
                ps[i] = *(const uint2*)(Pcat + (size_t)sE * LD1 + 200 + c4);
                rv[i] = *(const float4*)(R1i + (size_t)rxE * 200 + c4);
                if (ryE >= 0) {
                    float4 rb = *(const float4*)(R1i + (size_t)ryE * 200 + c4);
                    rv[i].x += rb.x; rv[i].y += rb.y; rv[i].z += rb.z; rv[i].w += rb.w;
                }
            }
        }
#pragma unroll
        for (int i = 0; i < 4; i++) {
            rsx[i] += wxe[i]; rsy[i] += wye[i];
            b[i][0] += wxe[i] * (bflo(ps[i].x) + rv[i].x);
            b[i][1] += wye[i] * (bfhi(ps[i].x) + rv[i].y);
            b[i][2] += wxe[i] * (bflo(ps[i].y) + rv[i].z);
            b[i][3] += wye[i] * (bfhi(ps[i].y) + rv[i].w);
        }
    }
    uint2 pt[4];
#pragma unroll
    for (int i = 0; i < 4; i++)
        pt[i] = fv ? *(const uint2*)(Pcat + (size_t)(n0 + i) * LD1 + c4) : make_uint2(0u, 0u);
#pragma unroll
    for (int i = 0; i < 4; i++) {
        unsigned short* xr = x + (size_t)(n0 + i) * KP2;
        if (fv) {
            if (deg[i] <= DTH) {
                float d0 = (rsx[i] == 0.f) ? 1e-12f : rsx[i];
                float d1 = (rsy[i] == 0.f) ? 1e-12f : rsy[i];
                float i0 = frcp(d0), i1 = frcp(d1);
                float v0 = (b[i][0] + rsx[i] * bflo(pt[i].x)) * i0;
                float v1 = (b[i][1] + rsy[i] * bfhi(pt[i].x)) * i1;
                float v2 = (b[i][2] + rsx[i] * bflo(pt[i].y)) * i0;
                float v3 = (b[i][3] + rsy[i] * bfhi(pt[i].y)) * i1;
                v0 = (v0 > 0.f) ? v0 : __expf(v0) - 1.f;
                v1 = (v1 > 0.f) ? v1 : __expf(v1) - 1.f;
                v2 = (v2 > 0.f) ? v2 : __expf(v2) - 1.f;
                v3 = (v3 > 0.f) ? v3 : __expf(v3) - 1.f;
                uint2 w;
                w.x = (uint32_t)f2bf(v0) | ((uint32_t)f2bf(v1) << 16);
                w.y = (uint32_t)f2bf(v2) | ((uint32_t)f2bf(v3) << 16);
                *(uint2*)(xr + c4) = w;
            }
        } else {
            *(uint2*)(xr + 200 + (lane - 50) * 4) = make_uint2(0u, 0u);
        }
    }
}

// ================= node layer-2 component (masked nodes) =================

static __device__ void d_node2_one(int node, int lane,
                        const int* __restrict__ rowptr, const int* __restrict__ srcs,
                        const int2* __restrict__ relpk,
                        const unsigned short* __restrict__ Qcat,
                        const unsigned short* __restrict__ Pcat,
                        const float* __restrict__ R2, const float* __restrict__ dR2,
                        const float* __restrict__ mask, float* __restrict__ out) {
    bool fv = (lane < 50);
    int c4 = lane * 4;
    int beg = rowptr[node], end = rowptr[node + 1];
    int deg = end - beg;
    int fast = (deg < 64) ? deg : 64;
    uint32_t tq = *(const uint32_t*)(Qcat + (size_t)node * LD2 + 400);
    float tdot = bflo(tq);
    int sL = 0, rxL = 0, ryL = -1;
    float WL = 0.f;
    if (lane < fast) {
        int p = beg + lane;
        sL = srcs[p];
        int2 rp = relpk[p];
        rxL = rp.x; ryL = rp.y;
        float dr = dR2[rp.x];
        if (rp.y >= 0) dr += dR2[rp.y];
        uint32_t sq = *(const uint32_t*)(Qcat + (size_t)sL * LD2 + 400);
        float pp = tdot + bfhi(sq) + dr;
        pp = (pp >= 0.f) ? pp : LRALPHA * pp;
        WL = __expf(-pp);
    }
    float c0 = 0.f, c1 = 0.f, c2 = 0.f, c3 = 0.f;
    float rs = 0.f;
    for (int j = 0; j < fast; j += 4) {
#pragma unroll
        for (int u = 0; u < 4; u++) {
            int jj = j + u;
            bool act = (jj < fast);
            int ls = act ? jj : 0;
            int sE = rdl(sL, ls);
            int rxE = rdl(rxL, ls);
            int ryE = act ? rdl(ryL, ls) : -1;
            float WE = act ? rdlf(WL, ls) : 0.f;
            uint2 qv = make_uint2(0u, 0u);
            float4 rv = make_float4(0.f, 0.f, 0.f, 0.f);
            if (fv) {
                qv = *(const uint2*)(Qcat + (size_t)sE * LD2 + 200 + c4);
                rv = *(const float4*)(R2 + (size_t)rxE * 200 + c4);
                if (ryE >= 0) {
                    float4 rb = *(const float4*)(R2 + (size_t)ryE * 200 + c4);
                    rv.x += rb.x; rv.y += rb.y; rv.z += rb.z; rv.w += rb.w;
                }
            }
            rs += WE;
            c0 += WE * (bflo(qv.x) + rv.x);
            c1 += WE * (bfhi(qv.x) + rv.y);
            c2 += WE * (bflo(qv.y) + rv.z);
            c3 += WE * (bfhi(qv.y) + rv.w);
        }
    }
    for (int p = beg + 64; p < end; p++) {
        int sE = srcs[p];
        int2 rp = relpk[p];
        float dr = dR2[rp.x];
        if (rp.y >= 0) dr += dR2[rp.y];
        uint32_t sq = *(const uint32_t*)(Qcat + (size_t)sE * LD2 + 400);
        float pp = tdot + bfhi(sq) + dr;
        pp = (pp >= 0.f) ? pp : LRALPHA * pp;
        float W = __expf(-pp);
        uint2 qv = make_uint2(0u, 0u);
        float4 rv = make_float4(0.f, 0.f, 0.f, 0.f);
        if (fv) {
            qv = *(const uint2*)(Qcat + (size_t)sE * LD2 + 200 + c4);
            rv = *(const float4*)(R2 + (size_t)rp.x * 200 + c4);
            if (rp.y >= 0) {
                float4 rb = *(const float4*)(R2 + (size_t)rp.y * 200 + c4);
                rv.x += rb.x; rv.y += rb.y; rv.z += rb.z; rv.w += rb.w;
            }
        }
        rs += W;
        c0 += W * (bflo(qv.x) + rv.x);
        c1 += W * (bfhi(qv.x) + rv.y);
        c2 += W * (bflo(qv.y) + rv.z);
        c3 += W * (bfhi(qv.y) + rv.w);
    }
    float d = (rs == 0.f) ? 1e-12f : rs;
    float idn = frcp(d);
    float mk = mask[node];
    float val0 = 0.f, val1 = 0.f, val2 = 0.f, val3 = 0.f;
    if (fv) {
        uint2 t = *(const uint2*)(Qcat + (size_t)node * LD2 + c4);
        uint2 e = *(const uint2*)(Pcat + (size_t)node * LD1 + 400 + c4);
        val0 = bflo(e.x) + mk * ((c0 + rs * bflo(t.x)) * idn);
        val1 = bfhi(e.x) + mk * ((c1 + rs * bfhi(t.x)) * idn);
        val2 = bflo(e.y) + mk * ((c2 + rs * bflo(t.y)) * idn);
        val3 = bfhi(e.y) + mk * ((c3 + rs * bfhi(t.y)) * idn);
    }
    float ss = val0 * val0 + val1 * val1 + val2 * val2 + val3 * val3;
#pragma unroll
    for (int o = 32; o > 0; o >>= 1) ss += __shfl_down(ss, o);
    ss = __shfl(ss, 0);
    float inv = frcp(fmaxf(sqrtf(ss), 1e-12f));
    if (fv) {
        *(float4*)(out + (size_t)node * 200 + c4) =
            make_float4(val0 * inv, val1 * inv, val2 * inv, val3 * inv);
    }
}

// ================= kernels =================

__global__ __launch_bounds__(256) void k_megaA(
        const int* __restrict__ tgt_el, const int* __restrict__ nhop, int* __restrict__ deg,
        const float* __restrict__ rel_emb, const float* __restrict__ att_a,
        float* __restrict__ R1i,
        const float* __restrict__ W_rel, float* __restrict__ outrel,
        const float* __restrict__ att_a2, const float* __restrict__ W_ent,
        unsigned short* __restrict__ W1,
        const float* __restrict__ out_a, const float* __restrict__ out_a2,
        unsigned short* __restrict__ W2,
        const int* __restrict__ batch, float* __restrict__ mask, float* __restrict__ oacc) {
    __shared__ __align__(16) char smem[8448];
    int bid = blockIdx.x, tid = threadIdx.x;
    if (bid < A_HIST) {
        d_hist(bid, tid, tgt_el, nhop, deg);
    } else if (bid < A_RELP) {
        d_relproj1(bid - A_HIST, tid, rel_emb, att_a, R1i);
    } else if (bid < A_MMW) {
        int i = bid - A_RELP;
        d_mm<false>(i & 3, i >> 2, smem, tid, rel_emb, 100, W_rel, 200, outrel, 200,
                    N_RELS, 200, 100);
    } else if (bid < A_PACK1) {
        d_pack1(bid - A_MMW, tid, att_a, att_a2, W_ent, W1);
    } else if (bid < A_PACK2) {
        d_pack2(bid - A_PACK1, tid, out_a, out_a2, W2);
    } else if (bid < A_MASK) {
        d_mask(bid - A_PACK2, tid, batch, mask);
    } else {
        d_ortho_part(bid - A_MASK, tid, att_a, out_a, oacc);
    }
}

__global__ void k_scan1(const int* __restrict__ deg, int* __restrict__ local,
                        int* __restrict__ bsums, int n) {
    int i = blockIdx.x * 256 + threadIdx.x;
    int v = (i < n) ? deg[i] : 0;
    int lane = threadIdx.x & 63;
    int wv = threadIdx.x >> 6;
    int x = v;
#pragma unroll
    for (int o = 1; o < 64; o <<= 1) {
        int t = __shfl_up(x, o);
        if (lane >= o) x += t;
    }
    __shared__ int wtot[4];
    if (lane == 63) wtot[wv] = x;
    __syncthreads();
    int add = 0;
    for (int k = 0; k < wv; k++) add += wtot[k];
    if (i < n) local[i] = add + x - v;
    if (threadIdx.x == 255) bsums[blockIdx.x] = add + x;
}

// scan2 (1 block) + gemm1f (1250) + dR1 (119) + R2 GEMM (32)
__global__ __launch_bounds__(256) void k_megaB(
        int* __restrict__ bsums, int nbk,
        const float* __restrict__ ent_emb, const unsigned short* __restrict__ Wcat1,
        unsigned short* __restrict__ Pcat,
        const float* __restrict__ mask, float* __restrict__ outbuf,
        const float* __restrict__ R1i, const float* __restrict__ att_a2,
        float* __restrict__ dR10, float* __restrict__ dR11,
        const float* __restrict__ outrel, const float* __restrict__ out_a,
        float* __restrict__ R2) {
    __shared__ __align__(16) char smem[33792];
    __shared__ int wtot[4];
    int bid = blockIdx.x, tid = threadIdx.x;
    if (bid == 0) {
        d_scan2(tid, wtot, bsums, nbk);
    } else if (bid < B_DR1) {
        int i = bid - B_G1F;
        d_gemm1f(i % 625, i / 625, smem, tid, ent_emb, Wcat1, Pcat, mask, outbuf);
    } else if (bid < B_R2) {
        d_dR1(bid - B_DR1, tid, R1i, att_a2, dR10, dR11);
    } else {
        int i = bid - B_R2;
        d_mm<true>(i & 3, i >> 2, smem, tid, outrel, 200, out_a + 400, 600, R2, 200,
                   N_RELS, 200, 200);
    }
}

// scan3 (157) + dotv (119)
__global__ void k_scan3d(const int* __restrict__ local, const int* __restrict__ bsums,
                         int* __restrict__ rowptr, int* __restrict__ cursor, int n, int nb,
                         const float* __restrict__ R2, const float* __restrict__ out_a2,
                         float* __restrict__ dR2) {
    int bid = blockIdx.x, tid = threadIdx.x;
    if (bid < S3_DOTV) {
        int i = bid * 256 + tid;
        if (i < n) {
            int v = local[i] + bsums[bid];
            rowptr[i] = v;
            cursor[i] = v;
        } else if (i == n) {
            rowptr[n] = bsums[nb];
        }
    } else {
        int w = (bid - S3_DOTV) * 4 + (tid >> 6);
        int lane = tid & 63;
        if (w < N_RELS) {
            const float* r = R2 + (size_t)w * 200;
            float s = 0.f;
            for (int j = lane; j < 200; j += 64) s += r[j] * out_a2[j];
#pragma unroll
            for (int o = 32; o > 0; o >>= 1) s += __shfl_down(s, o);
            if (lane == 0) dR2[w] = s;
        }
    }
}

// scatter + compact + ortho_fin
__global__ __launch_bounds__(256) void k_megaC(
        const int* __restrict__ tgt_el, const int* __restrict__ src_el,
        const int* __restrict__ etype, const int* __restrict__ nhop, int* __restrict__ cursor,
        int* __restrict__ srcs, int2* __restrict__ relpk,
        const int* __restrict__ rowptr, const float* __restrict__ mask,
        int* __restrict__ Hlist, int* __restrict__ Mlist, int* __restrict__ cnts,
        const float* __restrict__ oacc, float* __restrict__ oscalar) {
    int bid = blockIdx.x, tid = threadIdx.x;
    if (bid < C_CMP) {
        d_scatter(bid, tid, tgt_el, src_el, etype, nhop, cursor, srcs, relpk);
    } else if (bid < C_OFIN) {
        d_compact(bid - C_CMP, tid, rowptr, mask, Hlist, Mlist, cnts);
    } else {
        d_ortho_fin(tid, oacc, oscalar);
    }
}

// NODE1: layer-1 main | layer-1 hub
__global__ __launch_bounds__(256, 4) void k_node1(
                        const int* __restrict__ rowptr, const int* __restrict__ srcs,
                        const int2* __restrict__ relpk,
                        const unsigned short* __restrict__ Pcat,
                        const float* __restrict__ R1i,
                        const float* __restrict__ dR10, const float* __restrict__ dR11,
                        unsigned short* __restrict__ x,
                        const int* __restrict__ Hlist, const int* __restrict__ cnts) {
    int bid = blockIdx.x, tid = threadIdx.x;
    int lane = tid & 63;
    if (bid < N1_MAIN) {
        int wid = __builtin_amdgcn_readfirstlane(bid * 4 + (tid >> 6));
        d_node1_main(wid, lane, rowptr, srcs, relpk, Pcat, R1i, dR10, dR11, x);
    } else {
        int hw = (bid - N1_MAIN) * 4 + (tid >> 6);
        int cnt = cnts[0];
        for (int j = hw; j < cnt; j += HUBW) {
            int node = __builtin_amdgcn_readfirstlane(Hlist[j]);
            d_node1_one(node, lane, rowptr, srcs, relpk, Pcat, R1i, dR10, dR11, x);
        }
    }
}

__global__ __launch_bounds__(256) void k_gemm2(const unsigned short* __restrict__ A,
                                               const unsigned short* __restrict__ B,
                                               unsigned short* __restrict__ C,
                                               int ldc, int N, int gPerSplit) {
    __shared__ __align__(16) char smem[8192];
    d_gemm<KP2>(blockIdx.x, blockIdx.y, smem, threadIdx.x, A, B, C, ldc, N, gPerSplit);
}

// node2 hub: full-wave aggregation + final fuse for masked nodes only
__global__ __launch_bounds__(256, 4) void k_node2h(
                        const int* __restrict__ rowptr, const int* __restrict__ srcs,
                        const int2* __restrict__ relpk,
                        const unsigned short* __restrict__ Qcat,
                        const unsigned short* __restrict__ Pcat,
                        const float* __restrict__ R2, const float* __restrict__ dR2,
                        const float* __restrict__ mask,
                        const int* __restrict__ Mlist, const int* __restrict__ cnts,
                        float* __restrict__ out) {
    int tid = threadIdx.x;
    int lane = tid & 63;
    int hw = blockIdx.x * 4 + (tid >> 6);
    int cnt = cnts[1];
    for (int j = hw; j < cnt; j += HUBW) {
        int node = __builtin_amdgcn_readfirstlane(Mlist[j]);
        d_node2_one(node, lane, rowptr, srcs, relpk, Qcat, Pcat, R2, dR2, mask, out);
    }
}

// ================= launch =================
extern "C" void kernel_launch(void* const* d_in, const int* in_sizes, int n_in,
                              void* d_out, int out_size, void* d_ws, size_t ws_size,
                              hipStream_t stream) {
    const int* edge_list = (const int*)d_in[0];
    const int* edge_type = (const int*)d_in[1];
    const int* batch     = (const int*)d_in[2];
    const int* nhop      = (const int*)d_in[3];
    const float* ent_emb = (const float*)d_in[4];
    const float* rel_emb = (const float*)d_in[5];
    const float* W_ent   = (const float*)d_in[6];
    const float* W_rel   = (const float*)d_in[7];
    const float* att_a   = (const float*)d_in[8];
    const float* att_a2  = (const float*)d_in[9];
    const float* out_a   = (const float*)d_in[10];
    const float* out_a2  = (const float*)d_in[11];
    float* out = (float*)d_out;
    const int* tgt_el = edge_list;
    const int* src_el = edge_list + E0;

    char* ws = (char*)d_ws;
    size_t o = 0;
    auto alloc = [&](size_t nbytes) -> char* {
        char* p = ws + o;
        o += (nbytes + 255) & ~(size_t)255;
        return p;
    };
    unsigned short* x_bf    = (unsigned short*)alloc((size_t)N_NODES * KP2 * 2);
    unsigned short* Pcat    = (unsigned short*)alloc((size_t)N_NODES * LD1 * 2);
    unsigned short* Qcat    = (unsigned short*)alloc((size_t)N_NODES * LD2 * 2);
    unsigned short* Wcat1   = (unsigned short*)alloc((size_t)NPAD1 * KP1 * 2);
    unsigned short* Wcat2   = (unsigned short*)alloc((size_t)NPAD2 * KP2 * 2);
    float* R1i   = (float*)alloc(474u * 200 * 4);
    float* R2    = (float*)alloc(474u * 200 * 4);
    float* dR10  = (float*)alloc(474u * 4);
    float* dR11  = (float*)alloc(474u * 4);
    float* dR2   = (float*)alloc(474u * 4);
    int* rowptr  = (int*)alloc((N_NODES + 1) * 4);
    int* cursor  = (int*)alloc(N_NODES * 4);
    int* srcs    = (int*)alloc((size_t)NE * 4);
    int2* relpk  = (int2*)alloc((size_t)NE * 8);
    float* mask  = (float*)alloc(N_NODES * 4);
    int* scanloc = (int*)alloc(N_NODES * 4);
    int* bsums   = (int*)alloc(260 * 4);
    float* oacc  = (float*)alloc(9 * 4);
    int* Hlist   = (int*)alloc(N_NODES * 4);
    int* Mlist   = (int*)alloc(N_NODES * 4);
    int* cnts    = (int*)alloc(2 * 4);

    hipMemsetAsync(cursor, 0, N_NODES * 4, stream);
    hipMemsetAsync(mask, 0, N_NODES * 4, stream);
    hipMemsetAsync(oacc, 0, 9 * 4, stream);
    hipMemsetAsync(cnts, 0, 2 * 4, stream);

    // 1) hist + relproj1 + out_relation GEMM + pack1 + pack2 + mask + ortho partials
    k_megaA<<<A_TOT, 256, 0, stream>>>(tgt_el, nhop, cursor,
                                       rel_emb, att_a, R1i,
                                       W_rel, out + 8000000,
                                       att_a2, W_ent, Wcat1,
                                       out_a, out_a2, Wcat2,
                                       batch, mask, oacc);
    // 2) CSR scan phase 1
    k_scan1<<<157, 256, 0, stream>>>(cursor, scanloc, bsums, N_NODES);
    // 3) scan2 + layer-1 GEMM (fused l2norm + unmasked out-write) + dR1 + R2 GEMM
    k_megaB<<<B_TOT, 256, 0, stream>>>(bsums, 157, ent_emb, Wcat1, Pcat, mask, out,
                                       R1i, att_a2, dR10, dR11,
                                       out + 8000000, out_a, R2);
    // 4) scan phase 3 + dR2 dotv
    k_scan3d<<<S3_TOT, 256, 0, stream>>>(scanloc, bsums, rowptr, cursor, N_NODES, 157,
                                         R2, out_a2, dR2);
    // 5) scatter + compact + ortho finalize
    k_megaC<<<C_TOT, 256, 0, stream>>>(tgt_el, src_el, edge_type, nhop, cursor,
                                       srcs, relpk, rowptr, mask, Hlist, Mlist, cnts,
                                       oacc, out + 8094800);
    // 6) layer-1 aggregation (main + hub)
    k_node1<<<N1_TOT, 256, 0, stream>>>(rowptr, srcs, relpk, Pcat, R1i, dR10, dR11,
                                        x_bf, Hlist, cnts);
    // 7) layer-2 GEMM
    k_gemm2<<<dim3(625, 2), 256, 0, stream>>>(x_bf, Wcat2, Qcat, LD2, 416, 4);
    // 8) layer-2 masked-node aggregation + final fuse
    k_node2h<<<512, 256, 0, stream>>>(rowptr, srcs, relpk, Qcat, Pcat, R2, dR2,
                                      mask, Mlist, cnts, out);
}

// Round 11
// 319.352 us; speedup vs baseline: 1.0845x; 1.0113x over previous
//
#include <hip/hip_runtime.h>
#include <cstdint>
#include <cstddef>
#include <math.h>

#define N_NODES 40000
#define N_RELS  474
#define E0      100000
#define NE      130000
#define NB      8192
#define LRALPHA 0.2f

#define KP1 128
#define KP2 256
// Pcat cols: [0:200) Pt interleaved | [200:400) Ps interleaved | [400:600) entW | [600:604) dots | pad
#define LD1 608
// Qcat cols: [0:200) Qt | [200:400) Qs | 400 dqt | 401 dqs | pad
#define LD2 416
#define NPAD1 640
#define NPAD2 448
#define DTH 16
#define HUBW 2048

// MEGA-A block ranges (raw-input-only regions)
#define A_HIST   508
#define A_RELP   (A_HIST + 119)
#define A_MMW    (A_RELP + 32)
#define A_PACK1  (A_MMW + 320)
#define A_PACK2  (A_PACK1 + 448)
#define A_MASK   (A_PACK2 + 32)
#define A_TOT    (A_MASK + 128)
// MEGA-B: scan2 (1) | gemm1f (1250) | dR1 (119) | R2 GEMM (32)
#define B_G1F    1
#define B_DR1    (B_G1F + 1250)
#define B_R2     (B_DR1 + 119)
#define B_TOT    (B_R2 + 32)
// SCAN3D: scan3 (157) | dotv (119)
#define S3_DOTV  157
#define S3_TOT   (S3_DOTV + 119)
// MEGA-C: scatter | compact | ortho_fin
#define C_CMP    508
#define C_OFIN   (C_CMP + 157)
#define C_TOT    (C_OFIN + 1)
// NODE1: layer-1 hub FIRST (longest waves start at t=0) | layer-1 main interleave
#define N1_HUB   512
#define N1_TOT   (N1_HUB + 2500)

typedef __attribute__((ext_vector_type(8))) short short8;
typedef __attribute__((ext_vector_type(4))) float floatx4;

static __device__ __forceinline__ unsigned short f2bf(float f) {
    union { float f; uint32_t u; } v; v.f = f;
    uint32_t r = v.u + 0x7fff + ((v.u >> 16) & 1);
    return (unsigned short)(r >> 16);
}
static __device__ __forceinline__ float bf2f(unsigned short h) {
    union { uint32_t u; float f; } v; v.u = ((uint32_t)h) << 16;
    return v.f;
}
static __device__ __forceinline__ float bflo(uint32_t u) { return bf2f((unsigned short)(u & 0xffff)); }
static __device__ __forceinline__ float bfhi(uint32_t u) { return bf2f((unsigned short)(u >> 16)); }

static __device__ __forceinline__ int rdl(int v, int l) {
    return __builtin_amdgcn_readlane(v, l);
}
static __device__ __forceinline__ float rdlf(float v, int l) {
    return __int_as_float(__builtin_amdgcn_readlane(__float_as_int(v), l));
}
static __device__ __forceinline__ float frcp(float x) { return __builtin_amdgcn_rcpf(x); }

// ================= device components =================

static __device__ void d_hist(int bid, int tid, const int* __restrict__ tgt_el,
                              const int* __restrict__ nhop, int* __restrict__ deg) {
    int e = bid * 256 + tid;
    if (e >= NE) return;
    int t = (e < E0) ? tgt_el[e] : nhop[(size_t)(e - E0) * 4 + 3];
    atomicAdd(&deg[t], 1);
}

static __device__ void d_mask(int bid, int tid, const int* __restrict__ batch,
                              float* __restrict__ mask) {
    int i = bid * 256 + tid;
    if (i < NB) mask[batch[(size_t)i * 3 + 2]] = 1.0f;
}

static __device__ void d_ortho_part(int bid, int tid, const float* __restrict__ att_a,
                                    const float* __restrict__ out_a, float* __restrict__ accum) {
    float loc[9] = {0,0,0,0,0,0,0,0,0};
    for (int i = bid * 256 + tid; i < 90000; i += 128 * 256) {
        int seg, li;
        const float* base;
        int L;
        if (i < 15000)      { seg = 0; li = i;          base = att_a;         L = 15000; }
        else if (i < 30000) { seg = 1; li = i - 15000;  base = att_a + 30000; L = 15000; }
        else                { seg = 2; li = i - 30000;  base = out_a;         L = 60000; }
        float a = base[li], b = base[L + li];
        loc[seg * 3 + 0] += a * a;
        loc[seg * 3 + 1] += b * b;
        loc[seg * 3 + 2] += a * b;
    }
    int lane = tid & 63;
#pragma unroll
    for (int q = 0; q < 9; q++) {
        float s = loc[q];
#pragma unroll
        for (int o = 32; o > 0; o >>= 1) s += __shfl_down(s, o);
        if (lane == 0 && s != 0.f) atomicAdd(&accum[q], s);
    }
}

static __device__ void d_scan2(int tid, int* wtot, int* __restrict__ bsums, int nb) {
    int v = (tid < nb) ? bsums[tid] : 0;
    int lane = tid & 63, wv = tid >> 6;
    int x = v;
#pragma unroll
    for (int o = 1; o < 64; o <<= 1) {
        int t = __shfl_up(x, o);
        if (lane >= o) x += t;
    }
    if (lane == 63) wtot[wv] = x;
    __syncthreads();
    int add = 0;
    for (int k = 0; k < wv; k++) add += wtot[k];
    __syncthreads();
    if (tid < nb) bsums[tid] = add + x - v;
    if (tid == 255) bsums[nb] = add + x;
}

// ---- pack layer-1 B matrix (uvec rows computed inline) ----
static __device__ void d_pack1(int bid, int tid, const float* __restrict__ att_a,
                               const float* __restrict__ att_a2,
                               const float* __restrict__ W_ent,
                               unsigned short* __restrict__ W) {
    int idx = bid * 256 + tid;
    if (idx >= NPAD1 * KP1) return;
    int j = idx & 7;
    int lane = (idx >> 3) & 63;
    int u = idx >> 9;
    int ks = u & 3;
    int t = u >> 2;
    int r = t * 16 + (lane & 15);
    int k = ks * 32 + (lane >> 4) * 8 + j;
    float val = 0.f;
    if (k < 100) {
        if (r < 200) {
            int i = r >> 1, h = r & 1;
            val = att_a[h * 30000 + i * 300 + k];
        } else if (r < 400) {
            int rr = r - 200, i = rr >> 1, h = rr & 1;
            val = att_a[h * 30000 + i * 300 + 100 + k];
        } else if (r < 600) {
            val = W_ent[k * 200 + (r - 400)];
        } else if (r < 604) {
            int v = r - 600, head = v >> 1, part = v & 1;
            const float* base = att_a + head * 30000 + part * 100 + k;
            const float* a2v = att_a2 + head * 100;
            float s = 0.f;
            for (int n = 0; n < 100; n++) s += a2v[n] * base[n * 300];
            val = s;
        }
    }
    W[idx] = f2bf(val);
}

// ---- pack layer-2 B matrix (uvec rows computed inline) ----
static __device__ void d_pack2(int bid, int tid, const float* __restrict__ out_a,
                               const float* __restrict__ out_a2,
                               unsigned short* __restrict__ W) {
    int idx = bid * 256 + tid;
    if (idx >= NPAD2 * KP2) return;
    int j = idx & 7;
    int lane = (idx >> 3) & 63;
    int u = idx >> 9;
    int ks = u & 7;
    int t = u >> 3;
    int r = t * 16 + (lane & 15);
    int k = ks * 32 + (lane >> 4) * 8 + j;
    float val = 0.f;
    if (k < 200) {
        int klog = (k & 1) * 100 + (k >> 1);
        if (r < 200)       val = out_a[r * 600 + klog];
        else if (r < 400)  val = out_a[(r - 200) * 600 + 200 + klog];
        else if (r == 400) {
            float s = 0.f;
            for (int n = 0; n < 200; n++) s += out_a2[n] * out_a[n * 600 + klog];
            val = s;
        } else if (r == 401) {
            float s = 0.f;
            for (int n = 0; n < 200; n++) s += out_a2[n] * out_a[n * 600 + 200 + klog];
            val = s;
        }
    }
    W[idx] = f2bf(val);
}

static __device__ void d_scatter(int bid, int tid, const int* __restrict__ tgt_el,
                                 const int* __restrict__ src_el, const int* __restrict__ etype,
                                 const int* __restrict__ nhop, int* __restrict__ cursor,
                                 int* __restrict__ srcs, int2* __restrict__ relpk) {
    int e = bid * 256 + tid;
    if (e >= NE) return;
    int t, s, r1, r2;
    if (e < E0) {
        t = tgt_el[e]; s = src_el[e]; r1 = etype[e]; r2 = -1;
    } else {
        const int* nh = nhop + (size_t)(e - E0) * 4;
        t = nh[3]; s = nh[0]; r1 = nh[1]; r2 = nh[2];
    }
    int p = atomicAdd(&cursor[t], 1);
    srcs[p] = s;
    relpk[p] = make_int2(r1, r2);
}

static __device__ void d_compact(int bid, int tid, const int* __restrict__ rowptr,
                                 const float* __restrict__ mask,
                                 int* __restrict__ Hlist, int* __restrict__ Mlist,
                                 int* __restrict__ cnts) {
    int i = bid * 256 + tid;
    if (i >= N_NODES) return;
    int deg = rowptr[i + 1] - rowptr[i];
    if (deg > DTH) { int p = atomicAdd(&cnts[0], 1); Hlist[p] = i; }
    if (mask[i] != 0.f) { int p = atomicAdd(&cnts[1], 1); Mlist[p] = i; }
}

// ---- bf16 MFMA GEMM (fragment-ordered B) — layer-2 ----
template <int KP>
static __device__ void d_gemm(int bx, int by, char* smem_raw, int tid,
                              const unsigned short* __restrict__ A,
                              const unsigned short* __restrict__ B,
                              unsigned short* __restrict__ C,
                              int ldc, int N, int gPerSplit) {
    constexpr int KSTEPS = KP / 32;
    constexpr int KCH = KSTEPS / 4;
    unsigned short (*cbuf)[16][64] = (unsigned short (*)[16][64])smem_raw;
    int wave = tid >> 6;
    int lane = tid & 63;
    int quad = lane >> 4;
    int l16 = lane & 15;
    int m0 = bx * 64 + wave * 16;
    short8 afrag[KSTEPS];
    const unsigned short* arow = A + (size_t)(m0 + l16) * KP + quad * 8;
#pragma unroll
    for (int ks = 0; ks < KSTEPS; ks++)
        afrag[ks] = *(const short8*)(arow + ks * 32);

    int Gtot = (N + 63) >> 6;
    int g0 = by * gPerSplit;
    int g1 = g0 + gPerSplit;
    if (g1 > Gtot) g1 = Gtot;
    for (int g = g0; g < g1; g++) {
        int nb = g << 6;
        const unsigned short* bgrp = B + (((size_t)(g << 2) * KSTEPS) << 9) + (lane << 3);
        floatx4 acc[4];
#pragma unroll
        for (int t = 0; t < 4; t++) acc[t] = (floatx4){0.f, 0.f, 0.f, 0.f};
#pragma unroll
        for (int ch = 0; ch < KCH; ch++) {
            short8 bf[4][4];
#pragma unroll
            for (int t = 0; t < 4; t++)
#pragma unroll
                for (int k = 0; k < 4; k++)
                    bf[t][k] = *(const short8*)(bgrp + ((size_t)(t * KSTEPS + ch * 4 + k) << 9));
#pragma unroll
            for (int k = 0; k < 4; k++)
#pragma unroll
                for (int t = 0; t < 4; t++)
                    acc[t] = __builtin_amdgcn_mfma_f32_16x16x32_bf16(afrag[ch * 4 + k], bf[t][k], acc[t], 0, 0, 0);
        }
        int r0 = quad * 4;
#pragma unroll
        for (int t = 0; t < 4; t++)
#pragma unroll
            for (int i = 0; i < 4; i++)
                cbuf[wave][r0 + i][t * 16 + l16] = f2bf(acc[t][i]);
        int colsA = N - nb; if (colsA > 64) colsA = 64;
        int cols8 = colsA >> 3;
        int sh = (colsA >= 64) ? 3 : 2;
        int nchunks = cols8 << 4;
        for (int c = lane; c < nchunks; c += 64) {
            int row = c >> sh;
            int col8 = (c & (cols8 - 1)) << 3;
            *(uint4*)(C + (size_t)(m0 + row) * ldc + nb + col8) =
                *(const uint4*)&cbuf[wave][row][col8];
        }
    }
}

// ---- layer-1 GEMM: fused row-l2norm (raw fp32 in) + fused unmasked out-write (by==1) ----
static __device__ void d_gemm1f(int bx, int by, char* smem_raw, int tid,
                                const float* __restrict__ ent,
                                const unsigned short* __restrict__ B,
                                unsigned short* __restrict__ C,
                                const float* __restrict__ mask,
                                float* __restrict__ out) {
    float (*rows)[105] = (float (*)[105])smem_raw;              // 26880 B (consumed pre-loop)
    float* invn = (float*)(smem_raw + 64 * 105 * 4);            // +256 B  (consumed pre-loop)
    unsigned short (*entw)[200] = (unsigned short (*)[200])(smem_raw + 8192);  // 25600 B
    int m0 = bx * 64;
    for (int idx = tid; idx < 6400; idx += 256) {
        int r = idx / 100, c = idx - r * 100;
        rows[r][c] = ent[(size_t)(m0 + r) * 100 + c];
    }
    __syncthreads();
    {
        int r = tid >> 2, q = tid & 3;
        const float* rp = rows[r] + q * 25;
        float s = 0.f;
#pragma unroll
        for (int c = 0; c < 25; c++) { float v = rp[c]; s += v * v; }
        s += __shfl_xor(s, 1);
        s += __shfl_xor(s, 2);
        if (q == 0) invn[r] = 1.f / fmaxf(sqrtf(s), 1e-12f);
    }
    __syncthreads();
    int wave = tid >> 6;
    int lane = tid & 63;
    int quad = lane >> 4;
    int l16 = lane & 15;
    int rr = wave * 16 + l16;
    float inv = invn[rr];
    short8 afrag[4];
#pragma unroll
    for (int ks = 0; ks < 4; ks++) {
        short8 f;
#pragma unroll
        for (int j = 0; j < 8; j++) {
            int col = ks * 32 + quad * 8 + j;
            f[j] = (col < 100) ? (short)f2bf(rows[rr][col] * inv) : (short)0;
        }
        afrag[ks] = f;
    }
    __syncthreads();   // rows region reused as cbuf below
    unsigned short (*cbuf)[16][64] = (unsigned short (*)[16][64])smem_raw;
    int mo0 = m0 + wave * 16;
    int g0 = by * 5, g1 = g0 + 5;
    if (g1 > 10) g1 = 10;
    for (int g = g0; g < g1; g++) {
        int nb = g << 6;
        const unsigned short* bgrp = B + (((size_t)(g << 2) * 4) << 9) + (lane << 3);
        floatx4 acc[4];
#pragma unroll
        for (int t = 0; t < 4; t++) acc[t] = (floatx4){0.f, 0.f, 0.f, 0.f};
        short8 bf[4][4];
#pragma unroll
        for (int t = 0; t < 4; t++)
#pragma unroll
            for (int k = 0; k < 4; k++)
                bf[t][k] = *(const short8*)(bgrp + ((size_t)(t * 4 + k) << 9));
#pragma unroll
        for (int k = 0; k < 4; k++)
#pragma unroll
            for (int t = 0; t < 4; t++)
                acc[t] = __builtin_amdgcn_mfma_f32_16x16x32_bf16(afrag[k], bf[t][k], acc[t], 0, 0, 0);
        int r0 = quad * 4;
#pragma unroll
        for (int t = 0; t < 4; t++)
#pragma unroll
            for (int i = 0; i < 4; i++)
                cbuf[wave][r0 + i][t * 16 + l16] = f2bf(acc[t][i]);
        int colsA = 608 - nb; if (colsA > 64) colsA = 64;
        int cols8 = colsA >> 3;
        int sh = (colsA >= 64) ? 3 : 2;
        int nchunks = cols8 << 4;
        for (int c = lane; c < nchunks; c += 64) {
            int row = c >> sh;
            int col8 = (c & (cols8 - 1)) << 3;
            *(uint4*)(C + (size_t)(mo0 + row) * LD1 + nb + col8) =
                *(const uint4*)&cbuf[wave][row][col8];
        }
        // keep entW window (cols [400,600)) for fused out-write
        if (by == 1) {
            int cg = nb + lane;
            if (cg >= 400 && cg < 600) {
#pragma unroll
                for (int i = 0; i < 16; i++)
                    entw[wave * 16 + i][cg - 400] = cbuf[wave][i][lane];
            }
        }
    }
    // fused layer-2 unmasked streaming output: out[node] = l2norm(entW row)
    if (by == 1) {
        bool fv = (lane < 50);
        int c4 = lane * 4;
        for (int i = 0; i < 16; i++) {
            int row = wave * 16 + i;
            int node = m0 + row;
            float mk = mask[node];
            if (mk != 0.f) continue;    // masked nodes written by node2h
            float v0 = 0.f, v1 = 0.f, v2 = 0.f, v3 = 0.f;
            if (fv) {
                v0 = bf2f(entw[row][c4 + 0]);
                v1 = bf2f(entw[row][c4 + 1]);
                v2 = bf2f(entw[row][c4 + 2]);
                v3 = bf2f(entw[row][c4 + 3]);
            }
            float ss = v0 * v0 + v1 * v1 + v2 * v2 + v3 * v3;
#pragma unroll
            for (int o = 32; o > 0; o >>= 1) ss += __shfl_down(ss, o);
            ss = __shfl(ss, 0);
            float iv = frcp(fmaxf(sqrtf(ss), 1e-12f));
            if (fv) {
                *(float4*)(out + (size_t)node * 200 + c4) =
                    make_float4(v0 * iv, v1 * iv, v2 * iv, v3 * iv);
            }
        }
    }
}

// ---- generic tiled fp32 matmul (474-row cases) ----
template <bool BT>
static __device__ void d_mm(int bx, int by, char* smem_raw, int tid,
                            const float* __restrict__ A, int lda,
                            const float* __restrict__ B, int ldb,
                            float* __restrict__ C, int ldc,
                            int M, int N, int K) {
    float (*As)[65] = (float (*)[65])smem_raw;
    float (*Bs)[65] = (float (*)[65])(smem_raw + 16 * 65 * 4);
    int tx = tid & 15, ty = tid >> 4;
    int m0 = by * 64, n0 = bx * 64;
    float acc[4][4] = {};
    for (int k0 = 0; k0 < K; k0 += 16) {
        {
            int r = tid >> 2;
            int c4 = (tid & 3) * 4;
            int m = m0 + r;
#pragma unroll
            for (int u = 0; u < 4; u++) {
                int k = k0 + c4 + u;
                As[c4 + u][r] = (m < M && k < K) ? A[(size_t)m * lda + k] : 0.f;
            }
        }
        if (BT) {
            int r = tid >> 2;
            int c4 = (tid & 3) * 4;
            int n = n0 + r;
#pragma unroll
            for (int u = 0; u < 4; u++) {
                int k = k0 + c4 + u;
                Bs[c4 + u][r] = (n < N && k < K) ? B[(size_t)n * ldb + k] : 0.f;
            }
        } else {
            int kk = tid >> 4;
            int nn4 = (tid & 15) * 4;
            int k = k0 + kk;
#pragma unroll
            for (int u = 0; u < 4; u++) {
                int n = n0 + nn4 + u;
                Bs[kk][nn4 + u] = (k < K && n < N) ? B[(size_t)k * ldb + n] : 0.f;
            }
        }
        __syncthreads();
#pragma unroll
        for (int k = 0; k < 16; k++) {
            float a[4], b[4];
#pragma unroll
            for (int i = 0; i < 4; i++) a[i] = As[k][ty + 16 * i];
#pragma unroll
            for (int j = 0; j < 4; j++) b[j] = Bs[k][tx + 16 * j];
#pragma unroll
            for (int i = 0; i < 4; i++)
#pragma unroll
                for (int j = 0; j < 4; j++) acc[i][j] += a[i] * b[j];
        }
        __syncthreads();
    }
#pragma unroll
    for (int i = 0; i < 4; i++) {
        int m = m0 + ty + 16 * i;
        if (m >= M) continue;
#pragma unroll
        for (int j = 0; j < 4; j++) {
            int n = n0 + tx + 16 * j;
            if (n < N) C[(size_t)m * ldc + n] = acc[i][j];
        }
    }
}

static __device__ void d_relproj1(int bid, int tid, const float* __restrict__ rel_emb,
                                  const float* __restrict__ att_a, float* __restrict__ R1i) {
    int w = (bid * 256 + tid) >> 6;
    int lane = tid & 63;
    if (w >= N_RELS) return;
    const float* re = rel_emb + (size_t)w * 100;
    float2* dst = (float2*)(R1i + (size_t)w * 200);
    for (int f = lane; f < 100; f += 64) {
        const float* a0 = att_a + f * 300 + 200;
        const float* a1 = att_a + 30000 + f * 300 + 200;
        float s0 = 0.f, s1 = 0.f;
        for (int k = 0; k < 100; k++) {
            float rk = re[k];
            s0 += rk * a0[k];
            s1 += rk * a1[k];
        }
        dst[f] = make_float2(s0, s1);
    }
}

static __device__ void d_dR1(int bid, int tid, const float* __restrict__ R1i,
                             const float* __restrict__ att_a2,
                             float* __restrict__ dR10, float* __restrict__ dR11) {
    int w = (bid * 256 + tid) >> 6;
    int lane = tid & 63;
    if (w >= N_RELS) return;
    const float2* row = (const float2*)(R1i + (size_t)w * 200);
    float s0 = 0.f, s1 = 0.f;
    for (int f = lane; f < 100; f += 64) {
        float2 v = row[f];
        s0 += v.x * att_a2[f];
        s1 += v.y * att_a2[100 + f];
    }
#pragma unroll
    for (int o = 32; o > 0; o >>= 1) {
        s0 += __shfl_down(s0, o);
        s1 += __shfl_down(s1, o);
    }
    if (lane == 0) { dR10[w] = s0; dR11[w] = s1; }
}

static __device__ void d_ortho_fin(int tid, const float* __restrict__ accum,
                                   float* __restrict__ out_scalar) {
    if (tid != 0) return;
    float total = 0.f;
#pragma unroll
    for (int m = 0; m < 3; m++) {
        float s0 = accum[m * 3 + 0], s1 = accum[m * 3 + 1], sc = accum[m * 3 + 2];
        float c = sc / (fmaxf(sqrtf(s0), 1e-12f) * fmaxf(sqrtf(s1), 1e-12f));
        total += 0.01f * 2.f * c * c;
    }
    out_scalar[0] = total;
}

// ================= node layer-1 components =================

static __device__ void d_node1_one(int node, int lane,
                        const int* __restrict__ rowptr, const int* __restrict__ srcs,
                        const int2* __restrict__ relpk,
                        const unsigned short* __restrict__ Pcat,
                        const float* __restrict__ R1i,
                        const float* __restrict__ dR10, const float* __restrict__ dR11,
                        unsigned short* __restrict__ x) {
    bool fv = (lane < 50);
    int c4 = lane * 4;
    int beg = rowptr[node], end = rowptr[node + 1];
    int deg = end - beg;
    int fast = (deg < 64) ? deg : 64;
    uint2 td = *(const uint2*)(Pcat + (size_t)node * LD1 + 600);
    float t0h = bflo(td.x), t1h = bflo(td.y);
    int sL = 0, rxL = 0, ryL = -1;
    float wxL = 0.f, wyL = 0.f;
    if (lane < fast) {
        int p = beg + lane;
        sL = srcs[p];
        int2 rp = relpk[p];
        rxL = rp.x; ryL = rp.y;
        float dr0 = dR10[rp.x], dr1 = dR11[rp.x];
        if (rp.y >= 0) { dr0 += dR10[rp.y]; dr1 += dR11[rp.y]; }
        uint2 sd = *(const uint2*)(Pcat + (size_t)sL * LD1 + 600);
        float p0 = t0h + bfhi(sd.x) + dr0;
        float p1 = t1h + bfhi(sd.y) + dr1;
        p0 = (p0 >= 0.f) ? p0 : LRALPHA * p0;
        p1 = (p1 >= 0.f) ? p1 : LRALPHA * p1;
        wxL = __expf(-p0);
        wyL = __expf(-p1);
    }
    float b0 = 0.f, b1 = 0.f, b2 = 0.f, b3 = 0.f;
    float rs0 = 0.f, rs1 = 0.f;
    for (int j = 0; j < fast; j += 4) {
#pragma unroll
        for (int u = 0; u < 4; u++) {
            int jj = j + u;
            bool act = (jj < fast);
            int ls = act ? jj : 0;
            int sE = rdl(sL, ls);
            int rxE = rdl(rxL, ls);
            int ryE = act ? rdl(ryL, ls) : -1;
            float wxE = act ? rdlf(wxL, ls) : 0.f;
            float wyE = act ? rdlf(wyL, ls) : 0.f;
            uint2 ps = make_uint2(0u, 0u);
            float4 rv = make_float4(0.f, 0.f, 0.f, 0.f);
            if (fv) {
                ps = *(const uint2*)(Pcat + (size_t)sE * LD1 + 200 + c4);
                rv = *(const float4*)(R1i + (size_t)rxE * 200 + c4);
                if (ryE >= 0) {
                    float4 rb = *(const float4*)(R1i + (size_t)ryE * 200 + c4);
                    rv.x += rb.x; rv.y += rb.y; rv.z += rb.z; rv.w += rb.w;
                }
            }
            rs0 += wxE; rs1 += wyE;
            b0 += wxE * (bflo(ps.x) + rv.x);
            b1 += wyE * (bfhi(ps.x) + rv.y);
            b2 += wxE * (bflo(ps.y) + rv.z);
            b3 += wyE * (bfhi(ps.y) + rv.w);
        }
    }
    for (int p = beg + 64; p < end; p++) {
        int sE = srcs[p];
        int2 rp = relpk[p];
        float dr0 = dR10[rp.x], dr1 = dR11[rp.x];
        if (rp.y >= 0) { dr0 += dR10[rp.y]; dr1 += dR11[rp.y]; }
        uint2 sd = *(const uint2*)(Pcat + (size_t)sE * LD1 + 600);
        float p0 = t0h + bfhi(sd.x) + dr0;
        float p1 = t1h + bfhi(sd.y) + dr1;
        p0 = (p0 >= 0.f) ? p0 : LRALPHA * p0;
        p1 = (p1 >= 0.f) ? p1 : LRALPHA * p1;
        float wx = __expf(-p0), wy = __expf(-p1);
        uint2 ps = make_uint2(0u, 0u);
        float4 rv = make_float4(0.f, 0.f, 0.f, 0.f);
        if (fv) {
            ps = *(const uint2*)(Pcat + (size_t)sE * LD1 + 200 + c4);
            rv = *(const float4*)(R1i + (size_t)rp.x * 200 + c4);
            if (rp.y >= 0) {
                float4 rb = *(const float4*)(R1i + (size_t)rp.y * 200 + c4);
                rv.x += rb.x; rv.y += rb.y; rv.z += rb.z; rv.w += rb.w;
            }
        }
        rs0 += wx; rs1 += wy;
        b0 += wx * (bflo(ps.x) + rv.x);
        b1 += wy * (bfhi(ps.x) + rv.y);
        b2 += wx * (bflo(ps.y) + rv.z);
        b3 += wy * (bfhi(ps.y) + rv.w);
    }
    float d0 = (rs0 == 0.f) ? 1e-12f : rs0;
    float d1 = (rs1 == 0.f) ? 1e-12f : rs1;
    float i0 = frcp(d0), i1 = frcp(d1);
    if (fv) {
        uint2 pt = *(const uint2*)(Pcat + (size_t)node * LD1 + c4);
        float v0 = (b0 + rs0 * bflo(pt.x)) * i0;
        float v1 = (b1 + rs1 * bfhi(pt.x)) * i1;
        float v2 = (b2 + rs0 * bflo(pt.y)) * i0;
        float v3 = (b3 + rs1 * bfhi(pt.y)) * i1;
        v0 = (v0 > 0.f) ? v0 : __expf(v0) - 1.f;
        v1 = (v1 > 0.f) ? v1 : __expf(v1) - 1.f;
        v2 = (v2 > 0.f) ? v2 : __expf(v2) - 1.f;
        v3 = (v3 > 0.f) ? v3 : __expf(v3) - 1.f;
        uint2 w;
        w.x = (uint32_t)f2bf(v0) | ((uint32_t)f2bf(v1) << 16);
        w.y = (uint32_t)f2bf(v2) | ((uint32_t)f2bf(v3) << 16);
        unsigned short* xr = x + (size_t)node * KP2;
        *(uint2*)(xr + c4) = w;
    }
}

// ---- 4-nodes-per-wave interleaved main path (deg<=DTH), k-loop unrolled x2 ----
static __device__ void d_node1_main(int wid, int lane,
                        const int* __restrict__ rowptr, const int* __restrict__ srcs,
                        const int2* __restrict__ relpk,
                        const unsigned short* __restrict__ Pcat,
                        const float* __restrict__ R1i,
                        const float* __restrict__ dR10, const float* __restrict__ dR11,
                        unsigned short* __restrict__ x) {
    int n0 = wid * 4;
    if (n0 >= N_NODES) return;
    bool fv = (lane < 50);
    int c4 = lane * 4;
    int rp = (lane < 5) ? rowptr[n0 + lane] : 0;
    int bnd0 = rdl(rp, 0), bnd1 = rdl(rp, 1), bnd2 = rdl(rp, 2), bnd3 = rdl(rp, 3), bnd4 = rdl(rp, 4);
    int beg[4] = {bnd0, bnd1, bnd2, bnd3};
    int end[4] = {bnd1, bnd2, bnd3, bnd4};
    int deg[4], fast[4];
#pragma unroll
    for (int i = 0; i < 4; i++) {
        deg[i] = end[i] - beg[i];
        fast[i] = (deg[i] <= DTH) ? deg[i] : 0;
    }
    int li = lane >> 4, lk = lane & 15;
    int begL = (li == 0) ? bnd0 : (li == 1) ? bnd1 : (li == 2) ? bnd2 : bnd3;
    int endL = (li == 0) ? bnd1 : (li == 1) ? bnd2 : (li == 2) ? bnd3 : bnd4;
    int degL = endL - begL;
    int fastL = (degL <= DTH) ? degL : 0;
    uint2 tdL = *(const uint2*)(Pcat + (size_t)(n0 + li) * LD1 + 600);
    float t0L = bflo(tdL.x), t1L = bflo(tdL.y);
    int sL = 0, rxL = 0, ryL = -1;
    float wxL = 0.f, wyL = 0.f;
    if (lk < fastL) {
        int p = begL + lk;
        sL = srcs[p];
        int2 rq = relpk[p];
        rxL = rq.x; ryL = rq.y;
        float dr0 = dR10[rq.x], dr1 = dR11[rq.x];
        if (rq.y >= 0) { dr0 += dR10[rq.y]; dr1 += dR11[rq.y]; }
        uint2 sd = *(const uint2*)(Pcat + (size_t)sL * LD1 + 600);
        float p0 = t0L + bfhi(sd.x) + dr0;
        float p1 = t1L + bfhi(sd.y) + dr1;
        p0 = (p0 >= 0.f) ? p0 : LRALPHA * p0;
        p1 = (p1 >= 0.f) ? p1 : LRALPHA * p1;
        wxL = __expf(-p0);
        wyL = __expf(-p1);
    }
    float b[4][4] = {};
    float rsx[4] = {0.f, 0.f, 0.f, 0.f}, rsy[4] = {0.f, 0.f, 0.f, 0.f};
    int kmax = max(max(fast[0], fast[1]), max(fast[2], fast[3]));
    for (int k = 0; k < kmax; k += 2) {
        // --- load phase: 8 independent edge-gather sets (2 slots x 4 nodes) ---
        uint2 psA[4]; float4 rvA[4]; float wxeA[4], wyeA[4];
        uint2 psB[4]; float4 rvB[4]; float wxeB[4], wyeB[4];
#pragma unroll
        for (int i = 0; i < 4; i++) {
            bool act = (k < fast[i]);
            int ls = i * 16 + k;
            int sE = rdl(sL, ls);
            int rxE = rdl(rxL, ls);
            int ryE = act ? rdl(ryL, ls) : -1;
            wxeA[i] = act ? rdlf(wxL, ls) : 0.f;
            wyeA[i] = act ? rdlf(wyL, ls) : 0.f;
            psA[i] = make_uint2(0u, 0u);
            rvA[i] = make_float4(0.f, 0.f, 0.f, 0.f);
            if (fv) {
                psA[i] = *(const uint2*)(Pcat + (size_t)sE * LD1 + 200 + c4);
                rvA[i] = *(const float4*)(R1i + (size_t)rxE * 200 + c4);
                if (ryE >= 0) {
                    float4 rb = *(const float4*)(R1i + (size_t)ryE * 200 + c4);
                    rvA[i].x += rb.x; rvA[i].y += rb.y; rvA[i].z += rb.z; rvA[i].w += rb.w;
                }
            }
        }
        int k1 = k + 1;
#pragma unroll
        for (int i = 0; i < 4; i++) {
            bool act = (k1 < fast[i]);
            int ls = i * 16 + (k1 & 15);
            int sE = rdl(sL, ls);
            int rxE = rdl(rxL, ls);
            int ryE = act ? rdl(ryL, ls) : -1;
            wxeB[i] = act ? rdlf(wxL, ls) : 0.f;
            wyeB[i] = act ? rdlf(wyL, ls) : 0.f;
            psB[i] = make_uint2(0u, 0u);
            rvB[i] = make_float4(0.f, 0.f, 0.f, 0.f);
            if (fv && act) {
                psB[i] = *(const uint2*)(Pcat + (size_t)sE * LD1 + 200 + c4);
                rvB[i] = *(const float4*)(R1i + (size_t)rxE * 200 + c4);
                if (ryE >= 0) {
                    float4 rb = *(const float4*)(R1i + (size_t)ryE * 200 + c4);
                    rvB[i].x += rb.x; rvB[i].y += rb.y; rvB[i].z += rb.z; rvB[i].w += rb.w;
                }
            }
        }
        // --- accumulate: slot k first, then k+1 (preserves per-node order) ---
#pragma unroll
        for (int i = 0; i < 4; i++) {
            rsx[i] += wxeA[i]; rsy[i] += wyeA[i];
            b[i][0] += wxeA[i] * (bflo(psA[i].x) + rvA[i].x);
            b[i][1] += wyeA[i] * (bfhi(psA[i].x) + rvA[i].y);
            b[i][2] += wxeA[i] * (bflo(psA[i].y) + rvA[i].z);
            b[i][3] += wyeA[i] * (bfhi(psA[i].y) + rvA[i].w);
        }
#pragma unroll
        for (int i = 0; i < 4; i++) {
            rsx[i] += wxeB[i]; rsy[i] += wyeB[i];
            b[i][0] += wxeB[i] * (bflo(psB[i].x) + rvB[i].x);
            b[i][1] += wyeB[i] * (bfhi(psB[i].x) + rvB[i].y);
            b[i][2] += wxeB[i] * (bflo(psB[i].y) + rvB[i].z);
            b[i][3] += wyeB[i] * (bfhi(psB[i].y) + rvB[i].w);
        }
    }
    uint2 pt[4];
#pragma unroll
    for (int i = 0; i < 4; i++)
        pt[i] = fv ? *(const uint2*)(Pcat + (size_t)(n0 + i) * LD1 + c4) : make_uint2(0u, 0u);
#pragma unroll
    for (int i = 0; i < 4; i++) {
        unsigned short* xr = x + (size_t)(n0 + i) * KP2;
        if (fv) {
            if (deg[i] <= DTH) {
                float d0 = (rsx[i] == 0.f) ? 1e-12f : rsx[i];
                float d1 = (rsy[i] == 0.f) ? 1e-12f : rsy[i];
                float i0 = frcp(d0), i1 = frcp(d1);
                float v0 = (b[i][0] + rsx[i] * bflo(pt[i].x)) * i0;
                float v1 = (b[i][1] + rsy[i] * bfhi(pt[i].x)) * i1;
                float v2 = (b[i][2] + rsx[i] * bflo(pt[i].y)) * i0;
                float v3 = (b[i][3] + rsy[i] * bfhi(pt[i].y)) * i1;
                v0 = (v0 > 0.f) ? v0 : __expf(v0) - 1.f;
                v1 = (v1 > 0.f) ? v1 : __expf(v1) - 1.f;
                v2 = (v2 > 0.f) ? v2 : __expf(v2) - 1.f;
                v3 = (v3 > 0.f) ? v3 : __expf(v3) - 1.f;
                uint2 w;
                w.x = (uint32_t)f2bf(v0) | ((uint32_t)f2bf(v1) << 16);
                w.y = (uint32_t)f2bf(v2) | ((uint32_t)f2bf(v3) << 16);
                *(uint2*)(xr + c4) = w;
            }
        } else {
            *(uint2*)(xr + 200 + (lane - 50) * 4) = make_uint2(0u, 0u);
        }
    }
}

// ================= node layer-2 component (masked nodes) =================

static __device__ void d_node2_one(int node, int lane,
                        const int* __restrict__ rowptr, const int* __restrict__ srcs,
                        const int2* __restrict__ relpk,
                        const unsigned short* __restrict__ Qcat,
                        const unsigned short* __restrict__ Pcat,
                        const float* __restrict__ R2, const float* __restrict__ dR2,
                        const float* __restrict__ mask, float* __restrict__ out) {
    bool fv = (lane < 50);
    int c4 = lane * 4;
    int beg = rowptr[node], end = rowptr[node + 1];
    int deg = end - beg;
    int fast = (deg < 64) ? deg : 64;
    uint32_t tq = *(const uint32_t*)(Qcat + (size_t)node * LD2 + 400);
    float tdot = bflo(tq);
    int sL = 0, rxL = 0, ryL = -1;
    float WL = 0.f;
    if (lane < fast) {
        int p = beg + lane;
        sL = srcs[p];
        int2 rp = relpk[p];
        rxL = rp.x; ryL = rp.y;
        float dr = dR2[rp.x];
        if (rp.y >= 0) dr += dR2[rp.y];
        uint32_t sq = *(const uint32_t*)(Qcat + (size_t)sL * LD2 + 400);
        float pp = tdot + bfhi(sq) + dr;
        pp = (pp >= 0.f) ? pp : LRALPHA * pp;
        WL = __expf(-pp);
    }
    float c0 = 0.f, c1 = 0.f, c2 = 0.f, c3 = 0.f;
    float rs = 0.f;
    for (int j = 0; j < fast; j += 4) {
#pragma unroll
        for (int u = 0; u < 4; u++) {
            int jj = j + u;
            bool act = (jj < fast);
            int ls = act ? jj : 0;
            int sE = rdl(sL, ls);
            int rxE = rdl(rxL, ls);
            int ryE = act ? rdl(ryL, ls) : -1;
            float WE = act ? rdlf(WL, ls) : 0.f;
            uint2 qv = make_uint2(0u, 0u);
            float4 rv = make_float4(0.f, 0.f, 0.f, 0.f);
            if (fv) {
                qv = *(const uint2*)(Qcat + (size_t)sE * LD2 + 200 + c4);
                rv = *(const float4*)(R2 + (size_t)rxE * 200 + c4);
                if (ryE >= 0) {
                    float4 rb = *(const float4*)(R2 + (size_t)ryE * 200 + c4);
                    rv.x += rb.x; rv.y += rb.y; rv.z += rb.z; rv.w += rb.w;
                }
            }
            rs += WE;
            c0 += WE * (bflo(qv.x) + rv.x);
            c1 += WE * (bfhi(qv.x) + rv.y);
            c2 += WE * (bflo(qv.y) + rv.z);
            c3 += WE * (bfhi(qv.y) + rv.w);
        }
    }
    for (int p = beg + 64; p < end; p++) {
        int sE = srcs[p];
        int2 rp = relpk[p];
        float dr = dR2[rp.x];
        if (rp.y >= 0) dr += dR2[rp.y];
        uint32_t sq = *(const uint32_t*)(Qcat + (size_t)sE * LD2 + 400);
        float pp = tdot + bfhi(sq) + dr;
        pp = (pp >= 0.f) ? pp : LRALPHA * pp;
        float W = __expf(-pp);
        uint2 qv = make_uint2(0u, 0u);
        float4 rv = make_float4(0.f, 0.f, 0.f, 0.f);
        if (fv) {
            qv = *(const uint2*)(Qcat + (size_t)sE * LD2 + 200 + c4);
            rv = *(const float4*)(R2 + (size_t)rp.x * 200 + c4);
            if (rp.y >= 0) {
                float4 rb = *(const float4*)(R2 + (size_t)rp.y * 200 + c4);
                rv.x += rb.x; rv.y += rb.y; rv.z += rb.z; rv.w += rb.w;
            }
        }
        rs += W;
        c0 += W * (bflo(qv.x) + rv.x);
        c1 += W * (bfhi(qv.x) + rv.y);
        c2 += W * (bflo(qv.y) + rv.z);
        c3 += W * (bfhi(qv.y) + rv.w);
    }
    float d = (rs == 0.f) ? 1e-12f : rs;
    float idn = frcp(d);
    float mk = mask[node];
    float val0 = 0.f, val1 = 0.f, val2 = 0.f, val3 = 0.f;
    if (fv) {
        uint2 t = *(const uint2*)(Qcat + (size_t)node * LD2 + c4);
        uint2 e = *(const uint2*)(Pcat + (size_t)node * LD1 + 400 + c4);
        val0 = bflo(e.x) + mk * ((c0 + rs * bflo(t.x)) * idn);
        val1 = bfhi(e.x) + mk * ((c1 + rs * bfhi(t.x)) * idn);
        val2 = bflo(e.y) + mk * ((c2 + rs * bflo(t.y)) * idn);
        val3 = bfhi(e.y) + mk * ((c3 + rs * bfhi(t.y)) * idn);
    }
    float ss = val0 * val0 + val1 * val1 + val2 * val2 + val3 * val3;
#pragma unroll
    for (int o = 32; o > 0; o >>= 1) ss += __shfl_down(ss, o);
    ss = __shfl(ss, 0);
    float inv = frcp(fmaxf(sqrtf(ss), 1e-12f));
    if (fv) {
        *(float4*)(out + (size_t)node * 200 + c4) =
            make_float4(val0 * inv, val1 * inv, val2 * inv, val3 * inv);
    }
}

// ================= kernels =================

__global__ __launch_bounds__(256) void k_megaA(
        const int* __restrict__ tgt_el, const int* __restrict__ nhop, int* __restrict__ deg,
        const float* __restrict__ rel_emb, const float* __restrict__ att_a,
        float* __restrict__ R1i,
        const float* __restrict__ W_rel, float* __restrict__ outrel,
        const float* __restrict__ att_a2, const float* __restrict__ W_ent,
        unsigned short* __restrict__ W1,
        const float* __restrict__ out_a, const float* __restrict__ out_a2,
        unsigned short* __restrict__ W2,
        const int* __restrict__ batch, float* __restrict__ mask, float* __restrict__ oacc) {
    __shared__ __align__(16) char smem[8448];
    int bid = blockIdx.x, tid = threadIdx.x;
    if (bid < A_HIST) {
        d_hist(bid, tid, tgt_el, nhop, deg);
    } else if (bid < A_RELP) {
        d_relproj1(bid - A_HIST, tid, rel_emb, att_a, R1i);
    } else if (bid < A_MMW) {
        int i = bid - A_RELP;
        d_mm<false>(i & 3, i >> 2, smem, tid, rel_emb, 100, W_rel, 200, outrel, 200,
                    N_RELS, 200, 100);
    } else if (bid < A_PACK1) {
        d_pack1(bid - A_MMW, tid, att_a, att_a2, W_ent, W1);
    } else if (bid < A_PACK2) {
        d_pack2(bid - A_PACK1, tid, out_a, out_a2, W2);
    } else if (bid < A_MASK) {
        d_mask(bid - A_PACK2, tid, batch, mask);
    } else {
        d_ortho_part(bid - A_MASK, tid, att_a, out_a, oacc);
    }
}

__global__ void k_scan1(const int* __restrict__ deg, int* __restrict__ local,
                        int* __restrict__ bsums, int n) {
    int i = blockIdx.x * 256 + threadIdx.x;
    int v = (i < n) ? deg[i] : 0;
    int lane = threadIdx.x & 63;
    int wv = threadIdx.x >> 6;
    int x = v;
#pragma unroll
    for (int o = 1; o < 64; o <<= 1) {
        int t = __shfl_up(x, o);
        if (lane >= o) x += t;
    }
    __shared__ int wtot[4];
    if (lane == 63) wtot[wv] = x;
    __syncthreads();
    int add = 0;
    for (int k = 0; k < wv; k++) add += wtot[k];
    if (i < n) local[i] = add + x - v;
    if (threadIdx.x == 255) bsums[blockIdx.x] = add + x;
}

// scan2 (1 block) + gemm1f (1250) + dR1 (119) + R2 GEMM (32)
__global__ __launch_bounds__(256) void k_megaB(
        int* __restrict__ bsums, int nbk,
        const float* __restrict__ ent_emb, const unsigned short* __restrict__ Wcat1,
        unsigned short* __restrict__ Pcat,
        const float* __restrict__ mask, float* __restrict__ outbuf,
        const float* __restrict__ R1i, const float* __restrict__ att_a2,
        float* __restrict__ dR10, float* __restrict__ dR11,
        const float* __restrict__ outrel, const float* __restrict__ out_a,
        float* __restrict__ R2) {
    __shared__ __align__(16) char smem[33792];
    __shared__ int wtot[4];
    int bid = blockIdx.x, tid = threadIdx.x;
    if (bid == 0) {
        d_scan2(tid, wtot, bsums, nbk);
    } else if (bid < B_DR1) {
        int i = bid - B_G1F;
        d_gemm1f(i % 625, i / 625, smem, tid, ent_emb, Wcat1, Pcat, mask, outbuf);
    } else if (bid < B_R2) {
        d_dR1(bid - B_DR1, tid, R1i, att_a2, dR10, dR11);
    } else {
        int i = bid - B_R2;
        d_mm<true>(i & 3, i >> 2, smem, tid, outrel, 200, out_a + 400, 600, R2, 200,
                   N_RELS, 200, 200);
    }
}

// scan3 (157) + dotv (119)
__global__ void k_scan3d(const int* __restrict__ local, const int* __restrict__ bsums,
                         int* __restrict__ rowptr, int* __restrict__ cursor, int n, int nb,
                         const float* __restrict__ R2, const float* __restrict__ out_a2,
                         float* __restrict__ dR2) {
    int bid = blockIdx.x, tid = threadIdx.x;
    if (bid < S3_DOTV) {
        int i = bid * 256 + tid;
        if (i < n) {
            int v = local[i] + bsums[bid];
            rowptr[i] = v;
            cursor[i] = v;
        } else if (i == n) {
            rowptr[n] = bsums[nb];
        }
    } else {
        int w = (bid - S3_DOTV) * 4 + (tid >> 6);
        int lane = tid & 63;
        if (w < N_RELS) {
            const float* r = R2 + (size_t)w * 200;
            float s = 0.f;
            for (int j = lane; j < 200; j += 64) s += r[j] * out_a2[j];
#pragma unroll
            for (int o = 32; o > 0; o >>= 1) s += __shfl_down(s, o);
            if (lane == 0) dR2[w] = s;
        }
    }
}

// scatter + compact + ortho_fin
__global__ __launch_bounds__(256) void k_megaC(
        const int* __restrict__ tgt_el, const int* __restrict__ src_el,
        const int* __restrict__ etype, const int* __restrict__ nhop, int* __restrict__ cursor,
        int* __restrict__ srcs, int2* __restrict__ relpk,
        const int* __restrict__ rowptr, const float* __restrict__ mask,
        int* __restrict__ Hlist, int* __restrict__ Mlist, int* __restrict__ cnts,
        const float* __restrict__ oacc, float* __restrict__ oscalar) {
    int bid = blockIdx.x, tid = threadIdx.x;
    if (bid < C_CMP) {
        d_scatter(bid, tid, tgt_el, src_el, etype, nhop, cursor, srcs, relpk);
    } else if (bid < C_OFIN) {
        d_compact(bid - C_CMP, tid, rowptr, mask, Hlist, Mlist, cnts);
    } else {
        d_ortho_fin(tid, oacc, oscalar);
    }
}

// NODE1: layer-1 hub FIRST | layer-1 main
__global__ __launch_bounds__(256, 4) void k_node1(
                        const int* __restrict__ rowptr, const int* __restrict__ srcs,
                        const int2* __restrict__ relpk,
                        const unsigned short* __restrict__ Pcat,
                        const float* __restrict__ R1i,
                        const float* __restrict__ dR10, const float* __restrict__ dR11,
                        unsigned short* __restrict__ x,
                        const int* __restrict__ Hlist, const int* __restrict__ cnts) {
    int bid = blockIdx.x, tid = threadIdx.x;
    int lane = tid & 63;
    if (bid < N1_HUB) {
        int hw = bid * 4 + (tid >> 6);
        int cnt = cnts[0];
        for (int j = hw; j < cnt; j += HUBW) {
            int node = __builtin_amdgcn_readfirstlane(Hlist[j]);
            d_node1_one(node, lane, rowptr, srcs, relpk, Pcat, R1i, dR10, dR11, x);
        }
    } else {
        int wid = __builtin_amdgcn_readfirstlane((bid - N1_HUB) * 4 + (tid >> 6));
        d_node1_main(wid, lane, rowptr, srcs, relpk, Pcat, R1i, dR10, dR11, x);
    }
}

__global__ __launch_bounds__(256) void k_gemm2(const unsigned short* __restrict__ A,
                                               const unsigned short* __restrict__ B,
                                               unsigned short* __restrict__ C,
                                               int ldc, int N, int gPerSplit) {
    __shared__ __align__(16) char smem[8192];
    d_gemm<KP2>(blockIdx.x, blockIdx.y, smem, threadIdx.x, A, B, C, ldc, N, gPerSplit);
}

// node2 hub: full-wave aggregation + final fuse for masked nodes only
__global__ __launch_bounds__(256, 4) void k_node2h(
                        const int* __restrict__ rowptr, const int* __restrict__ srcs,
                        const int2* __restrict__ relpk,
                        const unsigned short* __restrict__ Qcat,
                        const unsigned short* __restrict__ Pcat,
                        const float* __restrict__ R2, const float* __restrict__ dR2,
                        const float* __restrict__ mask,
                        const int* __restrict__ Mlist, const int* __restrict__ cnts,
                        float* __restrict__ out) {
    int tid = threadIdx.x;
    int lane = tid & 63;
    int hw = blockIdx.x * 4 + (tid >> 6);
    int cnt = cnts[1];
    for (int j = hw; j < cnt; j += HUBW) {
        int node = __builtin_amdgcn_readfirstlane(Mlist[j]);
        d_node2_one(node, lane, rowptr, srcs, relpk, Qcat, Pcat, R2, dR2, mask, out);
    }
}

// ================= launch =================
extern "C" void kernel_launch(void* const* d_in, const int* in_sizes, int n_in,
                              void* d_out, int out_size, void* d_ws, size_t ws_size,
                              hipStream_t stream) {
    const int* edge_list = (const int*)d_in[0];
    const int* edge_type = (const int*)d_in[1];
    const int* batch     = (const int*)d_in[2];
    const int* nhop      = (const int*)d_in[3];
    const float* ent_emb = (const float*)d_in[4];
    const float* rel_emb = (const float*)d_in[5];
    const float* W_ent   = (const float*)d_in[6];
    const float* W_rel   = (const float*)d_in[7];
    const float* att_a   = (const float*)d_in[8];
    const float* att_a2  = (const float*)d_in[9];
    const float* out_a   = (const float*)d_in[10];
    const float* out_a2  = (const float*)d_in[11];
    float* out = (float*)d_out;
    const int* tgt_el = edge_list;
    const int* src_el = edge_list + E0;

    char* ws = (char*)d_ws;
    size_t o = 0;
    auto alloc = [&](size_t nbytes) -> char* {
        char* p = ws + o;
        o += (nbytes + 255) & ~(size_t)255;
        return p;
    };
    unsigned short* x_bf    = (unsigned short*)alloc((size_t)N_NODES * KP2 * 2);
    unsigned short* Pcat    = (unsigned short*)alloc((size_t)N_NODES * LD1 * 2);
    unsigned short* Qcat    = (unsigned short*)alloc((size_t)N_NODES * LD2 * 2);
    unsigned short* Wcat1   = (unsigned short*)alloc((size_t)NPAD1 * KP1 * 2);
    unsigned short* Wcat2   = (unsigned short*)alloc((size_t)NPAD2 * KP2 * 2);
    float* R1i   = (float*)alloc(474u * 200 * 4);
    float* R2    = (float*)alloc(474u * 200 * 4);
    float* dR10  = (float*)alloc(474u * 4);
    float* dR11  = (float*)alloc(474u * 4);
    float* dR2   = (float*)alloc(474u * 4);
    int* rowptr  = (int*)alloc((N_NODES + 1) * 4);
    int* cursor  = (int*)alloc(N_NODES * 4);
    int* srcs    = (int*)alloc((size_t)NE * 4);
    int2* relpk  = (int2*)alloc((size_t)NE * 8);
    float* mask  = (float*)alloc(N_NODES * 4);
    int* scanloc = (int*)alloc(N_NODES * 4);
    int* bsums   = (int*)alloc(260 * 4);
    float* oacc  = (float*)alloc(9 * 4);
    int* Hlist   = (int*)alloc(N_NODES * 4);
    int* Mlist   = (int*)alloc(N_NODES * 4);
    int* cnts    = (int*)alloc(2 * 4);

    hipMemsetAsync(cursor, 0, N_NODES * 4, stream);
    hipMemsetAsync(mask, 0, N_NODES * 4, stream);
    hipMemsetAsync(oacc, 0, 9 * 4, stream);
    hipMemsetAsync(cnts, 0, 2 * 4, stream);

    // 1) hist + relproj1 + out_relation GEMM + pack1 + pack2 + mask + ortho partials
    k_megaA<<<A_TOT, 256, 0, stream>>>(tgt_el, nhop, cursor,
                                       rel_emb, att_a, R1i,
                                       W_rel, out + 8000000,
                                       att_a2, W_ent, Wcat1,
                                       out_a, out_a2, Wcat2,
                                       batch, mask, oacc);
    // 2) CSR scan phase 1
    k_scan1<<<157, 256, 0, stream>>>(cursor, scanloc, bsums, N_NODES);
    // 3) scan2 + layer-1 GEMM (fused l2norm + unmasked out-write) + dR1 + R2 GEMM
    k_megaB<<<B_TOT, 256, 0, stream>>>(bsums, 157, ent_emb, Wcat1, Pcat, mask, out,
                                       R1i, att_a2, dR10, dR11,
                                       out + 8000000, out_a, R2);
    // 4) scan phase 3 + dR2 dotv
    k_scan3d<<<S3_TOT, 256, 0, stream>>>(scanloc, bsums, rowptr, cursor, N_NODES, 157,
                                         R2, out_a2, dR2);
    // 5) scatter + compact + ortho finalize
    k_megaC<<<C_TOT, 256, 0, stream>>>(tgt_el, src_el, edge_type, nhop, cursor,
                                       srcs, relpk, rowptr, mask, Hlist, Mlist, cnts,
                                       oacc, out + 8094800);
    // 6) layer-1 aggregation (hub first, then interleaved main)
    k_node1<<<N1_TOT, 256, 0, stream>>>(rowptr, srcs, relpk, Pcat, R1i, dR10, dR11,
                                        x_bf, Hlist, cnts);
    // 7) layer-2 GEMM
    k_gemm2<<<dim3(625, 2), 256, 0, stream>>>(x_bf, Wcat2, Qcat, LD2, 416, 4);
    // 8) layer-2 masked-node aggregation + final fuse
    k_node2h<<<512, 256, 0, stream>>>(rowptr, srcs, relpk, Qcat, Pcat, R2, dR2,
                                      mask, Mlist, cnts, out);
}

// Round 12
// 309.569 us; speedup vs baseline: 1.1188x; 1.0316x over previous
//
#include <hip/hip_runtime.h>
#include <cstdint>
#include <cstddef>
#include <math.h>

#define N_NODES 40000
#define N_RELS  474
#define E0      100000
#define NE      130000
#define NB      8192
#define LRALPHA 0.2f

#define KP1 128
#define KP2 256
// Pcat cols: [0:200) Pt interleaved | [200:400) Ps interleaved | [400:600) entW | [600:604) dots | pad
#define LD1 608
// Qcat cols: [0:200) Qt | [200:400) Qs | 400 dqt | 401 dqs | pad
#define LD2 416
#define NPAD1 640
#define NPAD2 448
#define DTH 16
#define HUBW 2048

// MEGA-A block ranges (raw-input-only regions)
#define A_HIST   508
#define A_RELP   (A_HIST + 119)
#define A_MMW    (A_RELP + 32)
#define A_PACK1  (A_MMW + 320)
#define A_PACK2  (A_PACK1 + 448)
#define A_MASK   (A_PACK2 + 32)
#define A_TOT    (A_MASK + 128)
// MEGA-B: scan2 (1) | gemm1f (1250) | dR1 (119) | R2 GEMM (32)
#define B_G1F    1
#define B_DR1    (B_G1F + 1250)
#define B_R2     (B_DR1 + 119)
#define B_TOT    (B_R2 + 32)
// SCAN3D: scan3 (157) | dotv (119)
#define S3_DOTV  157
#define S3_TOT   (S3_DOTV + 119)
// MEGA-C: scatter | compact | ortho_fin
#define C_CMP    508
#define C_OFIN   (C_CMP + 157)
#define C_TOT    (C_OFIN + 1)
// NODE1: layer-1 hub FIRST (longest waves start at t=0) | layer-1 main interleave
#define N1_HUB   512
#define N1_TOT   (N1_HUB + 2500)

typedef __attribute__((ext_vector_type(8))) short short8;
typedef __attribute__((ext_vector_type(4))) float floatx4;

static __device__ __forceinline__ unsigned short f2bf(float f) {
    union { float f; uint32_t u; } v; v.f = f;
    uint32_t r = v.u + 0x7fff + ((v.u >> 16) & 1);
    return (unsigned short)(r >> 16);
}
static __device__ __forceinline__ float bf2f(unsigned short h) {
    union { uint32_t u; float f; } v; v.u = ((uint32_t)h) << 16;
    return v.f;
}
static __device__ __forceinline__ float bflo(uint32_t u) { return bf2f((unsigned short)(u & 0xffff)); }
static __device__ __forceinline__ float bfhi(uint32_t u) { return bf2f((unsigned short)(u >> 16)); }

static __device__ __forceinline__ int rdl(int v, int l) {
    return __builtin_amdgcn_readlane(v, l);
}
static __device__ __forceinline__ float rdlf(float v, int l) {
    return __int_as_float(__builtin_amdgcn_readlane(__float_as_int(v), l));
}
static __device__ __forceinline__ float frcp(float x) { return __builtin_amdgcn_rcpf(x); }

// ================= device components =================

static __device__ void d_hist(int bid, int tid, const int* __restrict__ tgt_el,
                              const int* __restrict__ nhop, int* __restrict__ deg) {
    int e = bid * 256 + tid;
    if (e >= NE) return;
    int t = (e < E0) ? tgt_el[e] : nhop[(size_t)(e - E0) * 4 + 3];
    atomicAdd(&deg[t], 1);
}

static __device__ void d_mask(int bid, int tid, const int* __restrict__ batch,
                              float* __restrict__ mask, int* __restrict__ cnts) {
    if (bid == 0 && tid < 2) cnts[tid] = 0;   // zero cnts for megaC's compact (2 kernels later)
    int i = bid * 256 + tid;
    if (i < NB) mask[batch[(size_t)i * 3 + 2]] = 1.0f;
}

static __device__ void d_ortho_part(int bid, int tid, const float* __restrict__ att_a,
                                    const float* __restrict__ out_a, float* __restrict__ accum) {
    float loc[9] = {0,0,0,0,0,0,0,0,0};
    for (int i = bid * 256 + tid; i < 90000; i += 128 * 256) {
        int seg, li;
        const float* base;
        int L;
        if (i < 15000)      { seg = 0; li = i;          base = att_a;         L = 15000; }
        else if (i < 30000) { seg = 1; li = i - 15000;  base = att_a + 30000; L = 15000; }
        else                { seg = 2; li = i - 30000;  base = out_a;         L = 60000; }
        float a = base[li], b = base[L + li];
        loc[seg * 3 + 0] += a * a;
        loc[seg * 3 + 1] += b * b;
        loc[seg * 3 + 2] += a * b;
    }
    int lane = tid & 63;
#pragma unroll
    for (int q = 0; q < 9; q++) {
        float s = loc[q];
#pragma unroll
        for (int o = 32; o > 0; o >>= 1) s += __shfl_down(s, o);
        if (lane == 0 && s != 0.f) atomicAdd(&accum[q], s);
    }
}

static __device__ void d_scan2(int tid, int* wtot, int* __restrict__ bsums, int nb) {
    int v = (tid < nb) ? bsums[tid] : 0;
    int lane = tid & 63, wv = tid >> 6;
    int x = v;
#pragma unroll
    for (int o = 1; o < 64; o <<= 1) {
        int t = __shfl_up(x, o);
        if (lane >= o) x += t;
    }
    if (lane == 63) wtot[wv] = x;
    __syncthreads();
    int add = 0;
    for (int k = 0; k < wv; k++) add += wtot[k];
    __syncthreads();
    if (tid < nb) bsums[tid] = add + x - v;
    if (tid == 255) bsums[nb] = add + x;
}

// ---- pack layer-1 B matrix (uvec rows computed inline) ----
static __device__ void d_pack1(int bid, int tid, const float* __restrict__ att_a,
                               const float* __restrict__ att_a2,
                               const float* __restrict__ W_ent,
                               unsigned short* __restrict__ W) {
    int idx = bid * 256 + tid;
    if (idx >= NPAD1 * KP1) return;
    int j = idx & 7;
    int lane = (idx >> 3) & 63;
    int u = idx >> 9;
    int ks = u & 3;
    int t = u >> 2;
    int r = t * 16 + (lane & 15);
    int k = ks * 32 + (lane >> 4) * 8 + j;
    float val = 0.f;
    if (k < 100) {
        if (r < 200) {
            int i = r >> 1, h = r & 1;
            val = att_a[h * 30000 + i * 300 + k];
        } else if (r < 400) {
            int rr = r - 200, i = rr >> 1, h = rr & 1;
            val = att_a[h * 30000 + i * 300 + 100 + k];
        } else if (r < 600) {
            val = W_ent[k * 200 + (r - 400)];
        } else if (r < 604) {
            int v = r - 600, head = v >> 1, part = v & 1;
            const float* base = att_a + head * 30000 + part * 100 + k;
            const float* a2v = att_a2 + head * 100;
            float s = 0.f;
            for (int n = 0; n < 100; n++) s += a2v[n] * base[n * 300];
            val = s;
        }
    }
    W[idx] = f2bf(val);
}

// ---- pack layer-2 B matrix (uvec rows computed inline) ----
static __device__ void d_pack2(int bid, int tid, const float* __restrict__ out_a,
                               const float* __restrict__ out_a2,
                               unsigned short* __restrict__ W) {
    int idx = bid * 256 + tid;
    if (idx >= NPAD2 * KP2) return;
    int j = idx & 7;
    int lane = (idx >> 3) & 63;
    int u = idx >> 9;
    int ks = u & 7;
    int t = u >> 3;
    int r = t * 16 + (lane & 15);
    int k = ks * 32 + (lane >> 4) * 8 + j;
    float val = 0.f;
    if (k < 200) {
        int klog = (k & 1) * 100 + (k >> 1);
        if (r < 200)       val = out_a[r * 600 + klog];
        else if (r < 400)  val = out_a[(r - 200) * 600 + 200 + klog];
        else if (r == 400) {
            float s = 0.f;
            for (int n = 0; n < 200; n++) s += out_a2[n] * out_a[n * 600 + klog];
            val = s;
        } else if (r == 401) {
            float s = 0.f;
            for (int n = 0; n < 200; n++) s += out_a2[n] * out_a[n * 600 + 200 + klog];
            val = s;
        }
    }
    W[idx] = f2bf(val);
}

static __device__ void d_scatter(int bid, int tid, const int* __restrict__ tgt_el,
                                 const int* __restrict__ src_el, const int* __restrict__ etype,
                                 const int* __restrict__ nhop, int* __restrict__ cursor,
                                 int* __restrict__ srcs, int2* __restrict__ relpk) {
    int e = bid * 256 + tid;
    if (e >= NE) return;
    int t, s, r1, r2;
    if (e < E0) {
        t = tgt_el[e]; s = src_el[e]; r1 = etype[e]; r2 = -1;
    } else {
        const int* nh = nhop + (size_t)(e - E0) * 4;
        t = nh[3]; s = nh[0]; r1 = nh[1]; r2 = nh[2];
    }
    int p = atomicAdd(&cursor[t], 1);
    srcs[p] = s;
    relpk[p] = make_int2(r1, r2);
}

static __device__ void d_compact(int bid, int tid, const int* __restrict__ rowptr,
                                 const float* __restrict__ mask,
                                 int* __restrict__ Hlist, int* __restrict__ Mlist,
                                 int* __restrict__ cnts) {
    int i = bid * 256 + tid;
    if (i >= N_NODES) return;
    int deg = rowptr[i + 1] - rowptr[i];
    if (deg > DTH) { int p = atomicAdd(&cnts[0], 1); Hlist[p] = i; }
    if (mask[i] != 0.f) { int p = atomicAdd(&cnts[1], 1); Mlist[p] = i; }
}

// ---- bf16 MFMA GEMM (fragment-ordered B) — layer-2 ----
template <int KP>
static __device__ void d_gemm(int bx, int by, char* smem_raw, int tid,
                              const unsigned short* __restrict__ A,
                              const unsigned short* __restrict__ B,
                              unsigned short* __restrict__ C,
                              int ldc, int N, int gPerSplit) {
    constexpr int KSTEPS = KP / 32;
    constexpr int KCH = KSTEPS / 4;
    unsigned short (*cbuf)[16][64] = (unsigned short (*)[16][64])smem_raw;
    int wave = tid >> 6;
    int lane = tid & 63;
    int quad = lane >> 4;
    int l16 = lane & 15;
    int m0 = bx * 64 + wave * 16;
    short8 afrag[KSTEPS];
    const unsigned short* arow = A + (size_t)(m0 + l16) * KP + quad * 8;
#pragma unroll
    for (int ks = 0; ks < KSTEPS; ks++)
        afrag[ks] = *(const short8*)(arow + ks * 32);

    int Gtot = (N + 63) >> 6;
    int g0 = by * gPerSplit;
    int g1 = g0 + gPerSplit;
    if (g1 > Gtot) g1 = Gtot;
    for (int g = g0; g < g1; g++) {
        int nb = g << 6;
        const unsigned short* bgrp = B + (((size_t)(g << 2) * KSTEPS) << 9) + (lane << 3);
        floatx4 acc[4];
#pragma unroll
        for (int t = 0; t < 4; t++) acc[t] = (floatx4){0.f, 0.f, 0.f, 0.f};
#pragma unroll
        for (int ch = 0; ch < KCH; ch++) {
            short8 bf[4][4];
#pragma unroll
            for (int t = 0; t < 4; t++)
#pragma unroll
                for (int k = 0; k < 4; k++)
                    bf[t][k] = *(const short8*)(bgrp + ((size_t)(t * KSTEPS + ch * 4 + k) << 9));
#pragma unroll
            for (int k = 0; k < 4; k++)
#pragma unroll
                for (int t = 0; t < 4; t++)
                    acc[t] = __builtin_amdgcn_mfma_f32_16x16x32_bf16(afrag[ch * 4 + k], bf[t][k], acc[t], 0, 0, 0);
        }
        int r0 = quad * 4;
#pragma unroll
        for (int t = 0; t < 4; t++)
#pragma unroll
            for (int i = 0; i < 4; i++)
                cbuf[wave][r0 + i][t * 16 + l16] = f2bf(acc[t][i]);
        int colsA = N - nb; if (colsA > 64) colsA = 64;
        int cols8 = colsA >> 3;
        int sh = (colsA >= 64) ? 3 : 2;
        int nchunks = cols8 << 4;
        for (int c = lane; c < nchunks; c += 64) {
            int row = c >> sh;
            int col8 = (c & (cols8 - 1)) << 3;
            *(uint4*)(C + (size_t)(m0 + row) * ldc + nb + col8) =
                *(const uint4*)&cbuf[wave][row][col8];
        }
    }
}

// ---- layer-1 GEMM: fused row-l2norm (raw fp32 in) + fused unmasked out-write (by==1) ----
static __device__ void d_gemm1f(int bx, int by, char* smem_raw, int tid,
                                const float* __restrict__ ent,
                                const unsigned short* __restrict__ B,
                                unsigned short* __restrict__ C,
                                const float* __restrict__ mask,
                                float* __restrict__ out) {
    float (*rows)[105] = (float (*)[105])smem_raw;              // 26880 B (consumed pre-loop)
    float* invn = (float*)(smem_raw + 64 * 105 * 4);            // +256 B  (consumed pre-loop)
    unsigned short (*entw)[200] = (unsigned short (*)[200])(smem_raw + 8192);  // 25600 B
    int m0 = bx * 64;
    for (int idx = tid; idx < 6400; idx += 256) {
        int r = idx / 100, c = idx - r * 100;
        rows[r][c] = ent[(size_t)(m0 + r) * 100 + c];
    }
    __syncthreads();
    {
        int r = tid >> 2, q = tid & 3;
        const float* rp = rows[r] + q * 25;
        float s = 0.f;
#pragma unroll
        for (int c = 0; c < 25; c++) { float v = rp[c]; s += v * v; }
        s += __shfl_xor(s, 1);
        s += __shfl_xor(s, 2);
        if (q == 0) invn[r] = 1.f / fmaxf(sqrtf(s), 1e-12f);
    }
    __syncthreads();
    int wave = tid >> 6;
    int lane = tid & 63;
    int quad = lane >> 4;
    int l16 = lane & 15;
    int rr = wave * 16 + l16;
    float inv = invn[rr];
    short8 afrag[4];
#pragma unroll
    for (int ks = 0; ks < 4; ks++) {
        short8 f;
#pragma unroll
        for (int j = 0; j < 8; j++) {
            int col = ks * 32 + quad * 8 + j;
            f[j] = (col < 100) ? (short)f2bf(rows[rr][col] * inv) : (short)0;
        }
        afrag[ks] = f;
    }
    __syncthreads();   // rows region reused as cbuf below
    unsigned short (*cbuf)[16][64] = (unsigned short (*)[16][64])smem_raw;
    int mo0 = m0 + wave * 16;
    int g0 = by * 5, g1 = g0 + 5;
    if (g1 > 10) g1 = 10;
    for (int g = g0; g < g1; g++) {
        int nb = g << 6;
        const unsigned short* bgrp = B + (((size_t)(g << 2) * 4) << 9) + (lane << 3);
        floatx4 acc[4];
#pragma unroll
        for (int t = 0; t < 4; t++) acc[t] = (floatx4){0.f, 0.f, 0.f, 0.f};
        short8 bf[4][4];
#pragma unroll
        for (int t = 0; t < 4; t++)
#pragma unroll
            for (int k = 0; k < 4; k++)
                bf[t][k] = *(const short8*)(bgrp + ((size_t)(t * 4 + k) << 9));
#pragma unroll
        for (int k = 0; k < 4; k++)
#pragma unroll
            for (int t = 0; t < 4; t++)
                acc[t] = __builtin_amdgcn_mfma_f32_16x16x32_bf16(afrag[k], bf[t][k], acc[t], 0, 0, 0);
        int r0 = quad * 4;
#pragma unroll
        for (int t = 0; t < 4; t++)
#pragma unroll
            for (int i = 0; i < 4; i++)
                cbuf[wave][r0 + i][t * 16 + l16] = f2bf(acc[t][i]);
        int colsA = 608 - nb; if (colsA > 64) colsA = 64;
        int cols8 = colsA >> 3;
        int sh = (colsA >= 64) ? 3 : 2;
        int nchunks = cols8 << 4;
        for (int c = lane; c < nchunks; c += 64) {
            int row = c >> sh;
            int col8 = (c & (cols8 - 1)) << 3;
            *(uint4*)(C + (size_t)(mo0 + row) * LD1 + nb + col8) =
                *(const uint4*)&cbuf[wave][row][col8];
        }
        // keep entW window (cols [400,600)) for fused out-write
        if (by == 1) {
            int cg = nb + lane;
            if (cg >= 400 && cg < 600) {
#pragma unroll
                for (int i = 0; i < 16; i++)
                    entw[wave * 16 + i][cg - 400] = cbuf[wave][i][lane];
            }
        }
    }
    // fused layer-2 unmasked streaming output: out[node] = l2norm(entW row)
    if (by == 1) {
        bool fv = (lane < 50);
        int c4 = lane * 4;
        for (int i = 0; i < 16; i++) {
            int row = wave * 16 + i;
            int node = m0 + row;
            float mk = mask[node];
            if (mk != 0.f) continue;    // masked nodes written by node2h
            float v0 = 0.f, v1 = 0.f, v2 = 0.f, v3 = 0.f;
            if (fv) {
                v0 = bf2f(entw[row][c4 + 0]);
                v1 = bf2f(entw[row][c4 + 1]);
                v2 = bf2f(entw[row][c4 + 2]);
                v3 = bf2f(entw[row][c4 + 3]);
            }
            float ss = v0 * v0 + v1 * v1 + v2 * v2 + v3 * v3;
#pragma unroll
            for (int o = 32; o > 0; o >>= 1) ss += __shfl_down(ss, o);
            ss = __shfl(ss, 0);
            float iv = frcp(fmaxf(sqrtf(ss), 1e-12f));
            if (fv) {
                *(float4*)(out + (size_t)node * 200 + c4) =
                    make_float4(v0 * iv, v1 * iv, v2 * iv, v3 * iv);
            }
        }
    }
}

// ---- generic tiled fp32 matmul (474-row cases) ----
template <bool BT>
static __device__ void d_mm(int bx, int by, char* smem_raw, int tid,
                            const float* __restrict__ A, int lda,
                            const float* __restrict__ B, int ldb,
                            float* __restrict__ C, int ldc,
                            int M, int N, int K) {
    float (*As)[65] = (float (*)[65])smem_raw;
    float (*Bs)[65] = (float (*)[65])(smem_raw + 16 * 65 * 4);
    int tx = tid & 15, ty = tid >> 4;
    int m0 = by * 64, n0 = bx * 64;
    float acc[4][4] = {};
    for (int k0 = 0; k0 < K; k0 += 16) {
        {
            int r = tid >> 2;
            int c4 = (tid & 3) * 4;
            int m = m0 + r;
#pragma unroll
            for (int u = 0; u < 4; u++) {
                int k = k0 + c4 + u;
                As[c4 + u][r] = (m < M && k < K) ? A[(size_t)m * lda + k] : 0.f;
            }
        }
        if (BT) {
            int r = tid >> 2;
            int c4 = (tid & 3) * 4;
            int n = n0 + r;
#pragma unroll
            for (int u = 0; u < 4; u++) {
                int k = k0 + c4 + u;
                Bs[c4 + u][r] = (n < N && k < K) ? B[(size_t)n * ldb + k] : 0.f;
            }
        } else {
            int kk = tid >> 4;
            int nn4 = (tid & 15) * 4;
            int k = k0 + kk;
#pragma unroll
            for (int u = 0; u < 4; u++) {
                int n = n0 + nn4 + u;
                Bs[kk][nn4 + u] = (k < K && n < N) ? B[(size_t)k * ldb + n] : 0.f;
            }
        }
        __syncthreads();
#pragma unroll
        for (int k = 0; k < 16; k++) {
            float a[4], b[4];
#pragma unroll
            for (int i = 0; i < 4; i++) a[i] = As[k][ty + 16 * i];
#pragma unroll
            for (int j = 0; j < 4; j++) b[j] = Bs[k][tx + 16 * j];
#pragma unroll
            for (int i = 0; i < 4; i++)
#pragma unroll
                for (int j = 0; j < 4; j++) acc[i][j] += a[i] * b[j];
        }
        __syncthreads();
    }
#pragma unroll
    for (int i = 0; i < 4; i++) {
        int m = m0 + ty + 16 * i;
        if (m >= M) continue;
#pragma unroll
        for (int j = 0; j < 4; j++) {
            int n = n0 + tx + 16 * j;
            if (n < N) C[(size_t)m * ldc + n] = acc[i][j];
        }
    }
}

static __device__ void d_relproj1(int bid, int tid, const float* __restrict__ rel_emb,
                                  const float* __restrict__ att_a, float* __restrict__ R1i) {
    int w = (bid * 256 + tid) >> 6;
    int lane = tid & 63;
    if (w >= N_RELS) return;
    const float* re = rel_emb + (size_t)w * 100;
    float2* dst = (float2*)(R1i + (size_t)w * 200);
    for (int f = lane; f < 100; f += 64) {
        const float* a0 = att_a + f * 300 + 200;
        const float* a1 = att_a + 30000 + f * 300 + 200;
        float s0 = 0.f, s1 = 0.f;
        for (int k = 0; k < 100; k++) {
            float rk = re[k];
            s0 += rk * a0[k];
            s1 += rk * a1[k];
        }
        dst[f] = make_float2(s0, s1);
    }
}

static __device__ void d_dR1(int bid, int tid, const float* __restrict__ R1i,
                             const float* __restrict__ att_a2,
                             float* __restrict__ dR10, float* __restrict__ dR11) {
    int w = (bid * 256 + tid) >> 6;
    int lane = tid & 63;
    if (w >= N_RELS) return;
    const float2* row = (const float2*)(R1i + (size_t)w * 200);
    float s0 = 0.f, s1 = 0.f;
    for (int f = lane; f < 100; f += 64) {
        float2 v = row[f];
        s0 += v.x * att_a2[f];
        s1 += v.y * att_a2[100 + f];
    }
#pragma unroll
    for (int o = 32; o > 0; o >>= 1) {
        s0 += __shfl_down(s0, o);
        s1 += __shfl_down(s1, o);
    }
    if (lane == 0) { dR10[w] = s0; dR11[w] = s1; }
}

static __device__ void d_ortho_fin(int tid, const float* __restrict__ accum,
                                   float* __restrict__ out_scalar) {
    if (tid != 0) return;
    float total = 0.f;
#pragma unroll
    for (int m = 0; m < 3; m++) {
        float s0 = accum[m * 3 + 0], s1 = accum[m * 3 + 1], sc = accum[m * 3 + 2];
        float c = sc / (fmaxf(sqrtf(s0), 1e-12f) * fmaxf(sqrtf(s1), 1e-12f));
        total += 0.01f * 2.f * c * c;
    }
    out_scalar[0] = total;
}

// ================= node layer-1 components =================

static __device__ void d_node1_one(int node, int lane,
                        const int* __restrict__ rowptr, const int* __restrict__ srcs,
                        const int2* __restrict__ relpk,
                        const unsigned short* __restrict__ Pcat,
                        const float* __restrict__ R1i,
                        const float* __restrict__ dR10, const float* __restrict__ dR11,
                        unsigned short* __restrict__ x) {
    bool fv = (lane < 50);
    int c4 = lane * 4;
    int beg = rowptr[node], end = rowptr[node + 1];
    int deg = end - beg;
    int fast = (deg < 64) ? deg : 64;
    uint2 td = *(const uint2*)(Pcat + (size_t)node * LD1 + 600);
    float t0h = bflo(td.x), t1h = bflo(td.y);
    int sL = 0, rxL = 0, ryL = -1;
    float wxL = 0.f, wyL = 0.f;
    if (lane < fast) {
        int p = beg + lane;
        sL = srcs[p];
        int2 rp = relpk[p];
        rxL = rp.x; ryL = rp.y;
        float dr0 = dR10[rp.x], dr1 = dR11[rp.x];
        if (rp.y >= 0) { dr0 += dR10[rp.y]; dr1 += dR11[rp.y]; }
        uint2 sd = *(const uint2*)(Pcat + (size_t)sL * LD1 + 600);
        float p0 = t0h + bfhi(sd.x) + dr0;
        float p1 = t1h + bfhi(sd.y) + dr1;
        p0 = (p0 >= 0.f) ? p0 : LRALPHA * p0;
        p1 = (p1 >= 0.f) ? p1 : LRALPHA * p1;
        wxL = __expf(-p0);
        wyL = __expf(-p1);
    }
    float b0 = 0.f, b1 = 0.f, b2 = 0.f, b3 = 0.f;
    float rs0 = 0.f, rs1 = 0.f;
    for (int j = 0; j < fast; j += 4) {
#pragma unroll
        for (int u = 0; u < 4; u++) {
            int jj = j + u;
            bool act = (jj < fast);
            int ls = act ? jj : 0;
            int sE = rdl(sL, ls);
            int rxE = rdl(rxL, ls);
            int ryE = act ? rdl(ryL, ls) : -1;
            float wxE = act ? rdlf(wxL, ls) : 0.f;
            float wyE = act ? rdlf(wyL, ls) : 0.f;
            uint2 ps = make_uint2(0u, 0u);
            float4 rv = make_float4(0.f, 0.f, 0.f, 0.f);
            if (fv) {
                ps = *(const uint2*)(Pcat + (size_t)sE * LD1 + 200 + c4);
                rv = *(const float4*)(R1i + (size_t)rxE * 200 + c4);
                if (ryE >= 0) {
                    float4 rb = *(const float4*)(R1i + (size_t)ryE * 200 + c4);
                    rv.x += rb.x; rv.y += rb.y; rv.z += rb.z; rv.w += rb.w;
                }
            }
            rs0 += wxE; rs1 += wyE;
            b0 += wxE * (bflo(ps.x) + rv.x);
            b1 += wyE * (bfhi(ps.x) + rv.y);
            b2 += wxE * (bflo(ps.y) + rv.z);
            b3 += wyE * (bfhi(ps.y) + rv.w);
        }
    }
    for (int p = beg + 64; p < end; p++) {
        int sE = srcs[p];
        int2 rp = relpk[p];
        float dr0 = dR10[rp.x], dr1 = dR11[rp.x];
        if (rp.y >= 0) { dr0 += dR10[rp.y]; dr1 += dR11[rp.y]; }
        uint2 sd = *(const uint2*)(Pcat + (size_t)sE * LD1 + 600);
        float p0 = t0h + bfhi(sd.x) + dr0;
        float p1 = t1h + bfhi(sd.y) + dr1;
        p0 = (p0 >= 0.f) ? p0 : LRALPHA * p0;
        p1 = (p1 >= 0.f) ? p1 : LRALPHA * p1;
        float wx = __expf(-p0), wy = __expf(-p1);
        uint2 ps = make_uint2(0u, 0u);
        float4 rv = make_float4(0.f, 0.f, 0.f, 0.f);
        if (fv) {
            ps = *(const uint2*)(Pcat + (size_t)sE * LD1 + 200 + c4);
            rv = *(const float4*)(R1i + (size_t)rp.x * 200 + c4);
            if (rp.y >= 0) {
                float4 rb = *(const float4*)(R1i + (size_t)rp.y * 200 + c4);
                rv.x += rb.x; rv.y += rb.y; rv.z += rb.z; rv.w += rb.w;
            }
        }
        rs0 += wx; rs1 += wy;
        b0 += wx * (bflo(ps.x) + rv.x);
        b1 += wy * (bfhi(ps.x) + rv.y);
        b2 += wx * (bflo(ps.y) + rv.z);
        b3 += wy * (bfhi(ps.y) + rv.w);
    }
    float d0 = (rs0 == 0.f) ? 1e-12f : rs0;
    float d1 = (rs1 == 0.f) ? 1e-12f : rs1;
    float i0 = frcp(d0), i1 = frcp(d1);
    if (fv) {
        uint2 pt = *(const uint2*)(Pcat + (size_t)node * LD1 + c4);
        float v0 = (b0 + rs0 * bflo(pt.x)) * i0;
        float v1 = (b1 + rs1 * bfhi(pt.x)) * i1;
        float v2 = (b2 + rs0 * bflo(pt.y)) * i0;
        float v3 = (b3 + rs1 * bfhi(pt.y)) * i1;
        v0 = (v0 > 0.f) ? v0 : __expf(v0) - 1.f;
        v1 = (v1 > 0.f) ? v1 : __expf(v1) - 1.f;
        v2 = (v2 > 0.f) ? v2 : __expf(v2) - 1.f;
        v3 = (v3 > 0.f) ? v3 : __expf(v3) - 1.f;
        uint2 w;
        w.x = (uint32_t)f2bf(v0) | ((uint32_t)f2bf(v1) << 16);
        w.y = (uint32_t)f2bf(v2) | ((uint32_t)f2bf(v3) << 16);
        unsigned short* xr = x + (size_t)node * KP2;
        *(uint2*)(xr + c4) = w;
    }
}

// ---- 4-nodes-per-wave interleaved main path (deg<=DTH), k-loop unrolled x2 ----
static __device__ void d_node1_main(int wid, int lane,
                        const int* __restrict__ rowptr, const int* __restrict__ srcs,
                        const int2* __restrict__ relpk,
                        const unsigned short* __restrict__ Pcat,
                        const float* __restrict__ R1i,
                        const float* __restrict__ dR10, const float* __restrict__ dR11,
                        unsigned short* __restrict__ x) {
    int n0 = wid * 4;
    if (n0 >= N_NODES) return;
    bool fv = (lane < 50);
    int c4 = lane * 4;
    int rp = (lane < 5) ? rowptr[n0 + lane] : 0;
    int bnd0 = rdl(rp, 0), bnd1 = rdl(rp, 1), bnd2 = rdl(rp, 2), bnd3 = rdl(rp, 3), bnd4 = rdl(rp, 4);
    int beg[4] = {bnd0, bnd1, bnd2, bnd3};
    int end[4] = {bnd1, bnd2, bnd3, bnd4};
    int deg[4], fast[4];
#pragma unroll
    for (int i = 0; i < 4; i++) {
        deg[i] = end[i] - beg[i];
        fast[i] = (deg[i] <= DTH) ? deg[i] : 0;
    }
    int li = lane >> 4, lk = lane & 15;
    int begL = (li == 0) ? bnd0 : (li == 1) ? bnd1 : (li == 2) ? bnd2 : bnd3;
    int endL = (li == 0) ? bnd1 : (li == 1) ? bnd2 : (li == 2) ? bnd3 : bnd4;
    int degL = endL - begL;
    int fastL = (degL <= DTH) ? degL : 0;
    uint2 tdL = *(const uint2*)(Pcat + (size_t)(n0 + li) * LD1 + 600);
    float t0L = bflo(tdL.x), t1L = bflo(tdL.y);
    int sL = 0, rxL = 0, ryL = -1;
    float wxL = 0.f, wyL = 0.f;
    if (lk < fastL) {
        int p = begL + lk;
        sL = srcs[p];
        int2 rq = relpk[p];
        rxL = rq.x; ryL = rq.y;
        float dr0 = dR10[rq.x], dr1 = dR11[rq.x];
        if (rq.y >= 0) { dr0 += dR10[rq.y]; dr1 += dR11[rq.y]; }
        uint2 sd = *(const uint2*)(Pcat + (size_t)sL * LD1 + 600);
        float p0 = t0L + bfhi(sd.x) + dr0;
        float p1 = t1L + bfhi(sd.y) + dr1;
        p0 = (p0 >= 0.f) ? p0 : LRALPHA * p0;
        p1 = (p1 >= 0.f) ? p1 : LRALPHA * p1;
        wxL = __expf(-p0);
        wyL = __expf(-p1);
    }
    float b[4][4] = {};
    float rsx[4] = {0.f, 0.f, 0.f, 0.f}, rsy[4] = {0.f, 0.f, 0.f, 0.f};
    int kmax = max(max(fast[0], fast[1]), max(fast[2], fast[3]));
    for (int k = 0; k < kmax; k += 2) {
        // --- load phase: 8 independent edge-gather sets (2 slots x 4 nodes) ---
        uint2 psA[4]; float4 rvA[4]; float wxeA[4], wyeA[4];
        uint2 psB[4]; float4 rvB[4]; float wxeB[4], wyeB[4];
#pragma unroll
        for (int i = 0; i < 4; i++) {
            bool act = (k < fast[i]);
            int ls = i * 16 + k;
            int sE = rdl(sL, ls);
            int rxE = rdl(rxL, ls);
            int ryE = act ? rdl(ryL, ls) : -1;
            wxeA[i] = act ? rdlf(wxL, ls) : 0.f;
            wyeA[i] = act ? rdlf(wyL, ls) : 0.f;
            psA[i] = make_uint2(0u, 0u);
            rvA[i] = make_float4(0.f, 0.f, 0.f, 0.f);
            if (fv) {
                psA[i] = *(const uint2*)(Pcat + (size_t)sE * LD1 + 200 + c4);
                rvA[i] = *(const float4*)(R1i + (size_t)rxE * 200 + c4);
                if (ryE >= 0) {
                    float4 rb = *(const float4*)(R1i + (size_t)ryE * 200 + c4);
                    rvA[i].x += rb.x; rvA[i].y += rb.y; rvA[i].z += rb.z; rvA[i].w += rb.w;
                }
            }
        }
        int k1 = k + 1;
#pragma unroll
        for (int i = 0; i < 4; i++) {
            bool act = (k1 < fast[i]);
            int ls = i * 16 + (k1 & 15);
            int sE = rdl(sL, ls);
            int rxE = rdl(rxL, ls);
            int ryE = act ? rdl(ryL, ls) : -1;
            wxeB[i] = act ? rdlf(wxL, ls) : 0.f;
            wyeB[i] = act ? rdlf(wyL, ls) : 0.f;
            psB[i] = make_uint2(0u, 0u);
            rvB[i] = make_float4(0.f, 0.f, 0.f, 0.f);
            if (fv && act) {
                psB[i] = *(const uint2*)(Pcat + (size_t)sE * LD1 + 200 + c4);
                rvB[i] = *(const float4*)(R1i + (size_t)rxE * 200 + c4);
                if (ryE >= 0) {
                    float4 rb = *(const float4*)(R1i + (size_t)ryE * 200 + c4);
                    rvB[i].x += rb.x; rvB[i].y += rb.y; rvB[i].z += rb.z; rvB[i].w += rb.w;
                }
            }
        }
        // --- accumulate: slot k first, then k+1 (preserves per-node order) ---
#pragma unroll
        for (int i = 0; i < 4; i++) {
            rsx[i] += wxeA[i]; rsy[i] += wyeA[i];
            b[i][0] += wxeA[i] * (bflo(psA[i].x) + rvA[i].x);
            b[i][1] += wyeA[i] * (bfhi(psA[i].x) + rvA[i].y);
            b[i][2] += wxeA[i] * (bflo(psA[i].y) + rvA[i].z);
            b[i][3] += wyeA[i] * (bfhi(psA[i].y) + rvA[i].w);
        }
#pragma unroll
        for (int i = 0; i < 4; i++) {
            rsx[i] += wxeB[i]; rsy[i] += wyeB[i];
            b[i][0] += wxeB[i] * (bflo(psB[i].x) + rvB[i].x);
            b[i][1] += wyeB[i] * (bfhi(psB[i].x) + rvB[i].y);
            b[i][2] += wxeB[i] * (bflo(psB[i].y) + rvB[i].z);
            b[i][3] += wyeB[i] * (bfhi(psB[i].y) + rvB[i].w);
        }
    }
    uint2 pt[4];
#pragma unroll
    for (int i = 0; i < 4; i++)
        pt[i] = fv ? *(const uint2*)(Pcat + (size_t)(n0 + i) * LD1 + c4) : make_uint2(0u, 0u);
#pragma unroll
    for (int i = 0; i < 4; i++) {
        unsigned short* xr = x + (size_t)(n0 + i) * KP2;
        if (fv) {
            if (deg[i] <= DTH) {
                float d0 = (rsx[i] == 0.f) ? 1e-12f : rsx[i];
                float d1 = (rsy[i] == 0.f) ? 1e-12f : rsy[i];
                float i0 = frcp(d0), i1 = frcp(d1);
                float v0 = (b[i][0] + rsx[i] * bflo(pt[i].x)) * i0;
                float v1 = (b[i][1] + rsy[i] * bfhi(pt[i].x)) * i1;
                float v2 = (b[i][2] + rsx[i] * bflo(pt[i].y)) * i0;
                float v3 = (b[i][3] + rsy[i] * bfhi(pt[i].y)) * i1;
                v0 = (v0 > 0.f) ? v0 : __expf(v0) - 1.f;
                v1 = (v1 > 0.f) ? v1 : __expf(v1) - 1.f;
                v2 = (v2 > 0.f) ? v2 : __expf(v2) - 1.f;
                v3 = (v3 > 0.f) ? v3 : __expf(v3) - 1.f;
                uint2 w;
                w.x = (uint32_t)f2bf(v0) | ((uint32_t)f2bf(v1) << 16);
                w.y = (uint32_t)f2bf(v2) | ((uint32_t)f2bf(v3) << 16);
                *(uint2*)(xr + c4) = w;
            }
        } else {
            *(uint2*)(xr + 200 + (lane - 50) * 4) = make_uint2(0u, 0u);
        }
    }
}

// ================= node layer-2 component (masked nodes) =================

static __device__ void d_node2_one(int node, int lane,
                        const int* __restrict__ rowptr, const int* __restrict__ srcs,
                        const int2* __restrict__ relpk,
                        const unsigned short* __restrict__ Qcat,
                        const unsigned short* __restrict__ Pcat,
                        const float* __restrict__ R2, const float* __restrict__ dR2,
                        const float* __restrict__ mask, float* __restrict__ out) {
    bool fv = (lane < 50);
    int c4 = lane * 4;
    int beg = rowptr[node], end = rowptr[node + 1];
    int deg = end - beg;
    int fast = (deg < 64) ? deg : 64;
    uint32_t tq = *(const uint32_t*)(Qcat + (size_t)node * LD2 + 400);
    float tdot = bflo(tq);
    int sL = 0, rxL = 0, ryL = -1;
    float WL = 0.f;
    if (lane < fast) {
        int p = beg + lane;
        sL = srcs[p];
        int2 rp = relpk[p];
        rxL = rp.x; ryL = rp.y;
        float dr = dR2[rp.x];
        if (rp.y >= 0) dr += dR2[rp.y];
        uint32_t sq = *(const uint32_t*)(Qcat + (size_t)sL * LD2 + 400);
        float pp = tdot + bfhi(sq) + dr;
        pp = (pp >= 0.f) ? pp : LRALPHA * pp;
        WL = __expf(-pp);
    }
    float c0 = 0.f, c1 = 0.f, c2 = 0.f, c3 = 0.f;
    float rs = 0.f;
    for (int j = 0; j < fast; j += 4) {
#pragma unroll
        for (int u = 0; u < 4; u++) {
            int jj = j + u;
            bool act = (jj < fast);
            int ls = act ? jj : 0;
            int sE = rdl(sL, ls);
            int rxE = rdl(rxL, ls);
            int ryE = act ? rdl(ryL, ls) : -1;
            float WE = act ? rdlf(WL, ls) : 0.f;
            uint2 qv = make_uint2(0u, 0u);
            float4 rv = make_float4(0.f, 0.f, 0.f, 0.f);
            if (fv) {
                qv = *(const uint2*)(Qcat + (size_t)sE * LD2 + 200 + c4);
                rv = *(const float4*)(R2 + (size_t)rxE * 200 + c4);
                if (ryE >= 0) {
                    float4 rb = *(const float4*)(R2 + (size_t)ryE * 200 + c4);
                    rv.x += rb.x; rv.y += rb.y; rv.z += rb.z; rv.w += rb.w;
                }
            }
            rs += WE;
            c0 += WE * (bflo(qv.x) + rv.x);
            c1 += WE * (bfhi(qv.x) + rv.y);
            c2 += WE * (bflo(qv.y) + rv.z);
            c3 += WE * (bfhi(qv.y) + rv.w);
        }
    }
    for (int p = beg + 64; p < end; p++) {
        int sE = srcs[p];
        int2 rp = relpk[p];
        float dr = dR2[rp.x];
        if (rp.y >= 0) dr += dR2[rp.y];
        uint32_t sq = *(const uint32_t*)(Qcat + (size_t)sE * LD2 + 400);
        float pp = tdot + bfhi(sq) + dr;
        pp = (pp >= 0.f) ? pp : LRALPHA * pp;
        float W = __expf(-pp);
        uint2 qv = make_uint2(0u, 0u);
        float4 rv = make_float4(0.f, 0.f, 0.f, 0.f);
        if (fv) {
            qv = *(const uint2*)(Qcat + (size_t)sE * LD2 + 200 + c4);
            rv = *(const float4*)(R2 + (size_t)rp.x * 200 + c4);
            if (rp.y >= 0) {
                float4 rb = *(const float4*)(R2 + (size_t)rp.y * 200 + c4);
                rv.x += rb.x; rv.y += rb.y; rv.z += rb.z; rv.w += rb.w;
            }
        }
        rs += W;
        c0 += W * (bflo(qv.x) + rv.x);
        c1 += W * (bfhi(qv.x) + rv.y);
        c2 += W * (bflo(qv.y) + rv.z);
        c3 += W * (bfhi(qv.y) + rv.w);
    }
    float d = (rs == 0.f) ? 1e-12f : rs;
    float idn = frcp(d);
    float mk = mask[node];
    float val0 = 0.f, val1 = 0.f, val2 = 0.f, val3 = 0.f;
    if (fv) {
        uint2 t = *(const uint2*)(Qcat + (size_t)node * LD2 + c4);
        uint2 e = *(const uint2*)(Pcat + (size_t)node * LD1 + 400 + c4);
        val0 = bflo(e.x) + mk * ((c0 + rs * bflo(t.x)) * idn);
        val1 = bfhi(e.x) + mk * ((c1 + rs * bfhi(t.x)) * idn);
        val2 = bflo(e.y) + mk * ((c2 + rs * bflo(t.y)) * idn);
        val3 = bfhi(e.y) + mk * ((c3 + rs * bfhi(t.y)) * idn);
    }
    float ss = val0 * val0 + val1 * val1 + val2 * val2 + val3 * val3;
#pragma unroll
    for (int o = 32; o > 0; o >>= 1) ss += __shfl_down(ss, o);
    ss = __shfl(ss, 0);
    float inv = frcp(fmaxf(sqrtf(ss), 1e-12f));
    if (fv) {
        *(float4*)(out + (size_t)node * 200 + c4) =
            make_float4(val0 * inv, val1 * inv, val2 * inv, val3 * inv);
    }
}

// ================= kernels =================

__global__ __launch_bounds__(256) void k_megaA(
        const int* __restrict__ tgt_el, const int* __restrict__ nhop, int* __restrict__ deg,
        const float* __restrict__ rel_emb, const float* __restrict__ att_a,
        float* __restrict__ R1i,
        const float* __restrict__ W_rel, float* __restrict__ outrel,
        const float* __restrict__ att_a2, const float* __restrict__ W_ent,
        unsigned short* __restrict__ W1,
        const float* __restrict__ out_a, const float* __restrict__ out_a2,
        unsigned short* __restrict__ W2,
        const int* __restrict__ batch, float* __restrict__ mask, float* __restrict__ oacc,
        int* __restrict__ cnts) {
    __shared__ __align__(16) char smem[8448];
    int bid = blockIdx.x, tid = threadIdx.x;
    if (bid < A_HIST) {
        d_hist(bid, tid, tgt_el, nhop, deg);
    } else if (bid < A_RELP) {
        d_relproj1(bid - A_HIST, tid, rel_emb, att_a, R1i);
    } else if (bid < A_MMW) {
        int i = bid - A_RELP;
        d_mm<false>(i & 3, i >> 2, smem, tid, rel_emb, 100, W_rel, 200, outrel, 200,
                    N_RELS, 200, 100);
    } else if (bid < A_PACK1) {
        d_pack1(bid - A_MMW, tid, att_a, att_a2, W_ent, W1);
    } else if (bid < A_PACK2) {
        d_pack2(bid - A_PACK1, tid, out_a, out_a2, W2);
    } else if (bid < A_MASK) {
        d_mask(bid - A_PACK2, tid, batch, mask, cnts);
    } else {
        d_ortho_part(bid - A_MASK, tid, att_a, out_a, oacc);
    }
}

__global__ void k_scan1(const int* __restrict__ deg, int* __restrict__ local,
                        int* __restrict__ bsums, int n) {
    int i = blockIdx.x * 256 + threadIdx.x;
    int v = (i < n) ? deg[i] : 0;
    int lane = threadIdx.x & 63;
    int wv = threadIdx.x >> 6;
    int x = v;
#pragma unroll
    for (int o = 1; o < 64; o <<= 1) {
        int t = __shfl_up(x, o);
        if (lane >= o) x += t;
    }
    __shared__ int wtot[4];
    if (lane == 63) wtot[wv] = x;
    __syncthreads();
    int add = 0;
    for (int k = 0; k < wv; k++) add += wtot[k];
    if (i < n) local[i] = add + x - v;
    if (threadIdx.x == 255) bsums[blockIdx.x] = add + x;
}

// scan2 (1 block) + gemm1f (1250) + dR1 (119) + R2 GEMM (32)
__global__ __launch_bounds__(256) void k_megaB(
        int* __restrict__ bsums, int nbk,
        const float* __restrict__ ent_emb, const unsigned short* __restrict__ Wcat1,
        unsigned short* __restrict__ Pcat,
        const float* __restrict__ mask, float* __restrict__ outbuf,
        const float* __restrict__ R1i, const float* __restrict__ att_a2,
        float* __restrict__ dR10, float* __restrict__ dR11,
        const float* __restrict__ outrel, const float* __restrict__ out_a,
        float* __restrict__ R2) {
    __shared__ __align__(16) char smem[33792];
    __shared__ int wtot[4];
    int bid = blockIdx.x, tid = threadIdx.x;
    if (bid == 0) {
        d_scan2(tid, wtot, bsums, nbk);
    } else if (bid < B_DR1) {
        int i = bid - B_G1F;
        d_gemm1f(i % 625, i / 625, smem, tid, ent_emb, Wcat1, Pcat, mask, outbuf);
    } else if (bid < B_R2) {
        d_dR1(bid - B_DR1, tid, R1i, att_a2, dR10, dR11);
    } else {
        int i = bid - B_R2;
        d_mm<true>(i & 3, i >> 2, smem, tid, outrel, 200, out_a + 400, 600, R2, 200,
                   N_RELS, 200, 200);
    }
}

// scan3 (157) + dotv (119)
__global__ void k_scan3d(const int* __restrict__ local, const int* __restrict__ bsums,
                         int* __restrict__ rowptr, int* __restrict__ cursor, int n, int nb,
                         const float* __restrict__ R2, const float* __restrict__ out_a2,
                         float* __restrict__ dR2) {
    int bid = blockIdx.x, tid = threadIdx.x;
    if (bid < S3_DOTV) {
        int i = bid * 256 + tid;
        if (i < n) {
            int v = local[i] + bsums[bid];
            rowptr[i] = v;
            cursor[i] = v;
        } else if (i == n) {
            rowptr[n] = bsums[nb];
        }
    } else {
        int w = (bid - S3_DOTV) * 4 + (tid >> 6);
        int lane = tid & 63;
        if (w < N_RELS) {
            const float* r = R2 + (size_t)w * 200;
            float s = 0.f;
            for (int j = lane; j < 200; j += 64) s += r[j] * out_a2[j];
#pragma unroll
            for (int o = 32; o > 0; o >>= 1) s += __shfl_down(s, o);
            if (lane == 0) dR2[w] = s;
        }
    }
}

// scatter + compact + ortho_fin
__global__ __launch_bounds__(256) void k_megaC(
        const int* __restrict__ tgt_el, const int* __restrict__ src_el,
        const int* __restrict__ etype, const int* __restrict__ nhop, int* __restrict__ cursor,
        int* __restrict__ srcs, int2* __restrict__ relpk,
        const int* __restrict__ rowptr, const float* __restrict__ mask,
        int* __restrict__ Hlist, int* __restrict__ Mlist, int* __restrict__ cnts,
        const float* __restrict__ oacc, float* __restrict__ oscalar) {
    int bid = blockIdx.x, tid = threadIdx.x;
    if (bid < C_CMP) {
        d_scatter(bid, tid, tgt_el, src_el, etype, nhop, cursor, srcs, relpk);
    } else if (bid < C_OFIN) {
        d_compact(bid - C_CMP, tid, rowptr, mask, Hlist, Mlist, cnts);
    } else {
        d_ortho_fin(tid, oacc, oscalar);
    }
}

// NODE1: layer-1 hub FIRST | layer-1 main
__global__ __launch_bounds__(256, 4) void k_node1(
                        const int* __restrict__ rowptr, const int* __restrict__ srcs,
                        const int2* __restrict__ relpk,
                        const unsigned short* __restrict__ Pcat,
                        const float* __restrict__ R1i,
                        const float* __restrict__ dR10, const float* __restrict__ dR11,
                        unsigned short* __restrict__ x,
                        const int* __restrict__ Hlist, const int* __restrict__ cnts) {
    int bid = blockIdx.x, tid = threadIdx.x;
    int lane = tid & 63;
    if (bid < N1_HUB) {
        int hw = bid * 4 + (tid >> 6);
        int cnt = cnts[0];
        for (int j = hw; j < cnt; j += HUBW) {
            int node = __builtin_amdgcn_readfirstlane(Hlist[j]);
            d_node1_one(node, lane, rowptr, srcs, relpk, Pcat, R1i, dR10, dR11, x);
        }
    } else {
        int wid = __builtin_amdgcn_readfirstlane((bid - N1_HUB) * 4 + (tid >> 6));
        d_node1_main(wid, lane, rowptr, srcs, relpk, Pcat, R1i, dR10, dR11, x);
    }
}

__global__ __launch_bounds__(256) void k_gemm2(const unsigned short* __restrict__ A,
                                               const unsigned short* __restrict__ B,
                                               unsigned short* __restrict__ C,
                                               int ldc, int N, int gPerSplit) {
    __shared__ __align__(16) char smem[8192];
    d_gemm<KP2>(blockIdx.x, blockIdx.y, smem, threadIdx.x, A, B, C, ldc, N, gPerSplit);
}

// node2 hub: full-wave aggregation + final fuse for masked nodes only
__global__ __launch_bounds__(256, 4) void k_node2h(
                        const int* __restrict__ rowptr, const int* __restrict__ srcs,
                        const int2* __restrict__ relpk,
                        const unsigned short* __restrict__ Qcat,
                        const unsigned short* __restrict__ Pcat,
                        const float* __restrict__ R2, const float* __restrict__ dR2,
                        const float* __restrict__ mask,
                        const int* __restrict__ Mlist, const int* __restrict__ cnts,
                        float* __restrict__ out) {
    int tid = threadIdx.x;
    int lane = tid & 63;
    int hw = blockIdx.x * 4 + (tid >> 6);
    int cnt = cnts[1];
    for (int j = hw; j < cnt; j += HUBW) {
        int node = __builtin_amdgcn_readfirstlane(Mlist[j]);
        d_node2_one(node, lane, rowptr, srcs, relpk, Qcat, Pcat, R2, dR2, mask, out);
    }
}

// ================= launch =================
extern "C" void kernel_launch(void* const* d_in, const int* in_sizes, int n_in,
                              void* d_out, int out_size, void* d_ws, size_t ws_size,
                              hipStream_t stream) {
    const int* edge_list = (const int*)d_in[0];
    const int* edge_type = (const int*)d_in[1];
    const int* batch     = (const int*)d_in[2];
    const int* nhop      = (const int*)d_in[3];
    const float* ent_emb = (const float*)d_in[4];
    const float* rel_emb = (const float*)d_in[5];
    const float* W_ent   = (const float*)d_in[6];
    const float* W_rel   = (const float*)d_in[7];
    const float* att_a   = (const float*)d_in[8];
    const float* att_a2  = (const float*)d_in[9];
    const float* out_a   = (const float*)d_in[10];
    const float* out_a2  = (const float*)d_in[11];
    float* out = (float*)d_out;
    const int* tgt_el = edge_list;
    const int* src_el = edge_list + E0;

    char* ws = (char*)d_ws;
    size_t o = 0;
    auto alloc = [&](size_t nbytes) -> char* {
        char* p = ws + o;
        o += (nbytes + 255) & ~(size_t)255;
        return p;
    };
    // zero-group first (one memset covers all three, contiguously allocated)
    int* cursor  = (int*)alloc(N_NODES * 4);          // 160000 B
    float* mask  = (float*)alloc(N_NODES * 4);        // 160000 B
    float* oacc  = (float*)alloc(9 * 4);              // 256 B (rounded)
    size_t zbytes = (size_t)((char*)(oacc + 64) - (char*)cursor);  // 320256 + pad
    unsigned short* x_bf    = (unsigned short*)alloc((size_t)N_NODES * KP2 * 2);
    unsigned short* Pcat    = (unsigned short*)alloc((size_t)N_NODES * LD1 * 2);
    unsigned short* Qcat    = (unsigned short*)alloc((size_t)N_NODES * LD2 * 2);
    unsigned short* Wcat1   = (unsigned short*)alloc((size_t)NPAD1 * KP1 * 2);
    unsigned short* Wcat2   = (unsigned short*)alloc((size_t)NPAD2 * KP2 * 2);
    float* R1i   = (float*)alloc(474u * 200 * 4);
    float* R2    = (float*)alloc(474u * 200 * 4);
    float* dR10  = (float*)alloc(474u * 4);
    float* dR11  = (float*)alloc(474u * 4);
    float* dR2   = (float*)alloc(474u * 4);
    int* rowptr  = (int*)alloc((N_NODES + 1) * 4);
    int* srcs    = (int*)alloc((size_t)NE * 4);
    int2* relpk  = (int2*)alloc((size_t)NE * 8);
    int* scanloc = (int*)alloc(N_NODES * 4);
    int* bsums   = (int*)alloc(260 * 4);
    int* Hlist   = (int*)alloc(N_NODES * 4);
    int* Mlist   = (int*)alloc(N_NODES * 4);
    int* cnts    = (int*)alloc(2 * 4);                // zeroed inside megaA

    // single consolidated memset for cursor+mask+oacc
    hipMemsetAsync(cursor, 0, zbytes, stream);

    // 1) hist + relproj1 + out_relation GEMM + pack1 + pack2 + mask(+cnts zero) + ortho partials
    k_megaA<<<A_TOT, 256, 0, stream>>>(tgt_el, nhop, cursor,
                                       rel_emb, att_a, R1i,
                                       W_rel, out + 8000000,
                                       att_a2, W_ent, Wcat1,
                                       out_a, out_a2, Wcat2,
                                       batch, mask, oacc, cnts);
    // 2) CSR scan phase 1
    k_scan1<<<157, 256, 0, stream>>>(cursor, scanloc, bsums, N_NODES);
    // 3) scan2 + layer-1 GEMM (fused l2norm + unmasked out-write) + dR1 + R2 GEMM
    k_megaB<<<B_TOT, 256, 0, stream>>>(bsums, 157, ent_emb, Wcat1, Pcat, mask, out,
                                       R1i, att_a2, dR10, dR11,
                                       out + 8000000, out_a, R2);
    // 4) scan phase 3 + dR2 dotv
    k_scan3d<<<S3_TOT, 256, 0, stream>>>(scanloc, bsums, rowptr, cursor, N_NODES, 157,
                                         R2, out_a2, dR2);
    // 5) scatter + compact + ortho finalize
    k_megaC<<<C_TOT, 256, 0, stream>>>(tgt_el, src_el, edge_type, nhop, cursor,
                                       srcs, relpk, rowptr, mask, Hlist, Mlist, cnts,
                                       oacc, out + 8094800);
    // 6) layer-1 aggregation (hub first, then interleaved main)
    k_node1<<<N1_TOT, 256, 0, stream>>>(rowptr, srcs, relpk, Pcat, R1i, dR10, dR11,
                                        x_bf, Hlist, cnts);
    // 7) layer-2 GEMM
    k_gemm2<<<dim3(625, 2), 256, 0, stream>>>(x_bf, Wcat2, Qcat, LD2, 416, 4);
    // 8) layer-2 masked-node aggregation + final fuse
    k_node2h<<<512, 256, 0, stream>>>(rowptr, srcs, relpk, Qcat, Pcat, R2, dR2,
                                      mask, Mlist, cnts, out);
}